// Round 1
// baseline (355.029 us; speedup 1.0000x reference)
//
#include <hip/hip_runtime.h>
#include <hip/hip_bf16.h>
#include <math.h>

#define LRELU(x) ((x) > 0.0f ? (x) : 0.2f * (x))
#define EPS 1e-16f

// ---------------- CSR build ----------------

__global__ void k_init(int N, int* cnt, float* sumattr) {
    int i = blockIdx.x * blockDim.x + threadIdx.x;
    if (i < N) { cnt[i] = 0; sumattr[i] = 0.0f; }
}

__global__ void k_count(int E, const int* __restrict__ ei, const float* __restrict__ ea,
                        int* cnt, float* sumattr) {
    int e = blockIdx.x * blockDim.x + threadIdx.x;
    if (e < E) {
        int d = ei[E + e];
        atomicAdd(&cnt[d], 1);
        atomicAdd(&sumattr[d], ea[e]);
    }
}

__global__ void k_scan1(int N, const int* __restrict__ cnt, int* rowptr, int* bsums) {
    __shared__ int sm[256];
    int t = threadIdx.x;
    int n = blockIdx.x * 256 + t;
    int val = (n < N) ? (cnt[n] + 1) : 0;   // +1 self loop
    sm[t] = val; __syncthreads();
    for (int ofs = 1; ofs < 256; ofs <<= 1) {
        int v = (t >= ofs) ? sm[t - ofs] : 0;
        __syncthreads();
        sm[t] += v;
        __syncthreads();
    }
    if (n < N) rowptr[n] = sm[t] - val;      // local exclusive
    if (t == 255) bsums[blockIdx.x] = sm[255];
}

__global__ void k_scan2(int nb, int N, int* bsums, int* rowptr) {
    if (threadIdx.x == 0 && blockIdx.x == 0) {
        int run = 0;
        for (int i = 0; i < nb; ++i) { int v = bsums[i]; bsums[i] = run; run += v; }
        rowptr[N] = run;
    }
}

__global__ void k_scan3(int N, int* rowptr, const int* __restrict__ bsums, int* fill,
                        const int* __restrict__ cnt, const float* __restrict__ sumattr,
                        float* loopattr) {
    int n = blockIdx.x * blockDim.x + threadIdx.x;
    if (n < N) {
        rowptr[n] += bsums[n >> 8];
        fill[n] = 0;
        loopattr[n] = sumattr[n] / fmaxf((float)cnt[n], 1.0f);
    }
}

__global__ void k_scatter(int E, int N, const int* __restrict__ ei, const float* __restrict__ ea,
                          const float* __restrict__ loopattr, const int* __restrict__ rowptr,
                          int* fill, int* esrc, float* eattr) {
    int i = blockIdx.x * blockDim.x + threadIdx.x;
    if (i >= E + N) return;
    int s, d; float w;
    if (i < E) { s = ei[i]; d = ei[E + i]; w = ea[i]; }
    else       { s = d = i - E; w = loopattr[s]; }
    int pos = rowptr[d] + atomicAdd(&fill[d], 1);
    esrc[pos] = s;
    eattr[pos] = w;
}

// ---------------- tiny precompute: wed[h] = dot(We_h, att_edge_h) ----------------

__global__ void k_wedot(const float* __restrict__ We1, const float* __restrict__ ae1,
                        const float* __restrict__ We2, const float* __restrict__ ae2,
                        float* wed) {
    int t = threadIdx.x;
    if (t < 8) {
        float s = 0.0f;
        for (int c = 0; c < 16; ++c) s += We1[t * 16 + c] * ae1[t * 16 + c];
        wed[t] = s;
    }
    if (t == 8) {
        float s = 0.0f;
        for (int c = 0; c < 8; ++c) s += We2[c] * ae2[c];
        wed[8] = s;
    }
}

// ---------------- layer 1 dense: h1 = x @ W1 ; asrc1/adst1 dots ----------------
// block = 256 threads = 2 rows x 128 cols

__global__ void k_gemm1(int N, const float* __restrict__ x, const float* __restrict__ W,
                        const float* __restrict__ att_s, const float* __restrict__ att_d,
                        float* __restrict__ h1, float* __restrict__ asrc, float* __restrict__ adst) {
    __shared__ float smx[2][64];
    int t = threadIdx.x;
    int row0 = blockIdx.x * 2;
    if (t < 128) {
        int r = t >> 6, k = t & 63;
        int rr = row0 + r;
        smx[r][k] = (rr < N) ? x[rr * 64 + k] : 0.0f;
    }
    __syncthreads();
    int r = t >> 7, j = t & 127;
    int row = row0 + r;
    float acc = 0.0f;
#pragma unroll
    for (int k = 0; k < 64; ++k) acc = fmaf(smx[r][k], W[k * 128 + j], acc);
    if (row < N) h1[(size_t)row * 128 + j] = acc;
    float vs = acc * att_s[j];
    float vd = acc * att_d[j];
#pragma unroll
    for (int ofs = 8; ofs >= 1; ofs >>= 1) {
        vs += __shfl_down(vs, ofs, 16);
        vd += __shfl_down(vd, ofs, 16);
    }
    if (row < N && (j & 15) == 0) {
        int h = j >> 4;
        asrc[row * 8 + h] = vs;
        adst[row * 8 + h] = vd;
    }
}

// ---------------- layer 1 aggregation: one wave per node ----------------
// H=8, C=16. lane l: phase1 handles (edge slot l>>3, head l&7); phase2 holds
// output elements l (head l>>4) and 64+l (head 4+(l>>4)).

__global__ void k_agg1(int N, const int* __restrict__ rowptr, const int* __restrict__ esrc,
                       const float* __restrict__ eattr, const float* __restrict__ h1,
                       const float* __restrict__ asrc, const float* __restrict__ adst,
                       const float* __restrict__ wed, const float* __restrict__ b1,
                       float* __restrict__ h2out) {
    int wid = (blockIdx.x * blockDim.x + threadIdx.x) >> 6;
    if (wid >= N) return;
    int l = threadIdx.x & 63;
    int n = wid;
    int start = rowptr[n], end = rowptr[n + 1];
    int h = l & 7;
    float adn = adst[n * 8 + h];
    float wdh = wed[h];

    // phase 1: segment max per head
    float m = -INFINITY;
    int eo = l >> 3;
    for (int idx = start + eo; idx < end; idx += 8) {
        int s = esrc[idx];
        float w = eattr[idx];
        float a = asrc[s * 8 + h] + adn + w * wdh;
        m = fmaxf(m, LRELU(a));
    }
    m = fmaxf(m, __shfl_xor(m, 8));
    m = fmaxf(m, __shfl_xor(m, 16));
    m = fmaxf(m, __shfl_xor(m, 32));

    // phase 2: exp + weighted sum (coalesced 512B h1-row gather per edge)
    float denom = 0.0f, acc0 = 0.0f, acc1 = 0.0f;
    int h0 = l >> 4;
    for (int idx = start; idx < end; ++idx) {
        int s = esrc[idx];
        float w = eattr[idx];
        float a = asrc[s * 8 + h] + adn + w * wdh;
        a = LRELU(a);
        float p = __expf(a - m);
        denom += p;
        float p0 = __shfl(p, h0);
        float p1 = __shfl(p, h0 + 4);
        const float* hrow = h1 + (size_t)s * 128;
        acc0 = fmaf(p0, hrow[l], acc0);
        acc1 = fmaf(p1, hrow[64 + l], acc1);
    }
    float d0 = __shfl(denom, h0);
    float d1 = __shfl(denom, h0 + 4);
    float tv = acc0 / (d0 + EPS) + acc1 / (d1 + EPS);
    tv += __shfl_xor(tv, 16);
    tv += __shfl_xor(tv, 32);
    if (l < 16) {
        float v = tv * 0.125f + b1[l];
        h2out[(size_t)n * 16 + l] = fmaxf(v, 0.0f);   // ReLU
    }
}

// ---------------- layer 2 dense: hh = h2 @ W2 ; asrc2/adst2 dots ----------------

__global__ void k_gemm2(int N, const float* __restrict__ h2, const float* __restrict__ W2,
                        const float* __restrict__ as2w, const float* __restrict__ ad2w,
                        float* __restrict__ hh, float* __restrict__ asrc, float* __restrict__ adst) {
    int n = blockIdx.x * blockDim.x + threadIdx.x;
    if (n >= N) return;
    float xr[16];
    const float4* p4 = (const float4*)(h2 + (size_t)n * 16);
#pragma unroll
    for (int q = 0; q < 4; ++q) {
        float4 v = p4[q];
        xr[q * 4 + 0] = v.x; xr[q * 4 + 1] = v.y; xr[q * 4 + 2] = v.z; xr[q * 4 + 3] = v.w;
    }
    float o[8];
#pragma unroll
    for (int c = 0; c < 8; ++c) o[c] = 0.0f;
#pragma unroll
    for (int k = 0; k < 16; ++k) {
        float xk = xr[k];
#pragma unroll
        for (int c = 0; c < 8; ++c) o[c] = fmaf(xk, W2[k * 8 + c], o[c]);
    }
    float s = 0.0f, d = 0.0f;
#pragma unroll
    for (int c = 0; c < 8; ++c) {
        hh[(size_t)n * 8 + c] = o[c];
        s = fmaf(o[c], as2w[c], s);
        d = fmaf(o[c], ad2w[c], d);
    }
    asrc[n] = s;
    adst[n] = d;
}

// ---------------- layer 2 aggregation: one wave per node (H=1, C=8) ----------------

__global__ void k_agg2(int N, const int* __restrict__ rowptr, const int* __restrict__ esrc,
                       const float* __restrict__ eattr, const float* __restrict__ hh,
                       const float* __restrict__ asrc, const float* __restrict__ adst,
                       const float* __restrict__ wed, const float* __restrict__ b2,
                       float* __restrict__ out) {
    int wid = (blockIdx.x * blockDim.x + threadIdx.x) >> 6;
    if (wid >= N) return;
    int l = threadIdx.x & 63;
    int n = wid;
    int start = rowptr[n], end = rowptr[n + 1];
    float adn = adst[n];
    float w2 = wed[8];

    // phase 1: max across all edges (64 edges/iter)
    float m = -INFINITY;
    for (int idx = start + l; idx < end; idx += 64) {
        float a = asrc[esrc[idx]] + adn + eattr[idx] * w2;
        m = fmaxf(m, LRELU(a));
    }
#pragma unroll
    for (int msk = 32; msk >= 1; msk >>= 1) m = fmaxf(m, __shfl_xor(m, msk));

    // phase 2: 8 edges x 8 channels
    float denom = 0.0f, acc = 0.0f;
    int eo = l >> 3, c = l & 7;
    for (int idx = start + eo; idx < end; idx += 8) {
        int s = esrc[idx];
        float a = asrc[s] + adn + eattr[idx] * w2;
        a = LRELU(a);
        float p = __expf(a - m);
        denom += p;
        acc = fmaf(p, hh[(size_t)s * 8 + c], acc);
    }
    acc += __shfl_xor(acc, 8);  acc += __shfl_xor(acc, 16);  acc += __shfl_xor(acc, 32);
    denom += __shfl_xor(denom, 8); denom += __shfl_xor(denom, 16); denom += __shfl_xor(denom, 32);
    if (l < 8) out[(size_t)n * 8 + c] = acc / (denom + EPS) + b2[c];
}

// ---------------- launch ----------------

extern "C" void kernel_launch(void* const* d_in, const int* in_sizes, int n_in,
                              void* d_out, int out_size, void* d_ws, size_t ws_size,
                              hipStream_t stream) {
    const float* x        = (const float*)d_in[0];
    const int*   ei       = (const int*)d_in[1];
    const float* ea       = (const float*)d_in[2];
    const float* W1       = (const float*)d_in[3];
    const float* We1      = (const float*)d_in[4];
    const float* att_src1 = (const float*)d_in[5];
    const float* att_dst1 = (const float*)d_in[6];
    const float* att_edge1= (const float*)d_in[7];
    const float* b1       = (const float*)d_in[8];
    const float* W2       = (const float*)d_in[9];
    const float* We2      = (const float*)d_in[10];
    const float* att_src2 = (const float*)d_in[11];
    const float* att_dst2 = (const float*)d_in[12];
    const float* att_edge2= (const float*)d_in[13];
    const float* b2       = (const float*)d_in[14];
    float* out = (float*)d_out;

    const int N = in_sizes[0] / 64;
    const int E = in_sizes[2];
    const int E2 = E + N;

    // workspace carve (all 256B-aligned)
    char* p = (char*)d_ws;
    auto alloc = [&](size_t bytes) { void* r = (void*)p; p += (bytes + 255) & ~(size_t)255; return r; };
    int*   cnt      = (int*)  alloc((size_t)N * 4);
    float* sumattr  = (float*)alloc((size_t)N * 4);
    float* loopattr = (float*)alloc((size_t)N * 4);
    int*   rowptr   = (int*)  alloc((size_t)(N + 1) * 4);
    int*   fill     = (int*)  alloc((size_t)N * 4);
    int*   bsums    = (int*)  alloc((size_t)4096 * 4);
    int*   esrc     = (int*)  alloc((size_t)E2 * 4);
    float* eattr    = (float*)alloc((size_t)E2 * 4);
    float* h1       = (float*)alloc((size_t)N * 128 * 4);
    float* asrc1    = (float*)alloc((size_t)N * 8 * 4);
    float* adst1    = (float*)alloc((size_t)N * 8 * 4);
    float* h2       = (float*)alloc((size_t)N * 16 * 4);
    float* hh2      = (float*)alloc((size_t)N * 8 * 4);
    float* asrc2    = (float*)alloc((size_t)N * 4);
    float* adst2    = (float*)alloc((size_t)N * 4);
    float* wed      = (float*)alloc(16 * 4);

    const int nbN = (N + 255) / 256;

    hipLaunchKernelGGL(k_init,    dim3(nbN), dim3(256), 0, stream, N, cnt, sumattr);
    hipLaunchKernelGGL(k_count,   dim3((E + 255) / 256), dim3(256), 0, stream, E, ei, ea, cnt, sumattr);
    hipLaunchKernelGGL(k_scan1,   dim3(nbN), dim3(256), 0, stream, N, cnt, rowptr, bsums);
    hipLaunchKernelGGL(k_scan2,   dim3(1), dim3(64), 0, stream, nbN, N, bsums, rowptr);
    hipLaunchKernelGGL(k_scan3,   dim3(nbN), dim3(256), 0, stream, N, rowptr, bsums, fill, cnt, sumattr, loopattr);
    hipLaunchKernelGGL(k_scatter, dim3((E2 + 255) / 256), dim3(256), 0, stream, E, N, ei, ea, loopattr, rowptr, fill, esrc, eattr);
    hipLaunchKernelGGL(k_gemm1,   dim3((N + 1) / 2), dim3(256), 0, stream, N, x, W1, att_src1, att_dst1, h1, asrc1, adst1);
    hipLaunchKernelGGL(k_wedot,   dim3(1), dim3(64), 0, stream, We1, att_edge1, We2, att_edge2, wed);
    hipLaunchKernelGGL(k_agg1,    dim3((N + 3) / 4), dim3(256), 0, stream, N, rowptr, esrc, eattr, h1, asrc1, adst1, wed, b1, h2);
    hipLaunchKernelGGL(k_gemm2,   dim3(nbN), dim3(256), 0, stream, N, h2, W2, att_src2, att_dst2, hh2, asrc2, adst2);
    hipLaunchKernelGGL(k_agg2,    dim3((N + 3) / 4), dim3(256), 0, stream, N, rowptr, esrc, eattr, hh2, asrc2, adst2, wed, b2, out);
}

// Round 2
// 279.053 us; speedup vs baseline: 1.2723x; 1.2723x over previous
//
#include <hip/hip_runtime.h>
#include <hip/hip_fp16.h>
#include <math.h>

#define LRELU(x) ((x) > 0.0f ? (x) : 0.2f * (x))
#define EPS 1e-16f

// ---------------- CSR build ----------------

__global__ void k_init(int N, int* cnt, float* sumattr) {
    int i = blockIdx.x * blockDim.x + threadIdx.x;
    if (i < N) { cnt[i] = 0; sumattr[i] = 0.0f; }
}

__global__ void k_count(int E, const int* __restrict__ ei, const float* __restrict__ ea,
                        int* cnt, float* sumattr) {
    int e = blockIdx.x * blockDim.x + threadIdx.x;
    if (e < E) {
        int d = ei[E + e];
        atomicAdd(&cnt[d], 1);
        atomicAdd(&sumattr[d], ea[e]);
    }
}

__global__ void k_scan1(int N, const int* __restrict__ cnt, int* rowptr, int* bsums) {
    __shared__ int sm[256];
    int t = threadIdx.x;
    int n = blockIdx.x * 256 + t;
    int val = (n < N) ? (cnt[n] + 1) : 0;   // +1 self loop
    sm[t] = val; __syncthreads();
    for (int ofs = 1; ofs < 256; ofs <<= 1) {
        int v = (t >= ofs) ? sm[t - ofs] : 0;
        __syncthreads();
        sm[t] += v;
        __syncthreads();
    }
    if (n < N) rowptr[n] = sm[t] - val;      // local exclusive
    if (t == 255) bsums[blockIdx.x] = sm[255];
}

// parallel block-sum scan (nb <= 256 holds for N <= 65536)
__global__ void k_scan2(int nb, int N, int* bsums, int* rowptr) {
    __shared__ int sm[256];
    int t = threadIdx.x;
    int v = (t < nb) ? bsums[t] : 0;
    sm[t] = v; __syncthreads();
    for (int ofs = 1; ofs < 256; ofs <<= 1) {
        int u = (t >= ofs) ? sm[t - ofs] : 0;
        __syncthreads();
        sm[t] += u;
        __syncthreads();
    }
    if (t < nb) bsums[t] = sm[t] - v;        // exclusive
    if (t == 255) rowptr[N] = sm[255];
}

__global__ void k_scan3(int N, int* rowptr, const int* __restrict__ bsums, int* fill,
                        const int* __restrict__ cnt, const float* __restrict__ sumattr,
                        float* loopattr) {
    int n = blockIdx.x * blockDim.x + threadIdx.x;
    if (n < N) {
        rowptr[n] += bsums[n >> 8];
        fill[n] = 0;
        loopattr[n] = sumattr[n] / fmaxf((float)cnt[n], 1.0f);
    }
}

__global__ void k_scatter(int E, int N, const int* __restrict__ ei, const float* __restrict__ ea,
                          const float* __restrict__ loopattr, const int* __restrict__ rowptr,
                          int* fill, int* esrc, float* eattr) {
    int i = blockIdx.x * blockDim.x + threadIdx.x;
    if (i >= E + N) return;
    int s, d; float w;
    if (i < E) { s = ei[i]; d = ei[E + i]; w = ea[i]; }
    else       { s = d = i - E; w = loopattr[s]; }
    int pos = rowptr[d] + atomicAdd(&fill[d], 1);
    esrc[pos] = s;
    eattr[pos] = w;
}

// ---------------- tiny precompute: wed[h] = dot(We_h, att_edge_h) ----------------

__global__ void k_wedot(const float* __restrict__ We1, const float* __restrict__ ae1,
                        const float* __restrict__ We2, const float* __restrict__ ae2,
                        float* wed) {
    int t = threadIdx.x;
    if (t < 8) {
        float s = 0.0f;
        for (int c = 0; c < 16; ++c) s += We1[t * 16 + c] * ae1[t * 16 + c];
        wed[t] = s;
    }
    if (t == 8) {
        float s = 0.0f;
        for (int c = 0; c < 8; ++c) s += We2[c] * ae2[c];
        wed[8] = s;
    }
}

// ---------------- layer 1 dense: h1 = x @ W1 (fp16 out) ; asrc1/adst1 dots ----------------
// block = 256 threads = 2 rows x 128 cols

__global__ void k_gemm1(int N, const float* __restrict__ x, const float* __restrict__ W,
                        const float* __restrict__ att_s, const float* __restrict__ att_d,
                        __half* __restrict__ h1, float* __restrict__ asrc, float* __restrict__ adst) {
    __shared__ float smx[2][64];
    int t = threadIdx.x;
    int row0 = blockIdx.x * 2;
    if (t < 128) {
        int r = t >> 6, k = t & 63;
        int rr = row0 + r;
        smx[r][k] = (rr < N) ? x[rr * 64 + k] : 0.0f;
    }
    __syncthreads();
    int r = t >> 7, j = t & 127;
    int row = row0 + r;
    float acc = 0.0f;
#pragma unroll
    for (int k = 0; k < 64; ++k) acc = fmaf(smx[r][k], W[k * 128 + j], acc);
    if (row < N) h1[(size_t)row * 128 + j] = __float2half(acc);
    float vs = acc * att_s[j];
    float vd = acc * att_d[j];
#pragma unroll
    for (int ofs = 8; ofs >= 1; ofs >>= 1) {
        vs += __shfl_down(vs, ofs, 16);
        vd += __shfl_down(vd, ofs, 16);
    }
    if (row < N && (j & 15) == 0) {
        int h = j >> 4;
        asrc[row * 8 + h] = vs;
        adst[row * 8 + h] = vd;
    }
}

// ---------------- layer 1 aggregation: one wave per node, 4 edges/iter, shuffle-free loop ----
// fp16 h1 row = 256B = 16 lanes x 16B. lane l: g=l>>4 (edge slot), q=l&15,
// elements 8q..8q+7 (all in head q>>1). No max pass (logits bounded, exp-safe).

__global__ void k_agg1(int N, const int* __restrict__ rowptr, const int* __restrict__ esrc,
                       const float* __restrict__ eattr, const __half* __restrict__ h1,
                       const float* __restrict__ asrc, const float* __restrict__ adst,
                       const float* __restrict__ wed, const float* __restrict__ b1,
                       float* __restrict__ h2out) {
    int wid = (blockIdx.x * blockDim.x + threadIdx.x) >> 6;
    if (wid >= N) return;
    int l = threadIdx.x & 63;
    int g = l >> 4;
    int q = l & 15;
    int hq = q >> 1;
    int start = rowptr[wid], end = rowptr[wid + 1];
    float adn = adst[wid * 8 + hq];
    float wdh = wed[hq];

    float acc[8] = {0.f,0.f,0.f,0.f,0.f,0.f,0.f,0.f};
    float denom = 0.0f;
    for (int base = start; base < end; base += 4) {
        int e = base + g;
        bool valid = (e < end);
        int ee = valid ? e : end - 1;
        int s = esrc[ee];
        float w = eattr[ee];
        float a = asrc[s * 8 + hq] + adn + w * wdh;
        a = LRELU(a);
        float p = valid ? __expf(a) : 0.0f;
        denom += p;
        float4 hv = *(const float4*)(h1 + (size_t)s * 128 + q * 8);
        const __half2* hp = (const __half2*)&hv;
#pragma unroll
        for (int k = 0; k < 4; ++k) {
            float2 f = __half22float2(hp[k]);
            acc[2 * k]     = fmaf(p, f.x, acc[2 * k]);
            acc[2 * k + 1] = fmaf(p, f.y, acc[2 * k + 1]);
        }
    }
    // combine the 4 edge groups (disjoint edge subsets)
#pragma unroll
    for (int k = 0; k < 8; ++k) {
        acc[k] += __shfl_xor(acc[k], 16);
        acc[k] += __shfl_xor(acc[k], 32);
    }
    denom += __shfl_xor(denom, 16);
    denom += __shfl_xor(denom, 32);
    float inv = 1.0f / (denom + EPS);
    float val[8];
#pragma unroll
    for (int k = 0; k < 8; ++k) val[k] = acc[k] * inv;
    // head mean: q = 2h + par; sum over h = xor bits 1..3
#pragma unroll
    for (int k = 0; k < 8; ++k) {
        val[k] += __shfl_xor(val[k], 2);
        val[k] += __shfl_xor(val[k], 4);
        val[k] += __shfl_xor(val[k], 8);
    }
    if (l < 2) {
        int cbase = l * 8;   // l=0 -> c 0..7 ; l=1 -> c 8..15
#pragma unroll
        for (int k = 0; k < 8; ++k) {
            float v = val[k] * 0.125f + b1[cbase + k];
            h2out[(size_t)wid * 16 + cbase + k] = fmaxf(v, 0.0f);   // ReLU
        }
    }
}

// ---------------- layer 2 dense: hh = h2 @ W2 ; asrc2/adst2 dots ----------------

__global__ void k_gemm2(int N, const float* __restrict__ h2, const float* __restrict__ W2,
                        const float* __restrict__ as2w, const float* __restrict__ ad2w,
                        float* __restrict__ hh, float* __restrict__ asrc, float* __restrict__ adst) {
    int n = blockIdx.x * blockDim.x + threadIdx.x;
    if (n >= N) return;
    float xr[16];
    const float4* p4 = (const float4*)(h2 + (size_t)n * 16);
#pragma unroll
    for (int q = 0; q < 4; ++q) {
        float4 v = p4[q];
        xr[q * 4 + 0] = v.x; xr[q * 4 + 1] = v.y; xr[q * 4 + 2] = v.z; xr[q * 4 + 3] = v.w;
    }
    float o[8];
#pragma unroll
    for (int c = 0; c < 8; ++c) o[c] = 0.0f;
#pragma unroll
    for (int k = 0; k < 16; ++k) {
        float xk = xr[k];
#pragma unroll
        for (int c = 0; c < 8; ++c) o[c] = fmaf(xk, W2[k * 8 + c], o[c]);
    }
    float s = 0.0f, d = 0.0f;
#pragma unroll
    for (int c = 0; c < 8; ++c) {
        hh[(size_t)n * 8 + c] = o[c];
        s = fmaf(o[c], as2w[c], s);
        d = fmaf(o[c], ad2w[c], d);
    }
    asrc[n] = s;
    adst[n] = d;
}

// ---------------- layer 2 aggregation: one wave per node, 8 edges/iter, no max pass ------

__global__ void k_agg2(int N, const int* __restrict__ rowptr, const int* __restrict__ esrc,
                       const float* __restrict__ eattr, const float* __restrict__ hh,
                       const float* __restrict__ asrc, const float* __restrict__ adst,
                       const float* __restrict__ wed, const float* __restrict__ b2,
                       float* __restrict__ out) {
    int wid = (blockIdx.x * blockDim.x + threadIdx.x) >> 6;
    if (wid >= N) return;
    int l = threadIdx.x & 63;
    int eo = l >> 3, c = l & 7;
    int start = rowptr[wid], end = rowptr[wid + 1];
    float adn = adst[wid];
    float w2 = wed[8];

    float acc = 0.0f, denom = 0.0f;
    for (int base = start; base < end; base += 8) {
        int e = base + eo;
        bool valid = (e < end);
        int ee = valid ? e : end - 1;
        int s = esrc[ee];
        float a = asrc[s] + adn + eattr[ee] * w2;
        a = LRELU(a);
        float p = valid ? __expf(a) : 0.0f;
        denom += p;
        acc = fmaf(p, hh[(size_t)s * 8 + c], acc);
    }
    acc += __shfl_xor(acc, 8);  acc += __shfl_xor(acc, 16);  acc += __shfl_xor(acc, 32);
    denom += __shfl_xor(denom, 8); denom += __shfl_xor(denom, 16); denom += __shfl_xor(denom, 32);
    if (l < 8) out[(size_t)wid * 8 + l] = acc / (denom + EPS) + b2[l];
}

// ---------------- launch ----------------

extern "C" void kernel_launch(void* const* d_in, const int* in_sizes, int n_in,
                              void* d_out, int out_size, void* d_ws, size_t ws_size,
                              hipStream_t stream) {
    const float* x        = (const float*)d_in[0];
    const int*   ei       = (const int*)d_in[1];
    const float* ea       = (const float*)d_in[2];
    const float* W1       = (const float*)d_in[3];
    const float* We1      = (const float*)d_in[4];
    const float* att_src1 = (const float*)d_in[5];
    const float* att_dst1 = (const float*)d_in[6];
    const float* att_edge1= (const float*)d_in[7];
    const float* b1       = (const float*)d_in[8];
    const float* W2       = (const float*)d_in[9];
    const float* We2      = (const float*)d_in[10];
    const float* att_src2 = (const float*)d_in[11];
    const float* att_dst2 = (const float*)d_in[12];
    const float* att_edge2= (const float*)d_in[13];
    const float* b2       = (const float*)d_in[14];
    float* out = (float*)d_out;

    const int N = in_sizes[0] / 64;
    const int E = in_sizes[2];
    const int E2 = E + N;

    // workspace carve (all 256B-aligned)
    char* p = (char*)d_ws;
    auto alloc = [&](size_t bytes) { void* r = (void*)p; p += (bytes + 255) & ~(size_t)255; return r; };
    int*   cnt      = (int*)  alloc((size_t)N * 4);
    float* sumattr  = (float*)alloc((size_t)N * 4);
    float* loopattr = (float*)alloc((size_t)N * 4);
    int*   rowptr   = (int*)  alloc((size_t)(N + 1) * 4);
    int*   fill     = (int*)  alloc((size_t)N * 4);
    int*   bsums    = (int*)  alloc((size_t)4096 * 4);
    int*   esrc     = (int*)  alloc((size_t)E2 * 4);
    float* eattr    = (float*)alloc((size_t)E2 * 4);
    __half* h1      = (__half*)alloc((size_t)N * 128 * 2);
    float* asrc1    = (float*)alloc((size_t)N * 8 * 4);
    float* adst1    = (float*)alloc((size_t)N * 8 * 4);
    float* h2       = (float*)alloc((size_t)N * 16 * 4);
    float* hh2      = (float*)alloc((size_t)N * 8 * 4);
    float* asrc2    = (float*)alloc((size_t)N * 4);
    float* adst2    = (float*)alloc((size_t)N * 4);
    float* wed      = (float*)alloc(16 * 4);

    const int nbN = (N + 255) / 256;

    hipLaunchKernelGGL(k_init,    dim3(nbN), dim3(256), 0, stream, N, cnt, sumattr);
    hipLaunchKernelGGL(k_count,   dim3((E + 255) / 256), dim3(256), 0, stream, E, ei, ea, cnt, sumattr);
    hipLaunchKernelGGL(k_scan1,   dim3(nbN), dim3(256), 0, stream, N, cnt, rowptr, bsums);
    hipLaunchKernelGGL(k_scan2,   dim3(1), dim3(256), 0, stream, nbN, N, bsums, rowptr);
    hipLaunchKernelGGL(k_scan3,   dim3(nbN), dim3(256), 0, stream, N, rowptr, bsums, fill, cnt, sumattr, loopattr);
    hipLaunchKernelGGL(k_scatter, dim3((E2 + 255) / 256), dim3(256), 0, stream, E, N, ei, ea, loopattr, rowptr, fill, esrc, eattr);
    hipLaunchKernelGGL(k_gemm1,   dim3((N + 1) / 2), dim3(256), 0, stream, N, x, W1, att_src1, att_dst1, h1, asrc1, adst1);
    hipLaunchKernelGGL(k_wedot,   dim3(1), dim3(64), 0, stream, We1, att_edge1, We2, att_edge2, wed);
    hipLaunchKernelGGL(k_agg1,    dim3((N + 3) / 4), dim3(256), 0, stream, N, rowptr, esrc, eattr, h1, asrc1, adst1, wed, b1, h2);
    hipLaunchKernelGGL(k_gemm2,   dim3(nbN), dim3(256), 0, stream, N, h2, W2, att_src2, att_dst2, hh2, asrc2, adst2);
    hipLaunchKernelGGL(k_agg2,    dim3((N + 3) / 4), dim3(256), 0, stream, N, rowptr, esrc, eattr, hh2, asrc2, adst2, wed, b2, out);
}

// Round 3
// 211.339 us; speedup vs baseline: 1.6799x; 1.3204x over previous
//
#include <hip/hip_runtime.h>
#include <hip/hip_fp16.h>
#include <math.h>

#define LRELU(x) ((x) > 0.0f ? (x) : 0.2f * (x))
#define EPS 1e-16f

// CSR-build geometry: 4 dst-ranges x 16384 nodes (64KB LDS histogram),
// 32 edge-chunk blocks per range.
#define RNG 4
#define NRR 16384
#define RB  32

// ---------------- CSR build (atomic-free at global scope) ----------------

// grid = RNG*RB. Block (r,b): histogram dsts of edge chunk b that fall in range r,
// record per-edge local rank, dump histogram (incl. zeros -> no global zero-init).
__global__ __launch_bounds__(256) void k_hist(int E, int CH, const int* __restrict__ ei,
                                              int* __restrict__ H, int* __restrict__ rank) {
    int r = blockIdx.x / RB, b = blockIdx.x % RB;
    __shared__ int hist[NRR];
    for (int i = threadIdx.x; i < NRR; i += 256) hist[i] = 0;
    __syncthreads();
    int lo = b * CH, hi = min(E, (b + 1) * CH);
    int rlo = r << 14;
#pragma unroll 4
    for (int e = lo + threadIdx.x; e < hi; e += 256) {
        int d = ei[E + e];
        int dr = d - rlo;
        if ((unsigned)dr < NRR) rank[e] = atomicAdd(&hist[dr], 1);
    }
    __syncthreads();
    int* Hb = H + (size_t)blockIdx.x * NRR;
    for (int i = threadIdx.x; i < NRR; i += 256) Hb[i] = hist[i];
}

// per node: exclusive-scan its histogram column over the RB blocks (in place),
// emit real-edge count.
__global__ void k_blockscan(int N, int* __restrict__ H, int* __restrict__ cnt) {
    int d = blockIdx.x * blockDim.x + threadIdx.x;
    if (d >= N) return;
    int r = d >> 14, dr = d & (NRR - 1);
    size_t base = ((size_t)r * RB) * NRR + dr;
    int sum = 0;
#pragma unroll
    for (int b = 0; b < RB; ++b) {
        size_t idx = base + (size_t)b * NRR;
        int v = H[idx];
        H[idx] = sum;
        sum += v;
    }
    cnt[d] = sum;
}

__global__ void k_scan1(int N, const int* __restrict__ cnt, int* rowptr, int* bsums) {
    __shared__ int sm[256];
    int t = threadIdx.x;
    int n = blockIdx.x * 256 + t;
    int val = (n < N) ? (cnt[n] + 1) : 0;   // +1 self loop
    sm[t] = val; __syncthreads();
    for (int ofs = 1; ofs < 256; ofs <<= 1) {
        int v = (t >= ofs) ? sm[t - ofs] : 0;
        __syncthreads();
        sm[t] += v;
        __syncthreads();
    }
    if (n < N) rowptr[n] = sm[t] - val;      // local exclusive
    if (t == 255) bsums[blockIdx.x] = sm[255];
}

// parallel block-sum scan (nb <= 256 holds for N <= 65536)
__global__ void k_scan2(int nb, int N, int* bsums, int* rowptr) {
    __shared__ int sm[256];
    int t = threadIdx.x;
    int v = (t < nb) ? bsums[t] : 0;
    sm[t] = v; __syncthreads();
    for (int ofs = 1; ofs < 256; ofs <<= 1) {
        int u = (t >= ofs) ? sm[t - ofs] : 0;
        __syncthreads();
        sm[t] += u;
        __syncthreads();
    }
    if (t < nb) bsums[t] = sm[t] - v;        // exclusive
    if (t == 255) rowptr[N] = sm[255];
}

__global__ void k_scan3(int N, int* rowptr, const int* __restrict__ bsums) {
    int n = blockIdx.x * blockDim.x + threadIdx.x;
    if (n < N) rowptr[n] += bsums[n >> 8];
}

// atomic-free scatter: pos = rowptr[d] + blockoffset + local rank
__global__ void k_scatter(int E, int CH, const int* __restrict__ ei, const float* __restrict__ ea,
                          const int* __restrict__ rowptr, const int* __restrict__ H,
                          const int* __restrict__ rank, int* __restrict__ esrc,
                          float* __restrict__ eattr) {
    int e = blockIdx.x * blockDim.x + threadIdx.x;
    if (e >= E) return;
    int s = ei[e], d = ei[E + e];
    int r = d >> 14, dr = d & (NRR - 1);
    int b = e / CH;
    int pos = rowptr[d] + H[((size_t)(r * RB + b)) * NRR + dr] + rank[e];
    esrc[pos] = s;
    eattr[pos] = ea[e];
}

// fill the reserved last slot of each segment with the self loop (mean edge attr)
__global__ void k_selfloop(int N, const int* __restrict__ rowptr,
                           int* __restrict__ esrc, float* __restrict__ eattr) {
    int d = blockIdx.x * blockDim.x + threadIdx.x;
    if (d >= N) return;
    int start = rowptr[d], slot = rowptr[d + 1] - 1;
    float s = 0.0f;
    for (int i = start; i < slot; ++i) s += eattr[i];
    int c = slot - start;
    esrc[slot] = d;
    eattr[slot] = s / fmaxf((float)c, 1.0f);
}

// ---------------- tiny precompute: wed[h] = dot(We_h, att_edge_h) ----------------

__global__ void k_wedot(const float* __restrict__ We1, const float* __restrict__ ae1,
                        const float* __restrict__ We2, const float* __restrict__ ae2,
                        float* wed) {
    int t = threadIdx.x;
    if (t < 8) {
        float s = 0.0f;
        for (int c = 0; c < 16; ++c) s += We1[t * 16 + c] * ae1[t * 16 + c];
        wed[t] = s;
    }
    if (t == 8) {
        float s = 0.0f;
        for (int c = 0; c < 8; ++c) s += We2[c] * ae2[c];
        wed[8] = s;
    }
}

// ---------------- layer 1 dense: h1 = x @ W1 (fp16 out) ; asrc1/adst1 dots ----------------
// block = 256 threads = 2 rows x 128 cols

__global__ void k_gemm1(int N, const float* __restrict__ x, const float* __restrict__ W,
                        const float* __restrict__ att_s, const float* __restrict__ att_d,
                        __half* __restrict__ h1, float* __restrict__ asrc, float* __restrict__ adst) {
    __shared__ float smx[2][64];
    int t = threadIdx.x;
    int row0 = blockIdx.x * 2;
    if (t < 128) {
        int r = t >> 6, k = t & 63;
        int rr = row0 + r;
        smx[r][k] = (rr < N) ? x[rr * 64 + k] : 0.0f;
    }
    __syncthreads();
    int r = t >> 7, j = t & 127;
    int row = row0 + r;
    float acc = 0.0f;
#pragma unroll
    for (int k = 0; k < 64; ++k) acc = fmaf(smx[r][k], W[k * 128 + j], acc);
    if (row < N) h1[(size_t)row * 128 + j] = __float2half(acc);
    float vs = acc * att_s[j];
    float vd = acc * att_d[j];
#pragma unroll
    for (int ofs = 8; ofs >= 1; ofs >>= 1) {
        vs += __shfl_down(vs, ofs, 16);
        vd += __shfl_down(vd, ofs, 16);
    }
    if (row < N && (j & 15) == 0) {
        int h = j >> 4;
        asrc[row * 8 + h] = vs;
        adst[row * 8 + h] = vd;
    }
}

// ---------------- layer 1 aggregation: one wave per node, 4 edges/iter, shuffle-free loop ----
// fp16 h1 row = 256B = 16 lanes x 16B. lane l: g=l>>4 (edge slot), q=l&15,
// elements 8q..8q+7 (all in head q>>1). No max pass (logits bounded, exp-safe).

__global__ void k_agg1(int N, const int* __restrict__ rowptr, const int* __restrict__ esrc,
                       const float* __restrict__ eattr, const __half* __restrict__ h1,
                       const float* __restrict__ asrc, const float* __restrict__ adst,
                       const float* __restrict__ wed, const float* __restrict__ b1,
                       float* __restrict__ h2out) {
    int wid = (blockIdx.x * blockDim.x + threadIdx.x) >> 6;
    if (wid >= N) return;
    int l = threadIdx.x & 63;
    int g = l >> 4;
    int q = l & 15;
    int hq = q >> 1;
    int start = rowptr[wid], end = rowptr[wid + 1];
    float adn = adst[wid * 8 + hq];
    float wdh = wed[hq];

    float acc[8] = {0.f,0.f,0.f,0.f,0.f,0.f,0.f,0.f};
    float denom = 0.0f;
    for (int base = start; base < end; base += 4) {
        int e = base + g;
        bool valid = (e < end);
        int ee = valid ? e : end - 1;
        int s = esrc[ee];
        float w = eattr[ee];
        float a = asrc[s * 8 + hq] + adn + w * wdh;
        a = LRELU(a);
        float p = valid ? __expf(a) : 0.0f;
        denom += p;
        float4 hv = *(const float4*)(h1 + (size_t)s * 128 + q * 8);
        const __half2* hp = (const __half2*)&hv;
#pragma unroll
        for (int k = 0; k < 4; ++k) {
            float2 f = __half22float2(hp[k]);
            acc[2 * k]     = fmaf(p, f.x, acc[2 * k]);
            acc[2 * k + 1] = fmaf(p, f.y, acc[2 * k + 1]);
        }
    }
    // combine the 4 edge groups (disjoint edge subsets)
#pragma unroll
    for (int k = 0; k < 8; ++k) {
        acc[k] += __shfl_xor(acc[k], 16);
        acc[k] += __shfl_xor(acc[k], 32);
    }
    denom += __shfl_xor(denom, 16);
    denom += __shfl_xor(denom, 32);
    float inv = 1.0f / (denom + EPS);
    float val[8];
#pragma unroll
    for (int k = 0; k < 8; ++k) val[k] = acc[k] * inv;
    // head mean: q = 2h + par; sum over h = xor bits 1..3
#pragma unroll
    for (int k = 0; k < 8; ++k) {
        val[k] += __shfl_xor(val[k], 2);
        val[k] += __shfl_xor(val[k], 4);
        val[k] += __shfl_xor(val[k], 8);
    }
    if (l < 2) {
        int cbase = l * 8;   // l=0 -> c 0..7 ; l=1 -> c 8..15
#pragma unroll
        for (int k = 0; k < 8; ++k) {
            float v = val[k] * 0.125f + b1[cbase + k];
            h2out[(size_t)wid * 16 + cbase + k] = fmaxf(v, 0.0f);   // ReLU
        }
    }
}

// ---------------- layer 2 dense: hh = h2 @ W2 ; asrc2/adst2 dots ----------------

__global__ void k_gemm2(int N, const float* __restrict__ h2, const float* __restrict__ W2,
                        const float* __restrict__ as2w, const float* __restrict__ ad2w,
                        float* __restrict__ hh, float* __restrict__ asrc, float* __restrict__ adst) {
    int n = blockIdx.x * blockDim.x + threadIdx.x;
    if (n >= N) return;
    float xr[16];
    const float4* p4 = (const float4*)(h2 + (size_t)n * 16);
#pragma unroll
    for (int q = 0; q < 4; ++q) {
        float4 v = p4[q];
        xr[q * 4 + 0] = v.x; xr[q * 4 + 1] = v.y; xr[q * 4 + 2] = v.z; xr[q * 4 + 3] = v.w;
    }
    float o[8];
#pragma unroll
    for (int c = 0; c < 8; ++c) o[c] = 0.0f;
#pragma unroll
    for (int k = 0; k < 16; ++k) {
        float xk = xr[k];
#pragma unroll
        for (int c = 0; c < 8; ++c) o[c] = fmaf(xk, W2[k * 8 + c], o[c]);
    }
    float s = 0.0f, d = 0.0f;
#pragma unroll
    for (int c = 0; c < 8; ++c) {
        hh[(size_t)n * 8 + c] = o[c];
        s = fmaf(o[c], as2w[c], s);
        d = fmaf(o[c], ad2w[c], d);
    }
    asrc[n] = s;
    adst[n] = d;
}

// ---------------- layer 2 aggregation: one wave per node, 8 edges/iter, no max pass ------

__global__ void k_agg2(int N, const int* __restrict__ rowptr, const int* __restrict__ esrc,
                       const float* __restrict__ eattr, const float* __restrict__ hh,
                       const float* __restrict__ asrc, const float* __restrict__ adst,
                       const float* __restrict__ wed, const float* __restrict__ b2,
                       float* __restrict__ out) {
    int wid = (blockIdx.x * blockDim.x + threadIdx.x) >> 6;
    if (wid >= N) return;
    int l = threadIdx.x & 63;
    int eo = l >> 3, c = l & 7;
    int start = rowptr[wid], end = rowptr[wid + 1];
    float adn = adst[wid];
    float w2 = wed[8];

    float acc = 0.0f, denom = 0.0f;
    for (int base = start; base < end; base += 8) {
        int e = base + eo;
        bool valid = (e < end);
        int ee = valid ? e : end - 1;
        int s = esrc[ee];
        float a = asrc[s] + adn + eattr[ee] * w2;
        a = LRELU(a);
        float p = valid ? __expf(a) : 0.0f;
        denom += p;
        acc = fmaf(p, hh[(size_t)s * 8 + c], acc);
    }
    acc += __shfl_xor(acc, 8);  acc += __shfl_xor(acc, 16);  acc += __shfl_xor(acc, 32);
    denom += __shfl_xor(denom, 8); denom += __shfl_xor(denom, 16); denom += __shfl_xor(denom, 32);
    if (l < 8) out[(size_t)wid * 8 + l] = acc / (denom + EPS) + b2[l];
}

// ---------------- launch ----------------

extern "C" void kernel_launch(void* const* d_in, const int* in_sizes, int n_in,
                              void* d_out, int out_size, void* d_ws, size_t ws_size,
                              hipStream_t stream) {
    const float* x        = (const float*)d_in[0];
    const int*   ei       = (const int*)d_in[1];
    const float* ea       = (const float*)d_in[2];
    const float* W1       = (const float*)d_in[3];
    const float* We1      = (const float*)d_in[4];
    const float* att_src1 = (const float*)d_in[5];
    const float* att_dst1 = (const float*)d_in[6];
    const float* att_edge1= (const float*)d_in[7];
    const float* b1       = (const float*)d_in[8];
    const float* W2       = (const float*)d_in[9];
    const float* We2      = (const float*)d_in[10];
    const float* att_src2 = (const float*)d_in[11];
    const float* att_dst2 = (const float*)d_in[12];
    const float* att_edge2= (const float*)d_in[13];
    const float* b2       = (const float*)d_in[14];
    float* out = (float*)d_out;

    const int N = in_sizes[0] / 64;
    const int E = in_sizes[2];
    const int E2 = E + N;
    const int CH = (E + RB - 1) / RB;   // edges per chunk-block

    // workspace carve (all 256B-aligned)
    char* p = (char*)d_ws;
    auto alloc = [&](size_t bytes) { void* r = (void*)p; p += (bytes + 255) & ~(size_t)255; return r; };
    int*   cnt      = (int*)  alloc((size_t)N * 4);
    int*   rowptr   = (int*)  alloc((size_t)(N + 1) * 4);
    int*   bsums    = (int*)  alloc((size_t)4096 * 4);
    int*   rank     = (int*)  alloc((size_t)E * 4);
    int*   H        = (int*)  alloc((size_t)RNG * RB * NRR * 4);
    int*   esrc     = (int*)  alloc((size_t)E2 * 4);
    float* eattr    = (float*)alloc((size_t)E2 * 4);
    __half* h1      = (__half*)alloc((size_t)N * 128 * 2);
    float* asrc1    = (float*)alloc((size_t)N * 8 * 4);
    float* adst1    = (float*)alloc((size_t)N * 8 * 4);
    float* h2       = (float*)alloc((size_t)N * 16 * 4);
    float* hh2      = (float*)alloc((size_t)N * 8 * 4);
    float* asrc2    = (float*)alloc((size_t)N * 4);
    float* adst2    = (float*)alloc((size_t)N * 4);
    float* wed      = (float*)alloc(16 * 4);

    const int nbN = (N + 255) / 256;

    hipLaunchKernelGGL(k_hist,      dim3(RNG * RB), dim3(256), 0, stream, E, CH, ei, H, rank);
    hipLaunchKernelGGL(k_blockscan, dim3(nbN), dim3(256), 0, stream, N, H, cnt);
    hipLaunchKernelGGL(k_scan1,     dim3(nbN), dim3(256), 0, stream, N, cnt, rowptr, bsums);
    hipLaunchKernelGGL(k_scan2,     dim3(1), dim3(256), 0, stream, nbN, N, bsums, rowptr);
    hipLaunchKernelGGL(k_scan3,     dim3(nbN), dim3(256), 0, stream, N, rowptr, bsums);
    hipLaunchKernelGGL(k_scatter,   dim3((E + 255) / 256), dim3(256), 0, stream, E, CH, ei, ea, rowptr, H, rank, esrc, eattr);
    hipLaunchKernelGGL(k_selfloop,  dim3(nbN), dim3(256), 0, stream, N, rowptr, esrc, eattr);
    hipLaunchKernelGGL(k_gemm1,     dim3((N + 1) / 2), dim3(256), 0, stream, N, x, W1, att_src1, att_dst1, h1, asrc1, adst1);
    hipLaunchKernelGGL(k_wedot,     dim3(1), dim3(64), 0, stream, We1, att_edge1, We2, att_edge2, wed);
    hipLaunchKernelGGL(k_agg1,      dim3((N + 3) / 4), dim3(256), 0, stream, N, rowptr, esrc, eattr, h1, asrc1, adst1, wed, b1, h2);
    hipLaunchKernelGGL(k_gemm2,     dim3(nbN), dim3(256), 0, stream, N, h2, W2, att_src2, att_dst2, hh2, asrc2, adst2);
    hipLaunchKernelGGL(k_agg2,      dim3((N + 3) / 4), dim3(256), 0, stream, N, rowptr, esrc, eattr, hh2, asrc2, adst2, wed, b2, out);
}

// Round 4
// 187.354 us; speedup vs baseline: 1.8950x; 1.1280x over previous
//
#include <hip/hip_runtime.h>
#include <hip/hip_fp16.h>
#include <math.h>

#define LRELU(x) ((x) > 0.0f ? (x) : 0.2f * (x))
#define EPS 1e-16f

typedef _Float16 half8 __attribute__((ext_vector_type(8)));
typedef float floatx4 __attribute__((ext_vector_type(4)));

// CSR-build geometry: 4 dst-ranges x 16384 nodes (64KB LDS histogram),
// 32 edge-chunk blocks per range.
#define RNG 4
#define NRR 16384
#define RB  32

// ---------------- CSR build (atomic-free at global scope) ----------------

__global__ __launch_bounds__(256) void k_hist(int E, int CH, const int* __restrict__ ei,
                                              int* __restrict__ H, int* __restrict__ rank) {
    int r = blockIdx.x / RB, b = blockIdx.x % RB;
    __shared__ int hist[NRR];
    for (int i = threadIdx.x; i < NRR; i += 256) hist[i] = 0;
    __syncthreads();
    int lo = b * CH, hi = min(E, (b + 1) * CH);
    int rlo = r << 14;
#pragma unroll 4
    for (int e = lo + threadIdx.x; e < hi; e += 256) {
        int d = ei[E + e];
        int dr = d - rlo;
        if ((unsigned)dr < NRR) rank[e] = atomicAdd(&hist[dr], 1);
    }
    __syncthreads();
    int* Hb = H + (size_t)blockIdx.x * NRR;
    for (int i = threadIdx.x; i < NRR; i += 256) Hb[i] = hist[i];
}

__global__ void k_blockscan(int N, int* __restrict__ H, int* __restrict__ cnt) {
    int d = blockIdx.x * blockDim.x + threadIdx.x;
    if (d >= N) return;
    int r = d >> 14, dr = d & (NRR - 1);
    size_t base = ((size_t)r * RB) * NRR + dr;
    int sum = 0;
#pragma unroll
    for (int b = 0; b < RB; ++b) {
        size_t idx = base + (size_t)b * NRR;
        int v = H[idx];
        H[idx] = sum;
        sum += v;
    }
    cnt[d] = sum;
}

__global__ void k_scan1(int N, const int* __restrict__ cnt, int* rowptr, int* bsums) {
    __shared__ int sm[256];
    int t = threadIdx.x;
    int n = blockIdx.x * 256 + t;
    int val = (n < N) ? (cnt[n] + 1) : 0;   // +1 self loop
    sm[t] = val; __syncthreads();
    for (int ofs = 1; ofs < 256; ofs <<= 1) {
        int v = (t >= ofs) ? sm[t - ofs] : 0;
        __syncthreads();
        sm[t] += v;
        __syncthreads();
    }
    if (n < N) rowptr[n] = sm[t] - val;
    if (t == 255) bsums[blockIdx.x] = sm[255];
}

__global__ void k_scan2(int nb, int N, int* bsums, int* rowptr) {
    __shared__ int sm[256];
    int t = threadIdx.x;
    int v = (t < nb) ? bsums[t] : 0;
    sm[t] = v; __syncthreads();
    for (int ofs = 1; ofs < 256; ofs <<= 1) {
        int u = (t >= ofs) ? sm[t - ofs] : 0;
        __syncthreads();
        sm[t] += u;
        __syncthreads();
    }
    if (t < nb) bsums[t] = sm[t] - v;
    if (t == 255) rowptr[N] = sm[255];
}

__global__ void k_scan3(int N, int* rowptr, const int* __restrict__ bsums) {
    int n = blockIdx.x * blockDim.x + threadIdx.x;
    if (n < N) rowptr[n] += bsums[n >> 8];
}

__global__ void k_scatter(int E, int CH, const int* __restrict__ ei, const float* __restrict__ ea,
                          const int* __restrict__ rowptr, const int* __restrict__ H,
                          const int* __restrict__ rank, int* __restrict__ esrc,
                          float* __restrict__ eattr) {
    int e = blockIdx.x * blockDim.x + threadIdx.x;
    if (e >= E) return;
    int s = ei[e], d = ei[E + e];
    int r = d >> 14, dr = d & (NRR - 1);
    int b = e / CH;
    int pos = rowptr[d] + H[((size_t)(r * RB + b)) * NRR + dr] + rank[e];
    esrc[pos] = s;
    eattr[pos] = ea[e];
}

__global__ void k_selfloop(int N, const int* __restrict__ rowptr,
                           int* __restrict__ esrc, float* __restrict__ eattr) {
    int d = blockIdx.x * blockDim.x + threadIdx.x;
    if (d >= N) return;
    int start = rowptr[d], slot = rowptr[d + 1] - 1;
    float s = 0.0f;
    for (int i = start; i < slot; ++i) s += eattr[i];
    int c = slot - start;
    esrc[slot] = d;
    eattr[slot] = s / fmaxf((float)c, 1.0f);
}

// ---------------- tiny precompute ----------------

__global__ void k_wedot(const float* __restrict__ We1, const float* __restrict__ ae1,
                        const float* __restrict__ We2, const float* __restrict__ ae2,
                        float* wed) {
    int t = threadIdx.x;
    if (t < 8) {
        float s = 0.0f;
        for (int c = 0; c < 16; ++c) s += We1[t * 16 + c] * ae1[t * 16 + c];
        wed[t] = s;
    }
    if (t == 8) {
        float s = 0.0f;
        for (int c = 0; c < 8; ++c) s += We2[c] * ae2[c];
        wed[8] = s;
    }
}

// x -> fp16, zero-padded to Mpad rows. thread handles 8 contiguous elements.
__global__ void k_cvtx(int N, int Mpad, const float* __restrict__ x, _Float16* __restrict__ xh) {
    int t = blockIdx.x * blockDim.x + threadIdx.x;
    if (t >= Mpad * 8) return;
    int row = t >> 3;
    half8 h;
    if (row < N) {
        const float4* p = (const float4*)(x + (size_t)t * 8);
        float4 f0 = p[0], f1 = p[1];
        h[0] = (_Float16)f0.x; h[1] = (_Float16)f0.y; h[2] = (_Float16)f0.z; h[3] = (_Float16)f0.w;
        h[4] = (_Float16)f1.x; h[5] = (_Float16)f1.y; h[6] = (_Float16)f1.z; h[7] = (_Float16)f1.w;
    } else {
        for (int i = 0; i < 8; ++i) h[i] = (_Float16)0.0f;
    }
    *(half8*)(xh + (size_t)t * 8) = h;
}

// pack W1 (64x128 f32) into B-fragment order:
// Wpk[((ct*2+ks)*64 + lane)*8 + j] = W1[(ks*32 + (lane>>4)*8 + j)*128 + ct*16 + (lane&15)]
__global__ void k_prepW(const float* __restrict__ W1, _Float16* __restrict__ Wpk) {
    int t = threadIdx.x;
    for (int i = 0; i < 32; ++i) {
        int idx = i * 256 + t;           // 8192 total
        int j  = idx & 7;
        int l  = (idx >> 3) & 63;
        int ks = (idx >> 9) & 1;
        int ct = idx >> 10;
        int k   = ks * 32 + (l >> 4) * 8 + j;
        int col = ct * 16 + (l & 15);
        Wpk[idx] = (_Float16)W1[k * 128 + col];
    }
}

// ---------------- layer 1 dense via MFMA ----------------
// block = 256 = 4 waves; wave w computes rows [blk*64+w*16, +16) x 128 cols.
// 16 MFMAs (8 col-tiles x K=64), stage fp32 to LDS [64][132], then pass2:
// thread (r = t>>2, g = t&3) -> att dots for heads 2g,2g+1 + fp16 h1 store.

#define LDSP 132

__global__ __launch_bounds__(256) void k_gemm1m(
    int N, const _Float16* __restrict__ xh, const _Float16* __restrict__ Wpk,
    const float* __restrict__ att_s, const float* __restrict__ att_d,
    __half* __restrict__ h1, float* __restrict__ asrc, float* __restrict__ adst) {
    __shared__ float hs[4 * 16 * LDSP];
    int tid = threadIdx.x;
    int w = tid >> 6, l = tid & 63;
    int row0 = blockIdx.x * 64 + w * 16;
    int arow = row0 + (l & 15);
    half8 a0 = *(const half8*)(xh + (size_t)arow * 64 + (l >> 4) * 8);
    half8 a1 = *(const half8*)(xh + (size_t)arow * 64 + 32 + (l >> 4) * 8);
    float* base = &hs[w * 16 * LDSP];
    int r0 = (l >> 4) * 4;
#pragma unroll
    for (int ct = 0; ct < 8; ++ct) {
        half8 b0 = *(const half8*)(Wpk + ((ct * 2 + 0) * 64 + l) * 8);
        half8 b1 = *(const half8*)(Wpk + ((ct * 2 + 1) * 64 + l) * 8);
        floatx4 acc = {0.f, 0.f, 0.f, 0.f};
        acc = __builtin_amdgcn_mfma_f32_16x16x32_f16(a0, b0, acc, 0, 0, 0);
        acc = __builtin_amdgcn_mfma_f32_16x16x32_f16(a1, b1, acc, 0, 0, 0);
        int col = ct * 16 + (l & 15);
#pragma unroll
        for (int i = 0; i < 4; ++i)
            base[(r0 + i) * LDSP + col] = acc[i];
    }
    __syncthreads();
    // pass 2
    int r = tid >> 2, g = tid & 3;
    int rg = blockIdx.x * 64 + r;
    if (rg >= N) return;
    float v[32];
    const float* rp = &hs[r * LDSP + g * 32];
#pragma unroll
    for (int j = 0; j < 8; ++j) {
        floatx4 t4 = *(const floatx4*)(rp + j * 4);
        v[j * 4 + 0] = t4[0]; v[j * 4 + 1] = t4[1];
        v[j * 4 + 2] = t4[2]; v[j * 4 + 3] = t4[3];
    }
    float vs0 = 0.f, vs1 = 0.f, vd0 = 0.f, vd1 = 0.f;
    const float4* as4 = (const float4*)(att_s + g * 32);
    const float4* ad4 = (const float4*)(att_d + g * 32);
#pragma unroll
    for (int j = 0; j < 4; ++j) {
        float4 a4 = as4[j], d4 = ad4[j];
        vs0 += v[j*4+0]*a4.x + v[j*4+1]*a4.y + v[j*4+2]*a4.z + v[j*4+3]*a4.w;
        vd0 += v[j*4+0]*d4.x + v[j*4+1]*d4.y + v[j*4+2]*d4.z + v[j*4+3]*d4.w;
    }
#pragma unroll
    for (int j = 4; j < 8; ++j) {
        float4 a4 = as4[j], d4 = ad4[j];
        vs1 += v[j*4+0]*a4.x + v[j*4+1]*a4.y + v[j*4+2]*a4.z + v[j*4+3]*a4.w;
        vd1 += v[j*4+0]*d4.x + v[j*4+1]*d4.y + v[j*4+2]*d4.z + v[j*4+3]*d4.w;
    }
    union { __half h[32]; float4 f4[4]; } u;
#pragma unroll
    for (int i = 0; i < 32; ++i) u.h[i] = __float2half(v[i]);
    float4* hp = (float4*)(h1 + (size_t)rg * 128 + g * 32);
#pragma unroll
    for (int j = 0; j < 4; ++j) hp[j] = u.f4[j];
    asrc[rg * 8 + g * 2]     = vs0;
    asrc[rg * 8 + g * 2 + 1] = vs1;
    adst[rg * 8 + g * 2]     = vd0;
    adst[rg * 8 + g * 2 + 1] = vd1;
}

// ---------------- layer 1 aggregation (unchanged) ----------------

__global__ void k_agg1(int N, const int* __restrict__ rowptr, const int* __restrict__ esrc,
                       const float* __restrict__ eattr, const __half* __restrict__ h1,
                       const float* __restrict__ asrc, const float* __restrict__ adst,
                       const float* __restrict__ wed, const float* __restrict__ b1,
                       float* __restrict__ h2out) {
    int wid = (blockIdx.x * blockDim.x + threadIdx.x) >> 6;
    if (wid >= N) return;
    int l = threadIdx.x & 63;
    int g = l >> 4;
    int q = l & 15;
    int hq = q >> 1;
    int start = rowptr[wid], end = rowptr[wid + 1];
    float adn = adst[wid * 8 + hq];
    float wdh = wed[hq];

    float acc[8] = {0.f,0.f,0.f,0.f,0.f,0.f,0.f,0.f};
    float denom = 0.0f;
    for (int base = start; base < end; base += 4) {
        int e = base + g;
        bool valid = (e < end);
        int ee = valid ? e : end - 1;
        int s = esrc[ee];
        float w = eattr[ee];
        float a = asrc[s * 8 + hq] + adn + w * wdh;
        a = LRELU(a);
        float p = valid ? __expf(a) : 0.0f;
        denom += p;
        float4 hv = *(const float4*)(h1 + (size_t)s * 128 + q * 8);
        const __half2* hp = (const __half2*)&hv;
#pragma unroll
        for (int k = 0; k < 4; ++k) {
            float2 f = __half22float2(hp[k]);
            acc[2 * k]     = fmaf(p, f.x, acc[2 * k]);
            acc[2 * k + 1] = fmaf(p, f.y, acc[2 * k + 1]);
        }
    }
#pragma unroll
    for (int k = 0; k < 8; ++k) {
        acc[k] += __shfl_xor(acc[k], 16);
        acc[k] += __shfl_xor(acc[k], 32);
    }
    denom += __shfl_xor(denom, 16);
    denom += __shfl_xor(denom, 32);
    float inv = 1.0f / (denom + EPS);
    float val[8];
#pragma unroll
    for (int k = 0; k < 8; ++k) val[k] = acc[k] * inv;
#pragma unroll
    for (int k = 0; k < 8; ++k) {
        val[k] += __shfl_xor(val[k], 2);
        val[k] += __shfl_xor(val[k], 4);
        val[k] += __shfl_xor(val[k], 8);
    }
    if (l < 2) {
        int cbase = l * 8;
#pragma unroll
        for (int k = 0; k < 8; ++k) {
            float v = val[k] * 0.125f + b1[cbase + k];
            h2out[(size_t)wid * 16 + cbase + k] = fmaxf(v, 0.0f);
        }
    }
}

// ---------------- layer 2 dense ----------------

__global__ void k_gemm2(int N, const float* __restrict__ h2, const float* __restrict__ W2,
                        const float* __restrict__ as2w, const float* __restrict__ ad2w,
                        float* __restrict__ hh, float* __restrict__ asrc, float* __restrict__ adst) {
    int n = blockIdx.x * blockDim.x + threadIdx.x;
    if (n >= N) return;
    float xr[16];
    const float4* p4 = (const float4*)(h2 + (size_t)n * 16);
#pragma unroll
    for (int q = 0; q < 4; ++q) {
        float4 v = p4[q];
        xr[q * 4 + 0] = v.x; xr[q * 4 + 1] = v.y; xr[q * 4 + 2] = v.z; xr[q * 4 + 3] = v.w;
    }
    float o[8];
#pragma unroll
    for (int c = 0; c < 8; ++c) o[c] = 0.0f;
#pragma unroll
    for (int k = 0; k < 16; ++k) {
        float xk = xr[k];
#pragma unroll
        for (int c = 0; c < 8; ++c) o[c] = fmaf(xk, W2[k * 8 + c], o[c]);
    }
    float s = 0.0f, d = 0.0f;
#pragma unroll
    for (int c = 0; c < 8; ++c) {
        hh[(size_t)n * 8 + c] = o[c];
        s = fmaf(o[c], as2w[c], s);
        d = fmaf(o[c], ad2w[c], d);
    }
    asrc[n] = s;
    adst[n] = d;
}

// ---------------- layer 2 aggregation ----------------

__global__ void k_agg2(int N, const int* __restrict__ rowptr, const int* __restrict__ esrc,
                       const float* __restrict__ eattr, const float* __restrict__ hh,
                       const float* __restrict__ asrc, const float* __restrict__ adst,
                       const float* __restrict__ wed, const float* __restrict__ b2,
                       float* __restrict__ out) {
    int wid = (blockIdx.x * blockDim.x + threadIdx.x) >> 6;
    if (wid >= N) return;
    int l = threadIdx.x & 63;
    int eo = l >> 3, c = l & 7;
    int start = rowptr[wid], end = rowptr[wid + 1];
    float adn = adst[wid];
    float w2 = wed[8];

    float acc = 0.0f, denom = 0.0f;
    for (int base = start; base < end; base += 8) {
        int e = base + eo;
        bool valid = (e < end);
        int ee = valid ? e : end - 1;
        int s = esrc[ee];
        float a = asrc[s] + adn + eattr[ee] * w2;
        a = LRELU(a);
        float p = valid ? __expf(a) : 0.0f;
        denom += p;
        acc = fmaf(p, hh[(size_t)s * 8 + c], acc);
    }
    acc += __shfl_xor(acc, 8);  acc += __shfl_xor(acc, 16);  acc += __shfl_xor(acc, 32);
    denom += __shfl_xor(denom, 8); denom += __shfl_xor(denom, 16); denom += __shfl_xor(denom, 32);
    if (l < 8) out[(size_t)wid * 8 + l] = acc / (denom + EPS) + b2[l];
}

// ---------------- launch ----------------

extern "C" void kernel_launch(void* const* d_in, const int* in_sizes, int n_in,
                              void* d_out, int out_size, void* d_ws, size_t ws_size,
                              hipStream_t stream) {
    const float* x        = (const float*)d_in[0];
    const int*   ei       = (const int*)d_in[1];
    const float* ea       = (const float*)d_in[2];
    const float* W1       = (const float*)d_in[3];
    const float* We1      = (const float*)d_in[4];
    const float* att_src1 = (const float*)d_in[5];
    const float* att_dst1 = (const float*)d_in[6];
    const float* att_edge1= (const float*)d_in[7];
    const float* b1       = (const float*)d_in[8];
    const float* W2       = (const float*)d_in[9];
    const float* We2      = (const float*)d_in[10];
    const float* att_src2 = (const float*)d_in[11];
    const float* att_dst2 = (const float*)d_in[12];
    const float* att_edge2= (const float*)d_in[13];
    const float* b2       = (const float*)d_in[14];
    float* out = (float*)d_out;

    const int N = in_sizes[0] / 64;
    const int E = in_sizes[2];
    const int E2 = E + N;
    const int CH = (E + RB - 1) / RB;
    const int NB64 = (N + 63) / 64;
    const int Mpad = NB64 * 64;

    char* p = (char*)d_ws;
    auto alloc = [&](size_t bytes) { void* r = (void*)p; p += (bytes + 255) & ~(size_t)255; return r; };
    int*   cnt      = (int*)  alloc((size_t)N * 4);
    int*   rowptr   = (int*)  alloc((size_t)(N + 1) * 4);
    int*   bsums    = (int*)  alloc((size_t)4096 * 4);
    int*   rank     = (int*)  alloc((size_t)E * 4);
    int*   H        = (int*)  alloc((size_t)RNG * RB * NRR * 4);
    int*   esrc     = (int*)  alloc((size_t)E2 * 4);
    float* eattr    = (float*)alloc((size_t)E2 * 4);
    _Float16* xh    = (_Float16*)alloc((size_t)Mpad * 64 * 2);
    _Float16* Wpk   = (_Float16*)alloc((size_t)8192 * 2);
    __half* h1      = (__half*)alloc((size_t)Mpad * 128 * 2);
    float* asrc1    = (float*)alloc((size_t)N * 8 * 4);
    float* adst1    = (float*)alloc((size_t)N * 8 * 4);
    float* h2       = (float*)alloc((size_t)N * 16 * 4);
    float* hh2      = (float*)alloc((size_t)N * 8 * 4);
    float* asrc2    = (float*)alloc((size_t)N * 4);
    float* adst2    = (float*)alloc((size_t)N * 4);
    float* wed      = (float*)alloc(16 * 4);

    const int nbN = (N + 255) / 256;

    hipLaunchKernelGGL(k_cvtx,      dim3(Mpad / 32), dim3(256), 0, stream, N, Mpad, x, xh);
    hipLaunchKernelGGL(k_prepW,     dim3(1), dim3(256), 0, stream, W1, Wpk);
    hipLaunchKernelGGL(k_wedot,     dim3(1), dim3(64), 0, stream, We1, att_edge1, We2, att_edge2, wed);
    hipLaunchKernelGGL(k_hist,      dim3(RNG * RB), dim3(256), 0, stream, E, CH, ei, H, rank);
    hipLaunchKernelGGL(k_blockscan, dim3(nbN), dim3(256), 0, stream, N, H, cnt);
    hipLaunchKernelGGL(k_scan1,     dim3(nbN), dim3(256), 0, stream, N, cnt, rowptr, bsums);
    hipLaunchKernelGGL(k_scan2,     dim3(1), dim3(256), 0, stream, nbN, N, bsums, rowptr);
    hipLaunchKernelGGL(k_scan3,     dim3(nbN), dim3(256), 0, stream, N, rowptr, bsums);
    hipLaunchKernelGGL(k_scatter,   dim3((E + 255) / 256), dim3(256), 0, stream, E, CH, ei, ea, rowptr, H, rank, esrc, eattr);
    hipLaunchKernelGGL(k_selfloop,  dim3(nbN), dim3(256), 0, stream, N, rowptr, esrc, eattr);
    hipLaunchKernelGGL(k_gemm1m,    dim3(NB64), dim3(256), 0, stream, N, xh, Wpk, att_src1, att_dst1, h1, asrc1, adst1);
    hipLaunchKernelGGL(k_agg1,      dim3((N + 3) / 4), dim3(256), 0, stream, N, rowptr, esrc, eattr, h1, asrc1, adst1, wed, b1, h2);
    hipLaunchKernelGGL(k_gemm2,     dim3(nbN), dim3(256), 0, stream, N, h2, W2, att_src2, att_dst2, hh2, asrc2, adst2);
    hipLaunchKernelGGL(k_agg2,      dim3((N + 3) / 4), dim3(256), 0, stream, N, rowptr, esrc, eattr, hh2, asrc2, adst2, wed, b2, out);
}

// Round 5
// 173.773 us; speedup vs baseline: 2.0431x; 1.0782x over previous
//
#include <hip/hip_runtime.h>
#include <hip/hip_fp16.h>
#include <math.h>

#define LRELU(x) ((x) > 0.0f ? (x) : 0.2f * (x))
#define EPS 1e-16f

typedef _Float16 half8 __attribute__((ext_vector_type(8)));
typedef float floatx4 __attribute__((ext_vector_type(4)));

// CSR-build geometry: 4 dst-ranges x 16384 nodes (64KB LDS histogram),
// 64 edge-chunk blocks per range -> 256 blocks (all CUs).
#define RNG 4
#define NRR 16384
#define RB  64

// ---------------- CSR build (atomic-free at global scope) ----------------

__global__ __launch_bounds__(256) void k_hist(int E, int CH, const int* __restrict__ ei,
                                              int* __restrict__ H, int* __restrict__ rank) {
    int r = blockIdx.x / RB, b = blockIdx.x % RB;
    __shared__ int hist[NRR];
    for (int i = threadIdx.x; i < NRR; i += 256) hist[i] = 0;
    __syncthreads();
    int lo = b * CH, hi = min(E, (b + 1) * CH);
    int rlo = r << 14;
#pragma unroll 4
    for (int e = lo + threadIdx.x; e < hi; e += 256) {
        int d = ei[E + e];
        int dr = d - rlo;
        if ((unsigned)dr < NRR) rank[e] = atomicAdd(&hist[dr], 1);
    }
    __syncthreads();
    int* Hb = H + (size_t)blockIdx.x * NRR;
    for (int i = threadIdx.x; i < NRR; i += 256) Hb[i] = hist[i];
}

// fused: per-node scan of the RB block-histograms (in place) + block-level
// exclusive scan of (cnt+1) into rowptr-local + bsums.
__global__ __launch_bounds__(256) void k_cntscan(int N, int* __restrict__ H,
                                                 int* rowptr, int* bsums) {
    __shared__ int sm[256];
    int t = threadIdx.x;
    int n = blockIdx.x * 256 + t;
    int sum = 0;
    if (n < N) {
        int r = n >> 14, dr = n & (NRR - 1);
        size_t base = ((size_t)(r * RB)) * NRR + dr;
#pragma unroll 8
        for (int b = 0; b < RB; ++b) {
            size_t idx = base + (size_t)b * NRR;
            int v = H[idx];
            H[idx] = sum;
            sum += v;
        }
    }
    int val = (n < N) ? (sum + 1) : 0;   // +1 self loop
    sm[t] = val; __syncthreads();
    for (int ofs = 1; ofs < 256; ofs <<= 1) {
        int v = (t >= ofs) ? sm[t - ofs] : 0;
        __syncthreads();
        sm[t] += v;
        __syncthreads();
    }
    if (n < N) rowptr[n] = sm[t] - val;
    if (t == 255) bsums[blockIdx.x] = sm[255];
}

__global__ void k_scan2(int nb, int N, int* bsums, int* rowptr) {
    __shared__ int sm[256];
    int t = threadIdx.x;
    int v = (t < nb) ? bsums[t] : 0;
    sm[t] = v; __syncthreads();
    for (int ofs = 1; ofs < 256; ofs <<= 1) {
        int u = (t >= ofs) ? sm[t - ofs] : 0;
        __syncthreads();
        sm[t] += u;
        __syncthreads();
    }
    if (t < nb) bsums[t] = sm[t] - v;
    if (t == 255) rowptr[N] = sm[255];
}

__global__ void k_scan3(int N, int* rowptr, const int* __restrict__ bsums) {
    int n = blockIdx.x * blockDim.x + threadIdx.x;
    if (n < N) rowptr[n] += bsums[n >> 8];
}

__global__ void k_scatter(int E, int CH, const int* __restrict__ ei, const float* __restrict__ ea,
                          const int* __restrict__ rowptr, const int* __restrict__ H,
                          const int* __restrict__ rank, int* __restrict__ esrc,
                          float* __restrict__ eattr, int* __restrict__ dstp) {
    int e = blockIdx.x * blockDim.x + threadIdx.x;
    if (e >= E) return;
    int s = ei[e], d = ei[E + e];
    int r = d >> 14, dr = d & (NRR - 1);
    int b = e / CH;
    int pos = rowptr[d] + H[((size_t)(r * RB + b)) * NRR + dr] + rank[e];
    esrc[pos] = s;
    eattr[pos] = ea[e];
    dstp[pos] = d;
}

// ---------------- fused misc: selfloop fill + x->fp16 + W1 pack + wed dots ----------------

__global__ __launch_bounds__(256) void k_misc(
    int N, int nbN, int Mpad, const int* __restrict__ rowptr,
    int* __restrict__ esrc, float* __restrict__ eattr, int* __restrict__ dstp,
    const float* __restrict__ x, _Float16* __restrict__ xh,
    const float* __restrict__ W1, _Float16* __restrict__ Wpk,
    const float* __restrict__ We1, const float* __restrict__ ae1,
    const float* __restrict__ We2, const float* __restrict__ ae2,
    float* __restrict__ wed) {
    int bid = blockIdx.x;
    if (bid < nbN) {
        // self-loop: reserved last slot of each segment, mean incoming edge attr
        int d = bid * 256 + threadIdx.x;
        if (d < N) {
            int start = rowptr[d], slot = rowptr[d + 1] - 1;
            float ssum = 0.0f;
            for (int i = start; i < slot; ++i) ssum += eattr[i];
            esrc[slot] = d;
            dstp[slot] = d;
            eattr[slot] = ssum / fmaxf((float)(slot - start), 1.0f);
        }
    } else if (bid < nbN + Mpad / 32) {
        // x -> fp16, zero-padded
        int t = (bid - nbN) * 256 + threadIdx.x;
        int row = t >> 3;
        half8 h;
        if (row < N) {
            const float4* pp = (const float4*)(x + (size_t)t * 8);
            float4 f0 = pp[0], f1 = pp[1];
            h[0] = (_Float16)f0.x; h[1] = (_Float16)f0.y; h[2] = (_Float16)f0.z; h[3] = (_Float16)f0.w;
            h[4] = (_Float16)f1.x; h[5] = (_Float16)f1.y; h[6] = (_Float16)f1.z; h[7] = (_Float16)f1.w;
        } else {
#pragma unroll
            for (int i = 0; i < 8; ++i) h[i] = (_Float16)0.0f;
        }
        *(half8*)(xh + (size_t)t * 8) = h;
    } else {
        // W1 -> MFMA B-fragment order + wed dots
        int t = threadIdx.x;
        for (int i = 0; i < 32; ++i) {
            int idx = i * 256 + t;           // 8192 total
            int j  = idx & 7;
            int lq = (idx >> 3) & 63;
            int ks = (idx >> 9) & 1;
            int ct = idx >> 10;
            int k   = ks * 32 + (lq >> 4) * 8 + j;
            int col = ct * 16 + (lq & 15);
            Wpk[idx] = (_Float16)W1[k * 128 + col];
        }
        if (t < 8) {
            float ssum = 0.0f;
            for (int cc = 0; cc < 16; ++cc) ssum += We1[t * 16 + cc] * ae1[t * 16 + cc];
            wed[t] = ssum;
        }
        if (t == 8) {
            float ssum = 0.0f;
            for (int cc = 0; cc < 8; ++cc) ssum += We2[cc] * ae2[cc];
            wed[8] = ssum;
        }
    }
}

// ---------------- layer 1 dense via MFMA (unchanged) ----------------

#define LDSP 132

__global__ __launch_bounds__(256) void k_gemm1m(
    int N, const _Float16* __restrict__ xh, const _Float16* __restrict__ Wpk,
    const float* __restrict__ att_s, const float* __restrict__ att_d,
    __half* __restrict__ h1, float* __restrict__ asrc, float* __restrict__ adst) {
    __shared__ float hs[4 * 16 * LDSP];
    int tid = threadIdx.x;
    int w = tid >> 6, l = tid & 63;
    int row0 = blockIdx.x * 64 + w * 16;
    int arow = row0 + (l & 15);
    half8 a0 = *(const half8*)(xh + (size_t)arow * 64 + (l >> 4) * 8);
    half8 a1 = *(const half8*)(xh + (size_t)arow * 64 + 32 + (l >> 4) * 8);
    float* base = &hs[w * 16 * LDSP];
    int r0 = (l >> 4) * 4;
#pragma unroll
    for (int ct = 0; ct < 8; ++ct) {
        half8 b0 = *(const half8*)(Wpk + ((ct * 2 + 0) * 64 + l) * 8);
        half8 b1 = *(const half8*)(Wpk + ((ct * 2 + 1) * 64 + l) * 8);
        floatx4 acc = {0.f, 0.f, 0.f, 0.f};
        acc = __builtin_amdgcn_mfma_f32_16x16x32_f16(a0, b0, acc, 0, 0, 0);
        acc = __builtin_amdgcn_mfma_f32_16x16x32_f16(a1, b1, acc, 0, 0, 0);
        int col = ct * 16 + (l & 15);
#pragma unroll
        for (int i = 0; i < 4; ++i)
            base[(r0 + i) * LDSP + col] = acc[i];
    }
    __syncthreads();
    int r = tid >> 2, g = tid & 3;
    int rg = blockIdx.x * 64 + r;
    if (rg >= N) return;
    float v[32];
    const float* rp = &hs[r * LDSP + g * 32];
#pragma unroll
    for (int j = 0; j < 8; ++j) {
        floatx4 t4 = *(const floatx4*)(rp + j * 4);
        v[j * 4 + 0] = t4[0]; v[j * 4 + 1] = t4[1];
        v[j * 4 + 2] = t4[2]; v[j * 4 + 3] = t4[3];
    }
    float vs0 = 0.f, vs1 = 0.f, vd0 = 0.f, vd1 = 0.f;
    const float4* as4 = (const float4*)(att_s + g * 32);
    const float4* ad4 = (const float4*)(att_d + g * 32);
#pragma unroll
    for (int j = 0; j < 4; ++j) {
        float4 a4 = as4[j], d4 = ad4[j];
        vs0 += v[j*4+0]*a4.x + v[j*4+1]*a4.y + v[j*4+2]*a4.z + v[j*4+3]*a4.w;
        vd0 += v[j*4+0]*d4.x + v[j*4+1]*d4.y + v[j*4+2]*d4.z + v[j*4+3]*d4.w;
    }
#pragma unroll
    for (int j = 4; j < 8; ++j) {
        float4 a4 = as4[j], d4 = ad4[j];
        vs1 += v[j*4+0]*a4.x + v[j*4+1]*a4.y + v[j*4+2]*a4.z + v[j*4+3]*a4.w;
        vd1 += v[j*4+0]*d4.x + v[j*4+1]*d4.y + v[j*4+2]*d4.z + v[j*4+3]*d4.w;
    }
    union { __half h[32]; float4 f4[4]; } u;
#pragma unroll
    for (int i = 0; i < 32; ++i) u.h[i] = __float2half(v[i]);
    float4* hp = (float4*)(h1 + (size_t)rg * 128 + g * 32);
#pragma unroll
    for (int j = 0; j < 4; ++j) hp[j] = u.f4[j];
    asrc[rg * 8 + g * 2]     = vs0;
    asrc[rg * 8 + g * 2 + 1] = vs1;
    adst[rg * 8 + g * 2]     = vd0;
    adst[rg * 8 + g * 2 + 1] = vd1;
}

// ---------------- edge-parallel softmax weights, layer 1 ----------------

__global__ void k_pexp1(int M, const int* __restrict__ esrc, const int* __restrict__ dstp,
                        const float* __restrict__ eattr, const float* __restrict__ asrc,
                        const float* __restrict__ adst, const float* __restrict__ wedp,
                        float* __restrict__ pexp) {
    int e = blockIdx.x * blockDim.x + threadIdx.x;
    if (e >= M) return;
    int s = esrc[e], d = dstp[e];
    float w = eattr[e];
    float o[8];
#pragma unroll
    for (int h = 0; h < 8; ++h) {
        float a = asrc[s * 8 + h] + adst[d * 8 + h] + w * wedp[h];
        a = LRELU(a);
        o[h] = __expf(a);
    }
    float4* op = (float4*)(pexp + (size_t)e * 8);
    op[0] = make_float4(o[0], o[1], o[2], o[3]);
    op[1] = make_float4(o[4], o[5], o[6], o[7]);
}

// ---------------- layer 1 aggregation + fused layer-2 dense ----------------
// one wave per node, 4 edges/iter, prefetched, weights precomputed.
// lane l: g=l>>4 edge slot, q=l&15 -> h1 elements q*8..q*8+7 (head q>>1).
// epilogue: head-mean -> relu(h2) -> hh = h2@W2 + attention dots, in-wave.

__global__ __launch_bounds__(256) void k_agg1(
    int N, const int* __restrict__ rowptr, const int* __restrict__ esrc,
    const float* __restrict__ pexp, const __half* __restrict__ h1,
    const float* __restrict__ b1, const float* __restrict__ W2,
    const float* __restrict__ as2w, const float* __restrict__ ad2w,
    float* __restrict__ hh2, float* __restrict__ asrc2, float* __restrict__ adst2) {
    int wid = (blockIdx.x * blockDim.x + threadIdx.x) >> 6;
    if (wid >= N) return;
    int l = threadIdx.x & 63;
    int g = l >> 4, q = l & 15, hq = q >> 1;
    int start = rowptr[wid], end = rowptr[wid + 1];
    float acc[8] = {0.f,0.f,0.f,0.f,0.f,0.f,0.f,0.f};
    float denom = 0.0f;
    int e = start + g;
    int ee = min(e, end - 1);
    int s = esrc[ee];
    float pv = (e < end) ? pexp[(size_t)ee * 8 + hq] : 0.0f;
    for (int base = start; base < end; base += 4) {
        float4 hv = *(const float4*)(h1 + ((size_t)s << 7) + q * 8);   // gather now
        int en = base + 4 + g;                                         // prefetch next
        int een = min(en, end - 1);
        int sn = esrc[een];
        float pn = (en < end) ? pexp[(size_t)een * 8 + hq] : 0.0f;
        denom += pv;
        const _Float16* hp = (const _Float16*)&hv;
#pragma unroll
        for (int k = 0; k < 8; ++k) acc[k] = fmaf(pv, (float)hp[k], acc[k]);
        s = sn; pv = pn;
    }
    // combine the 4 edge groups
#pragma unroll
    for (int k = 0; k < 8; ++k) {
        acc[k] += __shfl_xor(acc[k], 16);
        acc[k] += __shfl_xor(acc[k], 32);
    }
    denom += __shfl_xor(denom, 16);
    denom += __shfl_xor(denom, 32);
    float inv = 1.0f / (denom + EPS);
    // head mean (heads live on l bits 1..3)
    float val[8];
#pragma unroll
    for (int k = 0; k < 8; ++k) {
        float v = acc[k] * inv;
        v += __shfl_xor(v, 2);
        v += __shfl_xor(v, 4);
        v += __shfl_xor(v, 8);
        val[k] = v;
    }
    // fused epilogue: t = relu(mean + b1), hh = t @ W2, att dots
    int par = l & 1;          // which half of the 16 channels this lane holds
    int c = (l >> 1) & 7;     // output channel this lane computes
    float t8[8];
#pragma unroll
    for (int j = 0; j < 8; ++j)
        t8[j] = fmaxf(val[j] * 0.125f + b1[par * 8 + j], 0.0f);
    float partial = 0.0f;
#pragma unroll
    for (int j = 0; j < 8; ++j)
        partial = fmaf(t8[j], W2[(par * 8 + j) * 8 + c], partial);
    float hhc = partial + __shfl_xor(partial, 1);   // sum both halves
    float sdot = hhc * as2w[c];
    float ddot = hhc * ad2w[c];
    sdot += __shfl_xor(sdot, 2); sdot += __shfl_xor(sdot, 4); sdot += __shfl_xor(sdot, 8);
    ddot += __shfl_xor(ddot, 2); ddot += __shfl_xor(ddot, 4); ddot += __shfl_xor(ddot, 8);
    if (l < 16 && par == 0) hh2[(size_t)wid * 8 + c] = hhc;
    if (l == 0) { asrc2[wid] = sdot; adst2[wid] = ddot; }
}

// ---------------- edge-parallel softmax weights, layer 2 ----------------

__global__ void k_pexp2(int M, const int* __restrict__ esrc, const int* __restrict__ dstp,
                        const float* __restrict__ eattr, const float* __restrict__ asrc2,
                        const float* __restrict__ adst2, const float* __restrict__ wedp,
                        float* __restrict__ pexp2) {
    int e = blockIdx.x * blockDim.x + threadIdx.x;
    if (e >= M) return;
    int s = esrc[e], d = dstp[e];
    float a = asrc2[s] + adst2[d] + eattr[e] * wedp[8];
    pexp2[e] = __expf(LRELU(a));
}

// ---------------- layer 2 aggregation: 8 edges/iter, prefetched ----------------

__global__ __launch_bounds__(256) void k_agg2(
    int N, const int* __restrict__ rowptr, const int* __restrict__ esrc,
    const float* __restrict__ pexp2, const float* __restrict__ hh,
    const float* __restrict__ b2, float* __restrict__ out) {
    int wid = (blockIdx.x * blockDim.x + threadIdx.x) >> 6;
    if (wid >= N) return;
    int l = threadIdx.x & 63;
    int eo = l >> 3, c = l & 7;
    int start = rowptr[wid], end = rowptr[wid + 1];
    float acc = 0.0f, denom = 0.0f;
    int e = start + eo;
    int ee = min(e, end - 1);
    int s = esrc[ee];
    float pv = (e < end) ? pexp2[ee] : 0.0f;
    for (int base = start; base < end; base += 8) {
        float hv = hh[(size_t)s * 8 + c];
        int en = base + 8 + eo;
        int een = min(en, end - 1);
        int sn = esrc[een];
        float pn = (en < end) ? pexp2[een] : 0.0f;
        denom += pv;
        acc = fmaf(pv, hv, acc);
        s = sn; pv = pn;
    }
    acc += __shfl_xor(acc, 8);  acc += __shfl_xor(acc, 16);  acc += __shfl_xor(acc, 32);
    denom += __shfl_xor(denom, 8); denom += __shfl_xor(denom, 16); denom += __shfl_xor(denom, 32);
    if (l < 8) out[(size_t)wid * 8 + l] = acc / (denom + EPS) + b2[l];
}

// ---------------- launch ----------------

extern "C" void kernel_launch(void* const* d_in, const int* in_sizes, int n_in,
                              void* d_out, int out_size, void* d_ws, size_t ws_size,
                              hipStream_t stream) {
    const float* x        = (const float*)d_in[0];
    const int*   ei       = (const int*)d_in[1];
    const float* ea       = (const float*)d_in[2];
    const float* W1       = (const float*)d_in[3];
    const float* We1      = (const float*)d_in[4];
    const float* att_src1 = (const float*)d_in[5];
    const float* att_dst1 = (const float*)d_in[6];
    const float* att_edge1= (const float*)d_in[7];
    const float* b1       = (const float*)d_in[8];
    const float* W2       = (const float*)d_in[9];
    const float* We2      = (const float*)d_in[10];
    const float* att_src2 = (const float*)d_in[11];
    const float* att_dst2 = (const float*)d_in[12];
    const float* att_edge2= (const float*)d_in[13];
    const float* b2       = (const float*)d_in[14];
    float* out = (float*)d_out;

    const int N = in_sizes[0] / 64;
    const int E = in_sizes[2];
    const int E2 = E + N;
    const int CH = (E + RB - 1) / RB;
    const int NB64 = (N + 63) / 64;
    const int Mpad = NB64 * 64;

    char* p = (char*)d_ws;
    auto alloc = [&](size_t bytes) { void* r = (void*)p; p += (bytes + 255) & ~(size_t)255; return r; };
    // ---- persistent ----
    int*   rowptr = (int*)  alloc((size_t)(N + 1) * 4);
    int*   bsums  = (int*)  alloc((size_t)4096 * 4);
    int*   esrc   = (int*)  alloc((size_t)E2 * 4);
    float* eattr  = (float*)alloc((size_t)E2 * 4);
    int*   dstp   = (int*)  alloc((size_t)E2 * 4);
    _Float16* Wpk = (_Float16*)alloc((size_t)8192 * 2);
    __half* h1    = (__half*)alloc((size_t)Mpad * 128 * 2);
    float* asrc1  = (float*)alloc((size_t)N * 8 * 4);
    float* adst1  = (float*)alloc((size_t)N * 8 * 4);
    float* hh2    = (float*)alloc((size_t)N * 8 * 4);
    float* asrc2  = (float*)alloc((size_t)N * 4);
    float* adst2  = (float*)alloc((size_t)N * 4);
    float* wed    = (float*)alloc(16 * 4);
    // ---- phase-aliased scratch (sequential lifetimes) ----
    char* pS = p;
    int*   rank  = (int*)pS;                                          // CSR phase
    int*   H     = (int*)(pS + (((size_t)E * 4 + 255) & ~(size_t)255)); // CSR phase
    _Float16* xh = (_Float16*)pS;                                     // gemm phase
    float* pexp1 = (float*)pS;                                        // agg1 phase (27MB)
    float* pexp2 = (float*)pS;                                        // agg2 phase (aliases pexp1)

    const int nbN = (N + 255) / 256;

    hipLaunchKernelGGL(k_hist,    dim3(RNG * RB), dim3(256), 0, stream, E, CH, ei, H, rank);
    hipLaunchKernelGGL(k_cntscan, dim3(nbN), dim3(256), 0, stream, N, H, rowptr, bsums);
    hipLaunchKernelGGL(k_scan2,   dim3(1), dim3(256), 0, stream, nbN, N, bsums, rowptr);
    hipLaunchKernelGGL(k_scan3,   dim3(nbN), dim3(256), 0, stream, N, rowptr, bsums);
    hipLaunchKernelGGL(k_scatter, dim3((E + 255) / 256), dim3(256), 0, stream, E, CH, ei, ea, rowptr, H, rank, esrc, eattr, dstp);
    hipLaunchKernelGGL(k_misc,    dim3(nbN + Mpad / 32 + 1), dim3(256), 0, stream, N, nbN, Mpad, rowptr,
                       esrc, eattr, dstp, x, xh, W1, Wpk, We1, att_edge1, We2, att_edge2, wed);
    hipLaunchKernelGGL(k_gemm1m,  dim3(NB64), dim3(256), 0, stream, N, xh, Wpk, att_src1, att_dst1, h1, asrc1, adst1);
    hipLaunchKernelGGL(k_pexp1,   dim3((E2 + 255) / 256), dim3(256), 0, stream, E2, esrc, dstp, eattr, asrc1, adst1, wed, pexp1);
    hipLaunchKernelGGL(k_agg1,    dim3((N + 3) / 4), dim3(256), 0, stream, N, rowptr, esrc, pexp1, h1, b1, W2, att_src2, att_dst2, hh2, asrc2, adst2);
    hipLaunchKernelGGL(k_pexp2,   dim3((E2 + 255) / 256), dim3(256), 0, stream, E2, esrc, dstp, eattr, asrc2, adst2, wed, pexp2);
    hipLaunchKernelGGL(k_agg2,    dim3((N + 3) / 4), dim3(256), 0, stream, N, rowptr, esrc, pexp2, hh2, b2, out);
}

// Round 6
// 162.541 us; speedup vs baseline: 2.1842x; 1.0691x over previous
//
#include <hip/hip_runtime.h>
#include <hip/hip_fp16.h>
#include <math.h>

#define LRELU(x) ((x) > 0.0f ? (x) : 0.2f * (x))
#define EPS 1e-16f

typedef _Float16 half8 __attribute__((ext_vector_type(8)));
typedef float floatx4 __attribute__((ext_vector_type(4)));

// CSR-build geometry: 4 dst-ranges x 16384 nodes (64KB LDS histogram),
// 64 edge-chunk blocks per range -> 256 blocks (all CUs).
#define RNG 4
#define NRR 16384
#define RB  64

// ---------------- CSR build (atomic-free at global scope) ----------------

__global__ __launch_bounds__(256) void k_hist(int E, int CH, const int* __restrict__ ei,
                                              int* __restrict__ H, int* __restrict__ rank) {
    int r = blockIdx.x / RB, b = blockIdx.x % RB;
    __shared__ int hist[NRR];
    for (int i = threadIdx.x; i < NRR; i += 256) hist[i] = 0;
    __syncthreads();
    int lo = b * CH, hi = min(E, (b + 1) * CH);
    int rlo = r << 14;
#pragma unroll 4
    for (int e = lo + threadIdx.x; e < hi; e += 256) {
        int d = ei[E + e];
        int dr = d - rlo;
        if ((unsigned)dr < NRR) rank[e] = atomicAdd(&hist[dr], 1);
    }
    __syncthreads();
    int* Hb = H + (size_t)blockIdx.x * NRR;
    for (int i = threadIdx.x; i < NRR; i += 256) Hb[i] = hist[i];
}

// fused: per-node scan of the RB block-histograms (in place) + block-level
// exclusive scan of (cnt+1) into rowptr-local + bsums.
__global__ __launch_bounds__(256) void k_cntscan(int N, int* __restrict__ H,
                                                 int* rowptr, int* bsums) {
    __shared__ int sm[256];
    int t = threadIdx.x;
    int n = blockIdx.x * 256 + t;
    int sum = 0;
    if (n < N) {
        int r = n >> 14, dr = n & (NRR - 1);
        size_t base = ((size_t)(r * RB)) * NRR + dr;
#pragma unroll 8
        for (int b = 0; b < RB; ++b) {
            size_t idx = base + (size_t)b * NRR;
            int v = H[idx];
            H[idx] = sum;
            sum += v;
        }
    }
    int val = (n < N) ? (sum + 1) : 0;   // +1 self loop
    sm[t] = val; __syncthreads();
    for (int ofs = 1; ofs < 256; ofs <<= 1) {
        int v = (t >= ofs) ? sm[t - ofs] : 0;
        __syncthreads();
        sm[t] += v;
        __syncthreads();
    }
    if (n < N) rowptr[n] = sm[t] - val;
    if (t == 255) bsums[blockIdx.x] = sm[255];
}

__global__ void k_scan2(int nb, int N, int* bsums, int* rowptr) {
    __shared__ int sm[256];
    int t = threadIdx.x;
    int v = (t < nb) ? bsums[t] : 0;
    sm[t] = v; __syncthreads();
    for (int ofs = 1; ofs < 256; ofs <<= 1) {
        int u = (t >= ofs) ? sm[t - ofs] : 0;
        __syncthreads();
        sm[t] += u;
        __syncthreads();
    }
    if (t < nb) bsums[t] = sm[t] - v;
    if (t == 255) rowptr[N] = sm[255];
}

__global__ void k_scan3(int N, int* rowptr, const int* __restrict__ bsums) {
    int n = blockIdx.x * blockDim.x + threadIdx.x;
    if (n < N) rowptr[n] += bsums[n >> 8];
}

// one packed 8B scattered store per edge: rec = {src, attr_bits}
__global__ void k_scatter(int E, int CH, const int* __restrict__ ei, const float* __restrict__ ea,
                          const int* __restrict__ rowptr, const int* __restrict__ H,
                          const int* __restrict__ rank, int2* __restrict__ rec) {
    int e = blockIdx.x * blockDim.x + threadIdx.x;
    if (e >= E) return;
    int s = ei[e], d = ei[E + e];
    int r = d >> 14, dr = d & (NRR - 1);
    int b = e / CH;
    int pos = rowptr[d] + H[((size_t)(r * RB + b)) * NRR + dr] + rank[e];
    rec[pos] = make_int2(s, __float_as_int(ea[e]));
}

// ---------------- fused misc: selfloop fill + x->fp16 + W1 pack + wed dots ----------------

__global__ __launch_bounds__(256) void k_misc(
    int N, int nbN, int Mpad, const int* __restrict__ rowptr, int2* __restrict__ rec,
    const float* __restrict__ x, _Float16* __restrict__ xh,
    const float* __restrict__ W1, _Float16* __restrict__ Wpk,
    const float* __restrict__ We1, const float* __restrict__ ae1,
    const float* __restrict__ We2, const float* __restrict__ ae2,
    float* __restrict__ wed) {
    int bid = blockIdx.x;
    if (bid < nbN) {
        // self-loop: reserved last slot of each segment, mean incoming edge attr
        int d = bid * 256 + threadIdx.x;
        if (d < N) {
            int start = rowptr[d], slot = rowptr[d + 1] - 1;
            float ssum = 0.0f;
            for (int i = start; i < slot; ++i) ssum += __int_as_float(rec[i].y);
            float mean = ssum / fmaxf((float)(slot - start), 1.0f);
            rec[slot] = make_int2(d, __float_as_int(mean));
        }
    } else if (bid < nbN + Mpad / 32) {
        // x -> fp16, zero-padded
        int t = (bid - nbN) * 256 + threadIdx.x;
        int row = t >> 3;
        half8 h;
        if (row < N) {
            const float4* pp = (const float4*)(x + (size_t)t * 8);
            float4 f0 = pp[0], f1 = pp[1];
            h[0] = (_Float16)f0.x; h[1] = (_Float16)f0.y; h[2] = (_Float16)f0.z; h[3] = (_Float16)f0.w;
            h[4] = (_Float16)f1.x; h[5] = (_Float16)f1.y; h[6] = (_Float16)f1.z; h[7] = (_Float16)f1.w;
        } else {
#pragma unroll
            for (int i = 0; i < 8; ++i) h[i] = (_Float16)0.0f;
        }
        *(half8*)(xh + (size_t)t * 8) = h;
    } else {
        // W1 -> MFMA B-fragment order + wed dots
        int t = threadIdx.x;
        for (int i = 0; i < 32; ++i) {
            int idx = i * 256 + t;           // 8192 total
            int j  = idx & 7;
            int lq = (idx >> 3) & 63;
            int ks = (idx >> 9) & 1;
            int ct = idx >> 10;
            int k   = ks * 32 + (lq >> 4) * 8 + j;
            int col = ct * 16 + (lq & 15);
            Wpk[idx] = (_Float16)W1[k * 128 + col];
        }
        if (t < 8) {
            float ssum = 0.0f;
            for (int cc = 0; cc < 16; ++cc) ssum += We1[t * 16 + cc] * ae1[t * 16 + cc];
            wed[t] = ssum;
        }
        if (t == 8) {
            float ssum = 0.0f;
            for (int cc = 0; cc < 8; ++cc) ssum += We2[cc] * ae2[cc];
            wed[8] = ssum;
        }
    }
}

// ---------------- layer 1 dense via MFMA ----------------

#define LDSP 132

__global__ __launch_bounds__(256) void k_gemm1m(
    int N, const _Float16* __restrict__ xh, const _Float16* __restrict__ Wpk,
    const float* __restrict__ att_s, const float* __restrict__ att_d,
    __half* __restrict__ h1, float* __restrict__ asrc, float* __restrict__ adst) {
    __shared__ float hs[4 * 16 * LDSP];
    int tid = threadIdx.x;
    int w = tid >> 6, l = tid & 63;
    int row0 = blockIdx.x * 64 + w * 16;
    int arow = row0 + (l & 15);
    half8 a0 = *(const half8*)(xh + (size_t)arow * 64 + (l >> 4) * 8);
    half8 a1 = *(const half8*)(xh + (size_t)arow * 64 + 32 + (l >> 4) * 8);
    float* base = &hs[w * 16 * LDSP];
    int r0 = (l >> 4) * 4;
#pragma unroll
    for (int ct = 0; ct < 8; ++ct) {
        half8 b0 = *(const half8*)(Wpk + ((ct * 2 + 0) * 64 + l) * 8);
        half8 b1 = *(const half8*)(Wpk + ((ct * 2 + 1) * 64 + l) * 8);
        floatx4 acc = {0.f, 0.f, 0.f, 0.f};
        acc = __builtin_amdgcn_mfma_f32_16x16x32_f16(a0, b0, acc, 0, 0, 0);
        acc = __builtin_amdgcn_mfma_f32_16x16x32_f16(a1, b1, acc, 0, 0, 0);
        int col = ct * 16 + (l & 15);
#pragma unroll
        for (int i = 0; i < 4; ++i)
            base[(r0 + i) * LDSP + col] = acc[i];
    }
    __syncthreads();
    int r = tid >> 2, g = tid & 3;
    int rg = blockIdx.x * 64 + r;
    if (rg >= N) return;
    float v[32];
    const float* rp = &hs[r * LDSP + g * 32];
#pragma unroll
    for (int j = 0; j < 8; ++j) {
        floatx4 t4 = *(const floatx4*)(rp + j * 4);
        v[j * 4 + 0] = t4[0]; v[j * 4 + 1] = t4[1];
        v[j * 4 + 2] = t4[2]; v[j * 4 + 3] = t4[3];
    }
    float vs0 = 0.f, vs1 = 0.f, vd0 = 0.f, vd1 = 0.f;
    const float4* as4 = (const float4*)(att_s + g * 32);
    const float4* ad4 = (const float4*)(att_d + g * 32);
#pragma unroll
    for (int j = 0; j < 4; ++j) {
        float4 a4 = as4[j], d4 = ad4[j];
        vs0 += v[j*4+0]*a4.x + v[j*4+1]*a4.y + v[j*4+2]*a4.z + v[j*4+3]*a4.w;
        vd0 += v[j*4+0]*d4.x + v[j*4+1]*d4.y + v[j*4+2]*d4.z + v[j*4+3]*d4.w;
    }
#pragma unroll
    for (int j = 4; j < 8; ++j) {
        float4 a4 = as4[j], d4 = ad4[j];
        vs1 += v[j*4+0]*a4.x + v[j*4+1]*a4.y + v[j*4+2]*a4.z + v[j*4+3]*a4.w;
        vd1 += v[j*4+0]*d4.x + v[j*4+1]*d4.y + v[j*4+2]*d4.z + v[j*4+3]*d4.w;
    }
    union { __half h[32]; float4 f4[4]; } u;
#pragma unroll
    for (int i = 0; i < 32; ++i) u.h[i] = __float2half(v[i]);
    float4* hp = (float4*)(h1 + (size_t)rg * 128 + g * 32);
#pragma unroll
    for (int j = 0; j < 4; ++j) hp[j] = u.f4[j];
    asrc[rg * 8 + g * 2]     = vs0;
    asrc[rg * 8 + g * 2 + 1] = vs1;
    adst[rg * 8 + g * 2]     = vd0;
    adst[rg * 8 + g * 2 + 1] = vd1;
}

// ---------------- layer 1: fused pexp (phase 0) + aggregation + layer-2 dense ----------------
// one wave per node.
// phase 0: lane = (edge slot l>>3, head l&7) computes p=exp(lrelu(...)) -> pexp[e*8+h]
//          (coalesced 256B stores per 8 edges; d == wid implicit).
// phase 1: lane = (edge slot l>>4, elem q=l&15) gathers h1 rows, weights by pexp (L1/L2-hot).
// epilogue: head-mean -> relu -> hh = t @ W2 + attention dots, in-wave.

__global__ __launch_bounds__(256) void k_agg1(
    int N, const int* __restrict__ rowptr, const int2* __restrict__ rec,
    const float* __restrict__ asrc1, const float* __restrict__ adst1,
    const float* __restrict__ wed, float* __restrict__ pexp,
    const __half* __restrict__ h1, const float* __restrict__ b1,
    const float* __restrict__ W2, const float* __restrict__ as2w, const float* __restrict__ ad2w,
    float* __restrict__ hh2, float* __restrict__ asrc2, float* __restrict__ adst2) {
    int wid = (blockIdx.x * blockDim.x + threadIdx.x) >> 6;
    if (wid >= N) return;
    int l = threadIdx.x & 63;
    int start = rowptr[wid], end = rowptr[wid + 1];

    // ---- phase 0: softmax weights for this segment ----
    {
        int eo = l >> 3, h = l & 7;
        float adn = adst1[wid * 8 + h];
        float wdh = wed[h];
        for (int base = start; base < end; base += 8) {
            int e = base + eo;
            if (e < end) {
                int2 rv = rec[e];
                float a = asrc1[rv.x * 8 + h] + adn + __int_as_float(rv.y) * wdh;
                pexp[(size_t)e * 8 + h] = __expf(LRELU(a));
            }
        }
    }
    asm volatile("s_waitcnt vmcnt(0)" ::: "memory");

    // ---- phase 1: weighted gather ----
    int g = l >> 4, q = l & 15, hq = q >> 1;
    float acc[8] = {0.f,0.f,0.f,0.f,0.f,0.f,0.f,0.f};
    float denom = 0.0f;
    int e = start + g;
    int ee = min(e, end - 1);
    int s = rec[ee].x;
    float pv = (e < end) ? pexp[(size_t)ee * 8 + hq] : 0.0f;
    for (int base = start; base < end; base += 4) {
        float4 hv = *(const float4*)(h1 + ((size_t)s << 7) + q * 8);   // gather now
        int en = base + 4 + g;                                         // prefetch next
        int een = min(en, end - 1);
        int sn = rec[een].x;
        float pn = (en < end) ? pexp[(size_t)een * 8 + hq] : 0.0f;
        denom += pv;
        const _Float16* hp = (const _Float16*)&hv;
#pragma unroll
        for (int k = 0; k < 8; ++k) acc[k] = fmaf(pv, (float)hp[k], acc[k]);
        s = sn; pv = pn;
    }
    // combine the 4 edge groups
#pragma unroll
    for (int k = 0; k < 8; ++k) {
        acc[k] += __shfl_xor(acc[k], 16);
        acc[k] += __shfl_xor(acc[k], 32);
    }
    denom += __shfl_xor(denom, 16);
    denom += __shfl_xor(denom, 32);
    float inv = 1.0f / (denom + EPS);
    // head mean (heads live on l bits 1..3)
    float val[8];
#pragma unroll
    for (int k = 0; k < 8; ++k) {
        float v = acc[k] * inv;
        v += __shfl_xor(v, 2);
        v += __shfl_xor(v, 4);
        v += __shfl_xor(v, 8);
        val[k] = v;
    }
    // fused epilogue: t = relu(mean + b1), hh = t @ W2, att dots
    int par = l & 1;
    int c = (l >> 1) & 7;
    float t8[8];
#pragma unroll
    for (int j = 0; j < 8; ++j)
        t8[j] = fmaxf(val[j] * 0.125f + b1[par * 8 + j], 0.0f);
    float partial = 0.0f;
#pragma unroll
    for (int j = 0; j < 8; ++j)
        partial = fmaf(t8[j], W2[(par * 8 + j) * 8 + c], partial);
    float hhc = partial + __shfl_xor(partial, 1);
    float sdot = hhc * as2w[c];
    float ddot = hhc * ad2w[c];
    sdot += __shfl_xor(sdot, 2); sdot += __shfl_xor(sdot, 4); sdot += __shfl_xor(sdot, 8);
    ddot += __shfl_xor(ddot, 2); ddot += __shfl_xor(ddot, 4); ddot += __shfl_xor(ddot, 8);
    if (l < 16 && par == 0) hh2[(size_t)wid * 8 + c] = hhc;
    if (l == 0) { asrc2[wid] = sdot; adst2[wid] = ddot; }
}

// ---------------- layer 2: fused pexp (phase 0) + aggregation ----------------

__global__ __launch_bounds__(256) void k_agg2(
    int N, const int* __restrict__ rowptr, const int2* __restrict__ rec,
    const float* __restrict__ asrc2, const float* __restrict__ adst2,
    const float* __restrict__ wed, float* __restrict__ pexp2,
    const float* __restrict__ hh, const float* __restrict__ b2, float* __restrict__ out) {
    int wid = (blockIdx.x * blockDim.x + threadIdx.x) >> 6;
    if (wid >= N) return;
    int l = threadIdx.x & 63;
    int start = rowptr[wid], end = rowptr[wid + 1];

    // ---- phase 0 ----
    {
        float adn = adst2[wid];
        float w2 = wed[8];
        for (int base = start; base < end; base += 64) {
            int e = base + l;
            if (e < end) {
                int2 rv = rec[e];
                float a = asrc2[rv.x] + adn + __int_as_float(rv.y) * w2;
                pexp2[e] = __expf(LRELU(a));
            }
        }
    }
    asm volatile("s_waitcnt vmcnt(0)" ::: "memory");

    // ---- phase 1: 8 edges/iter, prefetched ----
    int eo = l >> 3, c = l & 7;
    float acc = 0.0f, denom = 0.0f;
    int e = start + eo;
    int ee = min(e, end - 1);
    int s = rec[ee].x;
    float pv = (e < end) ? pexp2[ee] : 0.0f;
    for (int base = start; base < end; base += 8) {
        float hv = hh[(size_t)s * 8 + c];
        int en = base + 8 + eo;
        int een = min(en, end - 1);
        int sn = rec[een].x;
        float pn = (en < end) ? pexp2[een] : 0.0f;
        denom += pv;
        acc = fmaf(pv, hv, acc);
        s = sn; pv = pn;
    }
    acc += __shfl_xor(acc, 8);  acc += __shfl_xor(acc, 16);  acc += __shfl_xor(acc, 32);
    denom += __shfl_xor(denom, 8); denom += __shfl_xor(denom, 16); denom += __shfl_xor(denom, 32);
    if (l < 8) out[(size_t)wid * 8 + l] = acc / (denom + EPS) + b2[l];
}

// ---------------- launch ----------------

extern "C" void kernel_launch(void* const* d_in, const int* in_sizes, int n_in,
                              void* d_out, int out_size, void* d_ws, size_t ws_size,
                              hipStream_t stream) {
    const float* x        = (const float*)d_in[0];
    const int*   ei       = (const int*)d_in[1];
    const float* ea       = (const float*)d_in[2];
    const float* W1       = (const float*)d_in[3];
    const float* We1      = (const float*)d_in[4];
    const float* att_src1 = (const float*)d_in[5];
    const float* att_dst1 = (const float*)d_in[6];
    const float* att_edge1= (const float*)d_in[7];
    const float* b1       = (const float*)d_in[8];
    const float* W2       = (const float*)d_in[9];
    const float* We2      = (const float*)d_in[10];
    const float* att_src2 = (const float*)d_in[11];
    const float* att_dst2 = (const float*)d_in[12];
    const float* att_edge2= (const float*)d_in[13];
    const float* b2       = (const float*)d_in[14];
    float* out = (float*)d_out;

    const int N = in_sizes[0] / 64;
    const int E = in_sizes[2];
    const int E2 = E + N;
    const int CH = (E + RB - 1) / RB;
    const int NB64 = (N + 63) / 64;
    const int Mpad = NB64 * 64;

    char* p = (char*)d_ws;
    auto alloc = [&](size_t bytes) { void* r = (void*)p; p += (bytes + 255) & ~(size_t)255; return r; };
    // ---- persistent ----
    int*   rowptr = (int*)  alloc((size_t)(N + 1) * 4);
    int*   bsums  = (int*)  alloc((size_t)4096 * 4);
    int2*  rec    = (int2*) alloc((size_t)E2 * 8);
    _Float16* Wpk = (_Float16*)alloc((size_t)8192 * 2);
    __half* h1    = (__half*)alloc((size_t)Mpad * 128 * 2);
    float* asrc1  = (float*)alloc((size_t)N * 8 * 4);
    float* adst1  = (float*)alloc((size_t)N * 8 * 4);
    float* hh2    = (float*)alloc((size_t)N * 8 * 4);
    float* asrc2  = (float*)alloc((size_t)N * 4);
    float* adst2  = (float*)alloc((size_t)N * 4);
    float* wed    = (float*)alloc(16 * 4);
    // ---- phase-aliased scratch (sequential lifetimes) ----
    char* pS = p;
    int*   rank  = (int*)pS;                                            // CSR phase
    int*   H     = (int*)(pS + (((size_t)E * 4 + 255) & ~(size_t)255)); // CSR phase
    _Float16* xh = (_Float16*)pS;                                       // gemm phase
    float* pexp1 = (float*)pS;                                          // agg1 phase (27MB)
    float* pexp2 = (float*)pS;                                          // agg2 phase

    const int nbN = (N + 255) / 256;

    hipLaunchKernelGGL(k_hist,    dim3(RNG * RB), dim3(256), 0, stream, E, CH, ei, H, rank);
    hipLaunchKernelGGL(k_cntscan, dim3(nbN), dim3(256), 0, stream, N, H, rowptr, bsums);
    hipLaunchKernelGGL(k_scan2,   dim3(1), dim3(256), 0, stream, nbN, N, bsums, rowptr);
    hipLaunchKernelGGL(k_scan3,   dim3(nbN), dim3(256), 0, stream, N, rowptr, bsums);
    hipLaunchKernelGGL(k_scatter, dim3((E + 255) / 256), dim3(256), 0, stream, E, CH, ei, ea, rowptr, H, rank, rec);
    hipLaunchKernelGGL(k_misc,    dim3(nbN + Mpad / 32 + 1), dim3(256), 0, stream, N, nbN, Mpad, rowptr,
                       rec, x, xh, W1, Wpk, We1, att_edge1, We2, att_edge2, wed);
    hipLaunchKernelGGL(k_gemm1m,  dim3(NB64), dim3(256), 0, stream, N, xh, Wpk, att_src1, att_dst1, h1, asrc1, adst1);
    hipLaunchKernelGGL(k_agg1,    dim3((N + 3) / 4), dim3(256), 0, stream, N, rowptr, rec, asrc1, adst1, wed, pexp1,
                       h1, b1, W2, att_src2, att_dst2, hh2, asrc2, adst2);
    hipLaunchKernelGGL(k_agg2,    dim3((N + 3) / 4), dim3(256), 0, stream, N, rowptr, rec, asrc2, adst2, wed, pexp2,
                       hh2, b2, out);
}

// Round 7
// 156.821 us; speedup vs baseline: 2.2639x; 1.0365x over previous
//
#include <hip/hip_runtime.h>
#include <hip/hip_fp16.h>
#include <math.h>

#define LRELU(x) ((x) > 0.0f ? (x) : 0.2f * (x))
#define EPS 1e-16f

typedef _Float16 half8 __attribute__((ext_vector_type(8)));
typedef float floatx4 __attribute__((ext_vector_type(4)));

// CSR-build geometry: 4 dst-ranges x 16384 nodes (64KB LDS histogram),
// 64 edge-chunk blocks per range -> 256 blocks (all CUs).
#define RNG 4
#define NRR 16384
#define RB  64

// ---------------- CSR build (atomic-free at global scope) ----------------

__global__ __launch_bounds__(256) void k_hist(int E, int CH, const int* __restrict__ ei,
                                              int* __restrict__ H, int* __restrict__ rank) {
    int r = blockIdx.x / RB, b = blockIdx.x % RB;
    __shared__ int hist[NRR];
    for (int i = threadIdx.x; i < NRR; i += 256) hist[i] = 0;
    __syncthreads();
    int lo = b * CH, hi = min(E, (b + 1) * CH);
    int rlo = r << 14;
#pragma unroll 4
    for (int e = lo + threadIdx.x; e < hi; e += 256) {
        int d = ei[E + e];
        int dr = d - rlo;
        if ((unsigned)dr < NRR) rank[e] = atomicAdd(&hist[dr], 1);
    }
    __syncthreads();
    int* Hb = H + (size_t)blockIdx.x * NRR;
    for (int i = threadIdx.x; i < NRR; i += 256) Hb[i] = hist[i];
}

// fused: per-node scan of the RB block-histograms (in place) + block-level
// exclusive scan of (cnt+1) into rowptr-local + bsums.
__global__ __launch_bounds__(256) void k_cntscan(int N, int* __restrict__ H,
                                                 int* rowptr, int* bsums) {
    __shared__ int sm[256];
    int t = threadIdx.x;
    int n = blockIdx.x * 256 + t;
    int sum = 0;
    if (n < N) {
        int r = n >> 14, dr = n & (NRR - 1);
        size_t base = ((size_t)(r * RB)) * NRR + dr;
#pragma unroll 8
        for (int b = 0; b < RB; ++b) {
            size_t idx = base + (size_t)b * NRR;
            int v = H[idx];
            H[idx] = sum;
            sum += v;
        }
    }
    int val = (n < N) ? (sum + 1) : 0;   // +1 self loop
    sm[t] = val; __syncthreads();
    for (int ofs = 1; ofs < 256; ofs <<= 1) {
        int v = (t >= ofs) ? sm[t - ofs] : 0;
        __syncthreads();
        sm[t] += v;
        __syncthreads();
    }
    if (n < N) rowptr[n] = sm[t] - val;
    if (t == 255) bsums[blockIdx.x] = sm[255];
}

__global__ void k_scan2(int nb, int N, int* bsums, int* rowptr) {
    __shared__ int sm[256];
    int t = threadIdx.x;
    int v = (t < nb) ? bsums[t] : 0;
    sm[t] = v; __syncthreads();
    for (int ofs = 1; ofs < 256; ofs <<= 1) {
        int u = (t >= ofs) ? sm[t - ofs] : 0;
        __syncthreads();
        sm[t] += u;
        __syncthreads();
    }
    if (t < nb) bsums[t] = sm[t] - v;
    if (t == 255) rowptr[N] = sm[255];
}

__global__ void k_scan3(int N, int* rowptr, const int* __restrict__ bsums) {
    int n = blockIdx.x * blockDim.x + threadIdx.x;
    if (n < N) rowptr[n] += bsums[n >> 8];
}

// one packed 8B scattered store per edge: rec = {src, attr_bits}
__global__ void k_scatter(int E, int CH, const int* __restrict__ ei, const float* __restrict__ ea,
                          const int* __restrict__ rowptr, const int* __restrict__ H,
                          const int* __restrict__ rank, int2* __restrict__ rec) {
    int e = blockIdx.x * blockDim.x + threadIdx.x;
    if (e >= E) return;
    int s = ei[e], d = ei[E + e];
    int r = d >> 14, dr = d & (NRR - 1);
    int b = e / CH;
    int pos = rowptr[d] + H[((size_t)(r * RB + b)) * NRR + dr] + rank[e];
    unsigned long long pk = ((unsigned long long)(unsigned)__float_as_int(ea[e]) << 32)
                          | (unsigned long long)(unsigned)s;
    __builtin_nontemporal_store(pk, (unsigned long long*)&rec[pos]);
}

// ---------------- fused misc: selfloop fill + x->fp16 + W1 pack + wed dots ----------------

__global__ __launch_bounds__(256) void k_misc(
    int N, int nbN, int Mpad, const int* __restrict__ rowptr, int2* __restrict__ rec,
    const float* __restrict__ x, _Float16* __restrict__ xh,
    const float* __restrict__ W1, _Float16* __restrict__ Wpk,
    const float* __restrict__ We1, const float* __restrict__ ae1,
    const float* __restrict__ We2, const float* __restrict__ ae2,
    float* __restrict__ wed) {
    int bid = blockIdx.x;
    if (bid < nbN) {
        // self-loop: reserved last slot of each segment, mean incoming edge attr
        int d = bid * 256 + threadIdx.x;
        if (d < N) {
            int start = rowptr[d], slot = rowptr[d + 1] - 1;
            float ssum = 0.0f;
            for (int i = start; i < slot; ++i) ssum += __int_as_float(rec[i].y);
            float mean = ssum / fmaxf((float)(slot - start), 1.0f);
            rec[slot] = make_int2(d, __float_as_int(mean));
        }
    } else if (bid < nbN + Mpad / 32) {
        // x -> fp16, zero-padded
        int t = (bid - nbN) * 256 + threadIdx.x;
        int row = t >> 3;
        half8 h;
        if (row < N) {
            const float4* pp = (const float4*)(x + (size_t)t * 8);
            float4 f0 = pp[0], f1 = pp[1];
            h[0] = (_Float16)f0.x; h[1] = (_Float16)f0.y; h[2] = (_Float16)f0.z; h[3] = (_Float16)f0.w;
            h[4] = (_Float16)f1.x; h[5] = (_Float16)f1.y; h[6] = (_Float16)f1.z; h[7] = (_Float16)f1.w;
        } else {
#pragma unroll
            for (int i = 0; i < 8; ++i) h[i] = (_Float16)0.0f;
        }
        *(half8*)(xh + (size_t)t * 8) = h;
    } else {
        // W1 -> MFMA B-fragment order + wed dots
        int t = threadIdx.x;
        for (int i = 0; i < 32; ++i) {
            int idx = i * 256 + t;           // 8192 total
            int j  = idx & 7;
            int lq = (idx >> 3) & 63;
            int ks = (idx >> 9) & 1;
            int ct = idx >> 10;
            int k   = ks * 32 + (lq >> 4) * 8 + j;
            int col = ct * 16 + (lq & 15);
            Wpk[idx] = (_Float16)W1[k * 128 + col];
        }
        if (t < 8) {
            float ssum = 0.0f;
            for (int cc = 0; cc < 16; ++cc) ssum += We1[t * 16 + cc] * ae1[t * 16 + cc];
            wed[t] = ssum;
        }
        if (t == 8) {
            float ssum = 0.0f;
            for (int cc = 0; cc < 8; ++cc) ssum += We2[cc] * ae2[cc];
            wed[8] = ssum;
        }
    }
}

// ---------------- layer 1 dense via MFMA ----------------

#define LDSP 132

__global__ __launch_bounds__(256) void k_gemm1m(
    int N, const _Float16* __restrict__ xh, const _Float16* __restrict__ Wpk,
    const float* __restrict__ att_s, const float* __restrict__ att_d,
    __half* __restrict__ h1, float* __restrict__ asrc, float* __restrict__ adst) {
    __shared__ float hs[4 * 16 * LDSP];
    int tid = threadIdx.x;
    int w = tid >> 6, l = tid & 63;
    int row0 = blockIdx.x * 64 + w * 16;
    int arow = row0 + (l & 15);
    half8 a0 = *(const half8*)(xh + (size_t)arow * 64 + (l >> 4) * 8);
    half8 a1 = *(const half8*)(xh + (size_t)arow * 64 + 32 + (l >> 4) * 8);
    float* base = &hs[w * 16 * LDSP];
    int r0 = (l >> 4) * 4;
#pragma unroll
    for (int ct = 0; ct < 8; ++ct) {
        half8 b0 = *(const half8*)(Wpk + ((ct * 2 + 0) * 64 + l) * 8);
        half8 b1 = *(const half8*)(Wpk + ((ct * 2 + 1) * 64 + l) * 8);
        floatx4 acc = {0.f, 0.f, 0.f, 0.f};
        acc = __builtin_amdgcn_mfma_f32_16x16x32_f16(a0, b0, acc, 0, 0, 0);
        acc = __builtin_amdgcn_mfma_f32_16x16x32_f16(a1, b1, acc, 0, 0, 0);
        int col = ct * 16 + (l & 15);
#pragma unroll
        for (int i = 0; i < 4; ++i)
            base[(r0 + i) * LDSP + col] = acc[i];
    }
    __syncthreads();
    int r = tid >> 2, g = tid & 3;
    int rg = blockIdx.x * 64 + r;
    if (rg >= N) return;
    float v[32];
    const float* rp = &hs[r * LDSP + g * 32];
#pragma unroll
    for (int j = 0; j < 8; ++j) {
        floatx4 t4 = *(const floatx4*)(rp + j * 4);
        v[j * 4 + 0] = t4[0]; v[j * 4 + 1] = t4[1];
        v[j * 4 + 2] = t4[2]; v[j * 4 + 3] = t4[3];
    }
    float vs0 = 0.f, vs1 = 0.f, vd0 = 0.f, vd1 = 0.f;
    const float4* as4 = (const float4*)(att_s + g * 32);
    const float4* ad4 = (const float4*)(att_d + g * 32);
#pragma unroll
    for (int j = 0; j < 4; ++j) {
        float4 a4 = as4[j], d4 = ad4[j];
        vs0 += v[j*4+0]*a4.x + v[j*4+1]*a4.y + v[j*4+2]*a4.z + v[j*4+3]*a4.w;
        vd0 += v[j*4+0]*d4.x + v[j*4+1]*d4.y + v[j*4+2]*d4.z + v[j*4+3]*d4.w;
    }
#pragma unroll
    for (int j = 4; j < 8; ++j) {
        float4 a4 = as4[j], d4 = ad4[j];
        vs1 += v[j*4+0]*a4.x + v[j*4+1]*a4.y + v[j*4+2]*a4.z + v[j*4+3]*a4.w;
        vd1 += v[j*4+0]*d4.x + v[j*4+1]*d4.y + v[j*4+2]*d4.z + v[j*4+3]*d4.w;
    }
    union { __half h[32]; float4 f4[4]; } u;
#pragma unroll
    for (int i = 0; i < 32; ++i) u.h[i] = __float2half(v[i]);
    float4* hp = (float4*)(h1 + (size_t)rg * 128 + g * 32);
#pragma unroll
    for (int j = 0; j < 4; ++j) hp[j] = u.f4[j];
    asrc[rg * 8 + g * 2]     = vs0;
    asrc[rg * 8 + g * 2 + 1] = vs1;
    adst[rg * 8 + g * 2]     = vd0;
    adst[rg * 8 + g * 2 + 1] = vd1;
}

// ---------------- layer 1 aggregation (inline p) + fused layer-2 dense ----------------
// one wave per node, 4 edges/iter. lane l: g=l>>4 edge slot, q=l&15 ->
// h1 elements q*8..q*8+7 (head hq=q>>1). p computed in-register:
// asrc1[s*8+hq] gather (L2-hot) + reg-resident adst1/wed; exp 2x-redundant.
// pipeline: h1 gather uses prev-iter s; next rec/asrc1 issued before exp.

__global__ __launch_bounds__(256) void k_agg1(
    int N, const int* __restrict__ rowptr, const int2* __restrict__ rec,
    const float* __restrict__ asrc1, const float* __restrict__ adst1,
    const float* __restrict__ wed,
    const __half* __restrict__ h1, const float* __restrict__ b1,
    const float* __restrict__ W2, const float* __restrict__ as2w, const float* __restrict__ ad2w,
    float* __restrict__ hh2, float* __restrict__ asrc2, float* __restrict__ adst2) {
    int wid = (blockIdx.x * blockDim.x + threadIdx.x) >> 6;
    if (wid >= N) return;
    int l = threadIdx.x & 63;
    int g = l >> 4, q = l & 15, hq = q >> 1;
    int start = rowptr[wid], end = rowptr[wid + 1];
    float adn = adst1[wid * 8 + hq];
    float wdh = wed[hq];

    float acc[8] = {0.f,0.f,0.f,0.f,0.f,0.f,0.f,0.f};
    float denom = 0.0f;
    int e = start + g;
    int ee = min(e, end - 1);
    int2 rv = rec[ee];
    float av = asrc1[rv.x * 8 + hq];
    for (int base = start; base < end; base += 4) {
        float4 hv = *(const float4*)(h1 + ((size_t)rv.x << 7) + q * 8);  // gather now
        float w = __int_as_float(rv.y);
        int en = base + 4 + g;                                           // prefetch next
        int een = min(en, end - 1);
        int2 rn = rec[een];
        float an = asrc1[rn.x * 8 + hq];
        // p for current edge (av loaded an iteration ago -> no stall)
        float a = av + adn + w * wdh;
        a = LRELU(a);
        float p = (base + g < end) ? __expf(a) : 0.0f;
        denom += p;
        const _Float16* hp = (const _Float16*)&hv;
#pragma unroll
        for (int k = 0; k < 8; ++k) acc[k] = fmaf(p, (float)hp[k], acc[k]);
        rv = rn; av = an;
    }
    // combine the 4 edge groups
#pragma unroll
    for (int k = 0; k < 8; ++k) {
        acc[k] += __shfl_xor(acc[k], 16);
        acc[k] += __shfl_xor(acc[k], 32);
    }
    denom += __shfl_xor(denom, 16);
    denom += __shfl_xor(denom, 32);
    float inv = 1.0f / (denom + EPS);
    // head mean (heads live on l bits 1..3)
    float val[8];
#pragma unroll
    for (int k = 0; k < 8; ++k) {
        float v = acc[k] * inv;
        v += __shfl_xor(v, 2);
        v += __shfl_xor(v, 4);
        v += __shfl_xor(v, 8);
        val[k] = v;
    }
    // fused epilogue: t = relu(mean + b1), hh = t @ W2, att dots
    int par = l & 1;
    int c = (l >> 1) & 7;
    float t8[8];
#pragma unroll
    for (int j = 0; j < 8; ++j)
        t8[j] = fmaxf(val[j] * 0.125f + b1[par * 8 + j], 0.0f);
    float partial = 0.0f;
#pragma unroll
    for (int j = 0; j < 8; ++j)
        partial = fmaf(t8[j], W2[(par * 8 + j) * 8 + c], partial);
    float hhc = partial + __shfl_xor(partial, 1);
    float sdot = hhc * as2w[c];
    float ddot = hhc * ad2w[c];
    sdot += __shfl_xor(sdot, 2); sdot += __shfl_xor(sdot, 4); sdot += __shfl_xor(sdot, 8);
    ddot += __shfl_xor(ddot, 2); ddot += __shfl_xor(ddot, 4); ddot += __shfl_xor(ddot, 8);
    if (l < 16 && par == 0) hh2[(size_t)wid * 8 + c] = hhc;
    if (l == 0) { asrc2[wid] = sdot; adst2[wid] = ddot; }
}

// ---------------- layer 2 aggregation (inline p): 8 edges/iter, prefetched ----------------

__global__ __launch_bounds__(256) void k_agg2(
    int N, const int* __restrict__ rowptr, const int2* __restrict__ rec,
    const float* __restrict__ asrc2, const float* __restrict__ adst2,
    const float* __restrict__ wed,
    const float* __restrict__ hh, const float* __restrict__ b2, float* __restrict__ out) {
    int wid = (blockIdx.x * blockDim.x + threadIdx.x) >> 6;
    if (wid >= N) return;
    int l = threadIdx.x & 63;
    int eo = l >> 3, c = l & 7;
    int start = rowptr[wid], end = rowptr[wid + 1];
    float adn = adst2[wid];
    float w2 = wed[8];

    float acc = 0.0f, denom = 0.0f;
    int e = start + eo;
    int ee = min(e, end - 1);
    int2 rv = rec[ee];
    float av = asrc2[rv.x];
    for (int base = start; base < end; base += 8) {
        float hv = hh[(size_t)rv.x * 8 + c];
        float w = __int_as_float(rv.y);
        int en = base + 8 + eo;
        int een = min(en, end - 1);
        int2 rn = rec[een];
        float an = asrc2[rn.x];
        float a = av + adn + w * w2;
        a = LRELU(a);
        float p = (base + eo < end) ? __expf(a) : 0.0f;
        denom += p;
        acc = fmaf(p, hv, acc);
        rv = rn; av = an;
    }
    acc += __shfl_xor(acc, 8);  acc += __shfl_xor(acc, 16);  acc += __shfl_xor(acc, 32);
    denom += __shfl_xor(denom, 8); denom += __shfl_xor(denom, 16); denom += __shfl_xor(denom, 32);
    if (l < 8) out[(size_t)wid * 8 + l] = acc / (denom + EPS) + b2[l];
}

// ---------------- launch ----------------

extern "C" void kernel_launch(void* const* d_in, const int* in_sizes, int n_in,
                              void* d_out, int out_size, void* d_ws, size_t ws_size,
                              hipStream_t stream) {
    const float* x        = (const float*)d_in[0];
    const int*   ei       = (const int*)d_in[1];
    const float* ea       = (const float*)d_in[2];
    const float* W1       = (const float*)d_in[3];
    const float* We1      = (const float*)d_in[4];
    const float* att_src1 = (const float*)d_in[5];
    const float* att_dst1 = (const float*)d_in[6];
    const float* att_edge1= (const float*)d_in[7];
    const float* b1       = (const float*)d_in[8];
    const float* W2       = (const float*)d_in[9];
    const float* We2      = (const float*)d_in[10];
    const float* att_src2 = (const float*)d_in[11];
    const float* att_dst2 = (const float*)d_in[12];
    const float* att_edge2= (const float*)d_in[13];
    const float* b2       = (const float*)d_in[14];
    float* out = (float*)d_out;

    const int N = in_sizes[0] / 64;
    const int E = in_sizes[2];
    const int E2 = E + N;
    const int CH = (E + RB - 1) / RB;
    const int NB64 = (N + 63) / 64;
    const int Mpad = NB64 * 64;

    char* p = (char*)d_ws;
    auto alloc = [&](size_t bytes) { void* r = (void*)p; p += (bytes + 255) & ~(size_t)255; return r; };
    // ---- persistent ----
    int*   rowptr = (int*)  alloc((size_t)(N + 1) * 4);
    int*   bsums  = (int*)  alloc((size_t)4096 * 4);
    int2*  rec    = (int2*) alloc((size_t)E2 * 8);
    _Float16* Wpk = (_Float16*)alloc((size_t)8192 * 2);
    __half* h1    = (__half*)alloc((size_t)Mpad * 128 * 2);
    float* asrc1  = (float*)alloc((size_t)N * 8 * 4);
    float* adst1  = (float*)alloc((size_t)N * 8 * 4);
    float* hh2    = (float*)alloc((size_t)N * 8 * 4);
    float* asrc2  = (float*)alloc((size_t)N * 4);
    float* adst2  = (float*)alloc((size_t)N * 4);
    float* wed    = (float*)alloc(16 * 4);
    // ---- phase-aliased scratch (sequential lifetimes) ----
    char* pS = p;
    int*   rank  = (int*)pS;                                            // CSR phase
    int*   H     = (int*)(pS + (((size_t)E * 4 + 255) & ~(size_t)255)); // CSR phase
    _Float16* xh = (_Float16*)pS;                                       // gemm phase

    const int nbN = (N + 255) / 256;

    hipLaunchKernelGGL(k_hist,    dim3(RNG * RB), dim3(256), 0, stream, E, CH, ei, H, rank);
    hipLaunchKernelGGL(k_cntscan, dim3(nbN), dim3(256), 0, stream, N, H, rowptr, bsums);
    hipLaunchKernelGGL(k_scan2,   dim3(1), dim3(256), 0, stream, nbN, N, bsums, rowptr);
    hipLaunchKernelGGL(k_scan3,   dim3(nbN), dim3(256), 0, stream, N, rowptr, bsums);
    hipLaunchKernelGGL(k_scatter, dim3((E + 255) / 256), dim3(256), 0, stream, E, CH, ei, ea, rowptr, H, rank, rec);
    hipLaunchKernelGGL(k_misc,    dim3(nbN + Mpad / 32 + 1), dim3(256), 0, stream, N, nbN, Mpad, rowptr,
                       rec, x, xh, W1, Wpk, We1, att_edge1, We2, att_edge2, wed);
    hipLaunchKernelGGL(k_gemm1m,  dim3(NB64), dim3(256), 0, stream, N, xh, Wpk, att_src1, att_dst1, h1, asrc1, adst1);
    hipLaunchKernelGGL(k_agg1,    dim3((N + 3) / 4), dim3(256), 0, stream, N, rowptr, rec, asrc1, adst1, wed,
                       h1, b1, W2, att_src2, att_dst2, hh2, asrc2, adst2);
    hipLaunchKernelGGL(k_agg2,    dim3((N + 3) / 4), dim3(256), 0, stream, N, rowptr, rec, asrc2, adst2, wed,
                       hh2, b2, out);
}

// Round 8
// 151.146 us; speedup vs baseline: 2.3489x; 1.0375x over previous
//
#include <hip/hip_runtime.h>
#include <hip/hip_fp16.h>
#include <math.h>

#define LRELU(x) ((x) > 0.0f ? (x) : 0.2f * (x))
#define EPS 1e-16f

typedef _Float16 half8 __attribute__((ext_vector_type(8)));
typedef float floatx4 __attribute__((ext_vector_type(4)));

// CSR-build geometry: 4 dst-ranges x 16384 nodes (64KB LDS histogram),
// 64 edge-chunk blocks per range -> 256 blocks (all CUs).
#define RNG 4
#define NRR 16384
#define RB  64

// ---------------- CSR build (atomic-free at global scope) ----------------

__global__ __launch_bounds__(256) void k_hist(int E, int CH, const int* __restrict__ ei,
                                              int* __restrict__ H, int* __restrict__ rank) {
    int r = blockIdx.x / RB, b = blockIdx.x % RB;
    __shared__ int hist[NRR];
    for (int i = threadIdx.x; i < NRR; i += 256) hist[i] = 0;
    __syncthreads();
    int lo = b * CH, hi = min(E, (b + 1) * CH);
    int rlo = r << 14;
#pragma unroll 4
    for (int e = lo + threadIdx.x; e < hi; e += 256) {
        int d = ei[E + e];
        int dr = d - rlo;
        if ((unsigned)dr < NRR) rank[e] = atomicAdd(&hist[dr], 1);
    }
    __syncthreads();
    int* Hb = H + (size_t)blockIdx.x * NRR;
    for (int i = threadIdx.x; i < NRR; i += 256) Hb[i] = hist[i];
}

// fused: per-node scan of the RB block-histograms (in place) + block-level
// exclusive scan of (cnt+1) into rowptr-local + bsums.
__global__ __launch_bounds__(256) void k_cntscan(int N, int* __restrict__ H,
                                                 int* rowptr, int* bsums) {
    __shared__ int sm[256];
    int t = threadIdx.x;
    int n = blockIdx.x * 256 + t;
    int sum = 0;
    if (n < N) {
        int r = n >> 14, dr = n & (NRR - 1);
        size_t base = ((size_t)(r * RB)) * NRR + dr;
#pragma unroll 8
        for (int b = 0; b < RB; ++b) {
            size_t idx = base + (size_t)b * NRR;
            int v = H[idx];
            H[idx] = sum;
            sum += v;
        }
    }
    int val = (n < N) ? (sum + 1) : 0;   // +1 self loop
    sm[t] = val; __syncthreads();
    for (int ofs = 1; ofs < 256; ofs <<= 1) {
        int v = (t >= ofs) ? sm[t - ofs] : 0;
        __syncthreads();
        sm[t] += v;
        __syncthreads();
    }
    if (n < N) rowptr[n] = sm[t] - val;
    if (t == 255) bsums[blockIdx.x] = sm[255];
}

__global__ void k_scan2(int nb, int N, int* bsums, int* rowptr) {
    __shared__ int sm[256];
    int t = threadIdx.x;
    int v = (t < nb) ? bsums[t] : 0;
    sm[t] = v; __syncthreads();
    for (int ofs = 1; ofs < 256; ofs <<= 1) {
        int u = (t >= ofs) ? sm[t - ofs] : 0;
        __syncthreads();
        sm[t] += u;
        __syncthreads();
    }
    if (t < nb) bsums[t] = sm[t] - v;
    if (t == 255) rowptr[N] = sm[255];
}

__global__ void k_scan3(int N, int* rowptr, const int* __restrict__ bsums) {
    int n = blockIdx.x * blockDim.x + threadIdx.x;
    if (n < N) rowptr[n] += bsums[n >> 8];
}

// one packed 8B scattered store per edge: rec = {src, attr_bits}
__global__ void k_scatter(int E, int CH, const int* __restrict__ ei, const float* __restrict__ ea,
                          const int* __restrict__ rowptr, const int* __restrict__ H,
                          const int* __restrict__ rank, int2* __restrict__ rec) {
    int e = blockIdx.x * blockDim.x + threadIdx.x;
    if (e >= E) return;
    int s = ei[e], d = ei[E + e];
    int r = d >> 14, dr = d & (NRR - 1);
    int b = e / CH;
    int pos = rowptr[d] + H[((size_t)(r * RB + b)) * NRR + dr] + rank[e];
    unsigned long long pk = ((unsigned long long)(unsigned)__float_as_int(ea[e]) << 32)
                          | (unsigned long long)(unsigned)s;
    __builtin_nontemporal_store(pk, (unsigned long long*)&rec[pos]);
}

// ---------------- fused misc: selfloop fill + x->fp16 + W1 pack + wed dots ----------------

__global__ __launch_bounds__(256) void k_misc(
    int N, int nbN, int Mpad, const int* __restrict__ rowptr, int2* __restrict__ rec,
    const float* __restrict__ x, _Float16* __restrict__ xh,
    const float* __restrict__ W1, _Float16* __restrict__ Wpk,
    const float* __restrict__ We1, const float* __restrict__ ae1,
    const float* __restrict__ We2, const float* __restrict__ ae2,
    float* __restrict__ wed) {
    int bid = blockIdx.x;
    if (bid < nbN) {
        // self-loop: reserved last slot of each segment, mean incoming edge attr
        int d = bid * 256 + threadIdx.x;
        if (d < N) {
            int start = rowptr[d], slot = rowptr[d + 1] - 1;
            float ssum = 0.0f;
            for (int i = start; i < slot; ++i) ssum += __int_as_float(rec[i].y);
            float mean = ssum / fmaxf((float)(slot - start), 1.0f);
            rec[slot] = make_int2(d, __float_as_int(mean));
        }
    } else if (bid < nbN + Mpad / 32) {
        // x -> fp16, zero-padded
        int t = (bid - nbN) * 256 + threadIdx.x;
        int row = t >> 3;
        half8 h;
        if (row < N) {
            const float4* pp = (const float4*)(x + (size_t)t * 8);
            float4 f0 = pp[0], f1 = pp[1];
            h[0] = (_Float16)f0.x; h[1] = (_Float16)f0.y; h[2] = (_Float16)f0.z; h[3] = (_Float16)f0.w;
            h[4] = (_Float16)f1.x; h[5] = (_Float16)f1.y; h[6] = (_Float16)f1.z; h[7] = (_Float16)f1.w;
        } else {
#pragma unroll
            for (int i = 0; i < 8; ++i) h[i] = (_Float16)0.0f;
        }
        *(half8*)(xh + (size_t)t * 8) = h;
    } else {
        // W1 -> MFMA B-fragment order + wed dots
        int t = threadIdx.x;
        for (int i = 0; i < 32; ++i) {
            int idx = i * 256 + t;           // 8192 total
            int j  = idx & 7;
            int lq = (idx >> 3) & 63;
            int ks = (idx >> 9) & 1;
            int ct = idx >> 10;
            int k   = ks * 32 + (lq >> 4) * 8 + j;
            int col = ct * 16 + (lq & 15);
            Wpk[idx] = (_Float16)W1[k * 128 + col];
        }
        if (t < 8) {
            float ssum = 0.0f;
            for (int cc = 0; cc < 16; ++cc) ssum += We1[t * 16 + cc] * ae1[t * 16 + cc];
            wed[t] = ssum;
        }
        if (t == 8) {
            float ssum = 0.0f;
            for (int cc = 0; cc < 8; ++cc) ssum += We2[cc] * ae2[cc];
            wed[8] = ssum;
        }
    }
}

// ---------------- layer 1 dense via MFMA ----------------

#define LDSP 132

__global__ __launch_bounds__(256) void k_gemm1m(
    int N, const _Float16* __restrict__ xh, const _Float16* __restrict__ Wpk,
    const float* __restrict__ att_s, const float* __restrict__ att_d,
    __half* __restrict__ h1, float* __restrict__ asrc, float* __restrict__ adst) {
    __shared__ float hs[4 * 16 * LDSP];
    int tid = threadIdx.x;
    int w = tid >> 6, l = tid & 63;
    int row0 = blockIdx.x * 64 + w * 16;
    int arow = row0 + (l & 15);
    half8 a0 = *(const half8*)(xh + (size_t)arow * 64 + (l >> 4) * 8);
    half8 a1 = *(const half8*)(xh + (size_t)arow * 64 + 32 + (l >> 4) * 8);
    float* base = &hs[w * 16 * LDSP];
    int r0 = (l >> 4) * 4;
#pragma unroll
    for (int ct = 0; ct < 8; ++ct) {
        half8 b0 = *(const half8*)(Wpk + ((ct * 2 + 0) * 64 + l) * 8);
        half8 b1 = *(const half8*)(Wpk + ((ct * 2 + 1) * 64 + l) * 8);
        floatx4 acc = {0.f, 0.f, 0.f, 0.f};
        acc = __builtin_amdgcn_mfma_f32_16x16x32_f16(a0, b0, acc, 0, 0, 0);
        acc = __builtin_amdgcn_mfma_f32_16x16x32_f16(a1, b1, acc, 0, 0, 0);
        int col = ct * 16 + (l & 15);
#pragma unroll
        for (int i = 0; i < 4; ++i)
            base[(r0 + i) * LDSP + col] = acc[i];
    }
    __syncthreads();
    int r = tid >> 2, g = tid & 3;
    int rg = blockIdx.x * 64 + r;
    if (rg >= N) return;
    float v[32];
    const float* rp = &hs[r * LDSP + g * 32];
#pragma unroll
    for (int j = 0; j < 8; ++j) {
        floatx4 t4 = *(const floatx4*)(rp + j * 4);
        v[j * 4 + 0] = t4[0]; v[j * 4 + 1] = t4[1];
        v[j * 4 + 2] = t4[2]; v[j * 4 + 3] = t4[3];
    }
    float vs0 = 0.f, vs1 = 0.f, vd0 = 0.f, vd1 = 0.f;
    const float4* as4 = (const float4*)(att_s + g * 32);
    const float4* ad4 = (const float4*)(att_d + g * 32);
#pragma unroll
    for (int j = 0; j < 4; ++j) {
        float4 a4 = as4[j], d4 = ad4[j];
        vs0 += v[j*4+0]*a4.x + v[j*4+1]*a4.y + v[j*4+2]*a4.z + v[j*4+3]*a4.w;
        vd0 += v[j*4+0]*d4.x + v[j*4+1]*d4.y + v[j*4+2]*d4.z + v[j*4+3]*d4.w;
    }
#pragma unroll
    for (int j = 4; j < 8; ++j) {
        float4 a4 = as4[j], d4 = ad4[j];
        vs1 += v[j*4+0]*a4.x + v[j*4+1]*a4.y + v[j*4+2]*a4.z + v[j*4+3]*a4.w;
        vd1 += v[j*4+0]*d4.x + v[j*4+1]*d4.y + v[j*4+2]*d4.z + v[j*4+3]*d4.w;
    }
    union { __half h[32]; float4 f4[4]; } u;
#pragma unroll
    for (int i = 0; i < 32; ++i) u.h[i] = __float2half(v[i]);
    float4* hp = (float4*)(h1 + (size_t)rg * 128 + g * 32);
#pragma unroll
    for (int j = 0; j < 4; ++j) hp[j] = u.f4[j];
    asrc[rg * 8 + g * 2]     = vs0;
    asrc[rg * 8 + g * 2 + 1] = vs1;
    adst[rg * 8 + g * 2]     = vd0;
    adst[rg * 8 + g * 2 + 1] = vd1;
}

// ---------------- layer 1 aggregation (inline p, TWO streams) + fused layer-2 dense ----
// one wave per node. lane l: g=l>>4 edge slot, q=l&15 -> h1 elems q*8..q*8+7 (head q>>1).
// segment split into two independent 4-edge-group streams -> 2x outstanding h1
// gathers per wave (MLP). Clamped tails produce p=0 with safe loads.

__global__ __launch_bounds__(256) void k_agg1(
    int N, const int* __restrict__ rowptr, const int2* __restrict__ rec,
    const float* __restrict__ asrc1, const float* __restrict__ adst1,
    const float* __restrict__ wed,
    const __half* __restrict__ h1, const float* __restrict__ b1,
    const float* __restrict__ W2, const float* __restrict__ as2w, const float* __restrict__ ad2w,
    float* __restrict__ hh2, float* __restrict__ asrc2, float* __restrict__ adst2) {
    int wid = (blockIdx.x * blockDim.x + threadIdx.x) >> 6;
    if (wid >= N) return;
    int l = threadIdx.x & 63;
    int g = l >> 4, q = l & 15, hq = q >> 1;
    int start = rowptr[wid], end = rowptr[wid + 1];
    int len = end - start;
    int G = (len + 3) >> 2;          // 4-edge groups
    int nIt = (G + 1) >> 1;          // stream A gets ceil(G/2) groups
    int startB = start + (nIt << 2);
    int endA = min(startB, end);
    float adn = adst1[wid * 8 + hq];
    float wdh = wed[hq];

    float acc[8] = {0.f,0.f,0.f,0.f,0.f,0.f,0.f,0.f};
    float denom = 0.0f;
    int eA = start + g, eB = startB + g;
    int last = end - 1;
    int2 rvA = rec[min(eA, last)];
    int2 rvB = rec[min(eB, last)];
    float avA = asrc1[rvA.x * 8 + hq];
    float avB = asrc1[rvB.x * 8 + hq];
    for (int it = 0; it < nIt; ++it) {
        float4 hvA = *(const float4*)(h1 + ((size_t)rvA.x << 7) + q * 8);
        float4 hvB = *(const float4*)(h1 + ((size_t)rvB.x << 7) + q * 8);
        int eAn = eA + 4, eBn = eB + 4;
        int2 rnA = rec[min(eAn, last)];
        int2 rnB = rec[min(eBn, last)];
        float anA = asrc1[rnA.x * 8 + hq];
        float anB = asrc1[rnB.x * 8 + hq];
        float aA = avA + adn + __int_as_float(rvA.y) * wdh;
        aA = LRELU(aA);
        float pA = (eA < endA) ? __expf(aA) : 0.0f;
        float aB = avB + adn + __int_as_float(rvB.y) * wdh;
        aB = LRELU(aB);
        float pB = (eB < end) ? __expf(aB) : 0.0f;
        denom += pA + pB;
        const _Float16* hpA = (const _Float16*)&hvA;
        const _Float16* hpB = (const _Float16*)&hvB;
#pragma unroll
        for (int k = 0; k < 8; ++k)
            acc[k] = fmaf(pA, (float)hpA[k], fmaf(pB, (float)hpB[k], acc[k]));
        rvA = rnA; avA = anA; rvB = rnB; avB = anB;
        eA = eAn; eB = eBn;
    }
    // combine the 4 edge groups
#pragma unroll
    for (int k = 0; k < 8; ++k) {
        acc[k] += __shfl_xor(acc[k], 16);
        acc[k] += __shfl_xor(acc[k], 32);
    }
    denom += __shfl_xor(denom, 16);
    denom += __shfl_xor(denom, 32);
    float inv = 1.0f / (denom + EPS);
    // head mean (heads live on l bits 1..3)
    float val[8];
#pragma unroll
    for (int k = 0; k < 8; ++k) {
        float v = acc[k] * inv;
        v += __shfl_xor(v, 2);
        v += __shfl_xor(v, 4);
        v += __shfl_xor(v, 8);
        val[k] = v;
    }
    // fused epilogue: t = relu(mean + b1), hh = t @ W2, att dots
    int par = l & 1;
    int c = (l >> 1) & 7;
    float t8[8];
#pragma unroll
    for (int j = 0; j < 8; ++j)
        t8[j] = fmaxf(val[j] * 0.125f + b1[par * 8 + j], 0.0f);
    float partial = 0.0f;
#pragma unroll
    for (int j = 0; j < 8; ++j)
        partial = fmaf(t8[j], W2[(par * 8 + j) * 8 + c], partial);
    float hhc = partial + __shfl_xor(partial, 1);
    float sdot = hhc * as2w[c];
    float ddot = hhc * ad2w[c];
    sdot += __shfl_xor(sdot, 2); sdot += __shfl_xor(sdot, 4); sdot += __shfl_xor(sdot, 8);
    ddot += __shfl_xor(ddot, 2); ddot += __shfl_xor(ddot, 4); ddot += __shfl_xor(ddot, 8);
    if (l < 16 && par == 0) hh2[(size_t)wid * 8 + c] = hhc;
    if (l == 0) { asrc2[wid] = sdot; adst2[wid] = ddot; }
}

// ---------------- layer 2 aggregation (inline p, TWO streams) ----------------

__global__ __launch_bounds__(256) void k_agg2(
    int N, const int* __restrict__ rowptr, const int2* __restrict__ rec,
    const float* __restrict__ asrc2, const float* __restrict__ adst2,
    const float* __restrict__ wed,
    const float* __restrict__ hh, const float* __restrict__ b2, float* __restrict__ out) {
    int wid = (blockIdx.x * blockDim.x + threadIdx.x) >> 6;
    if (wid >= N) return;
    int l = threadIdx.x & 63;
    int eo = l >> 3, c = l & 7;
    int start = rowptr[wid], end = rowptr[wid + 1];
    int len = end - start;
    int G = (len + 7) >> 3;          // 8-edge groups
    int nIt = (G + 1) >> 1;
    int startB = start + (nIt << 3);
    int endA = min(startB, end);
    float adn = adst2[wid];
    float w2 = wed[8];

    float acc = 0.0f, denom = 0.0f;
    int eA = start + eo, eB = startB + eo;
    int last = end - 1;
    int2 rvA = rec[min(eA, last)];
    int2 rvB = rec[min(eB, last)];
    float avA = asrc2[rvA.x];
    float avB = asrc2[rvB.x];
    for (int it = 0; it < nIt; ++it) {
        float hvA = hh[(size_t)rvA.x * 8 + c];
        float hvB = hh[(size_t)rvB.x * 8 + c];
        int eAn = eA + 8, eBn = eB + 8;
        int2 rnA = rec[min(eAn, last)];
        int2 rnB = rec[min(eBn, last)];
        float anA = asrc2[rnA.x];
        float anB = asrc2[rnB.x];
        float aA = avA + adn + __int_as_float(rvA.y) * w2;
        aA = LRELU(aA);
        float pA = (eA < endA) ? __expf(aA) : 0.0f;
        float aB = avB + adn + __int_as_float(rvB.y) * w2;
        aB = LRELU(aB);
        float pB = (eB < end) ? __expf(aB) : 0.0f;
        denom += pA + pB;
        acc = fmaf(pA, hvA, fmaf(pB, hvB, acc));
        rvA = rnA; avA = anA; rvB = rnB; avB = anB;
        eA = eAn; eB = eBn;
    }
    acc += __shfl_xor(acc, 8);  acc += __shfl_xor(acc, 16);  acc += __shfl_xor(acc, 32);
    denom += __shfl_xor(denom, 8); denom += __shfl_xor(denom, 16); denom += __shfl_xor(denom, 32);
    if (l < 8) out[(size_t)wid * 8 + l] = acc / (denom + EPS) + b2[l];
}

// ---------------- launch ----------------

extern "C" void kernel_launch(void* const* d_in, const int* in_sizes, int n_in,
                              void* d_out, int out_size, void* d_ws, size_t ws_size,
                              hipStream_t stream) {
    const float* x        = (const float*)d_in[0];
    const int*   ei       = (const int*)d_in[1];
    const float* ea       = (const float*)d_in[2];
    const float* W1       = (const float*)d_in[3];
    const float* We1      = (const float*)d_in[4];
    const float* att_src1 = (const float*)d_in[5];
    const float* att_dst1 = (const float*)d_in[6];
    const float* att_edge1= (const float*)d_in[7];
    const float* b1       = (const float*)d_in[8];
    const float* W2       = (const float*)d_in[9];
    const float* We2      = (const float*)d_in[10];
    const float* att_src2 = (const float*)d_in[11];
    const float* att_dst2 = (const float*)d_in[12];
    const float* att_edge2= (const float*)d_in[13];
    const float* b2       = (const float*)d_in[14];
    float* out = (float*)d_out;

    const int N = in_sizes[0] / 64;
    const int E = in_sizes[2];
    const int E2 = E + N;
    const int CH = (E + RB - 1) / RB;
    const int NB64 = (N + 63) / 64;
    const int Mpad = NB64 * 64;

    char* p = (char*)d_ws;
    auto alloc = [&](size_t bytes) { void* r = (void*)p; p += (bytes + 255) & ~(size_t)255; return r; };
    // ---- persistent ----
    int*   rowptr = (int*)  alloc((size_t)(N + 1) * 4);
    int*   bsums  = (int*)  alloc((size_t)4096 * 4);
    int2*  rec    = (int2*) alloc((size_t)E2 * 8);
    _Float16* Wpk = (_Float16*)alloc((size_t)8192 * 2);
    __half* h1    = (__half*)alloc((size_t)Mpad * 128 * 2);
    float* asrc1  = (float*)alloc((size_t)N * 8 * 4);
    float* adst1  = (float*)alloc((size_t)N * 8 * 4);
    float* hh2    = (float*)alloc((size_t)N * 8 * 4);
    float* asrc2  = (float*)alloc((size_t)N * 4);
    float* adst2  = (float*)alloc((size_t)N * 4);
    float* wed    = (float*)alloc(16 * 4);
    // ---- phase-aliased scratch (sequential lifetimes) ----
    char* pS = p;
    int*   rank  = (int*)pS;                                            // CSR phase
    int*   H     = (int*)(pS + (((size_t)E * 4 + 255) & ~(size_t)255)); // CSR phase
    _Float16* xh = (_Float16*)pS;                                       // gemm phase

    const int nbN = (N + 255) / 256;

    hipLaunchKernelGGL(k_hist,    dim3(RNG * RB), dim3(256), 0, stream, E, CH, ei, H, rank);
    hipLaunchKernelGGL(k_cntscan, dim3(nbN), dim3(256), 0, stream, N, H, rowptr, bsums);
    hipLaunchKernelGGL(k_scan2,   dim3(1), dim3(256), 0, stream, nbN, N, bsums, rowptr);
    hipLaunchKernelGGL(k_scan3,   dim3(nbN), dim3(256), 0, stream, N, rowptr, bsums);
    hipLaunchKernelGGL(k_scatter, dim3((E + 255) / 256), dim3(256), 0, stream, E, CH, ei, ea, rowptr, H, rank, rec);
    hipLaunchKernelGGL(k_misc,    dim3(nbN + Mpad / 32 + 1), dim3(256), 0, stream, N, nbN, Mpad, rowptr,
                       rec, x, xh, W1, Wpk, We1, att_edge1, We2, att_edge2, wed);
    hipLaunchKernelGGL(k_gemm1m,  dim3(NB64), dim3(256), 0, stream, N, xh, Wpk, att_src1, att_dst1, h1, asrc1, adst1);
    hipLaunchKernelGGL(k_agg1,    dim3((N + 3) / 4), dim3(256), 0, stream, N, rowptr, rec, asrc1, adst1, wed,
                       h1, b1, W2, att_src2, att_dst2, hh2, asrc2, adst2);
    hipLaunchKernelGGL(k_agg2,    dim3((N + 3) / 4), dim3(256), 0, stream, N, rowptr, rec, asrc2, adst2, wed,
                       hh2, b2, out);
}

// Round 9
// 143.715 us; speedup vs baseline: 2.4704x; 1.0517x over previous
//
#include <hip/hip_runtime.h>
#include <hip/hip_fp16.h>
#include <math.h>

#define EPS 1e-16f
#define LOG2E 1.44269504088896340736f

typedef _Float16 half8 __attribute__((ext_vector_type(8)));
typedef float floatx4 __attribute__((ext_vector_type(4)));

// CSR-build geometry: 4 dst-ranges x 16384 nodes (64KB LDS histogram),
// 64 edge-chunk blocks per range -> 256 blocks (all CUs).
#define RNG 4
#define NRR 16384
#define RB  64

// ---------------- CSR build (atomic-free at global scope) ----------------

__global__ __launch_bounds__(256) void k_hist(int E, int CH, const int* __restrict__ ei,
                                              int* __restrict__ H, int* __restrict__ rank) {
    int r = blockIdx.x / RB, b = blockIdx.x % RB;
    __shared__ int hist[NRR];
    for (int i = threadIdx.x; i < NRR; i += 256) hist[i] = 0;
    __syncthreads();
    int lo = b * CH, hi = min(E, (b + 1) * CH);
    int rlo = r << 14;
#pragma unroll 4
    for (int e = lo + threadIdx.x; e < hi; e += 256) {
        int d = ei[E + e];
        int dr = d - rlo;
        if ((unsigned)dr < NRR) rank[e] = atomicAdd(&hist[dr], 1);
    }
    __syncthreads();
    int* Hb = H + (size_t)blockIdx.x * NRR;
    for (int i = threadIdx.x; i < NRR; i += 256) Hb[i] = hist[i];
}

// fused: per-node scan of the RB block-histograms (in place) + block-level
// exclusive scan of (cnt+1) into rowptr-local + bsums.
__global__ __launch_bounds__(256) void k_cntscan(int N, int* __restrict__ H,
                                                 int* rowptr, int* bsums) {
    __shared__ int sm[256];
    int t = threadIdx.x;
    int n = blockIdx.x * 256 + t;
    int sum = 0;
    if (n < N) {
        int r = n >> 14, dr = n & (NRR - 1);
        size_t base = ((size_t)(r * RB)) * NRR + dr;
#pragma unroll 8
        for (int b = 0; b < RB; ++b) {
            size_t idx = base + (size_t)b * NRR;
            int v = H[idx];
            H[idx] = sum;
            sum += v;
        }
    }
    int val = (n < N) ? (sum + 1) : 0;   // +1 self loop
    sm[t] = val; __syncthreads();
    for (int ofs = 1; ofs < 256; ofs <<= 1) {
        int v = (t >= ofs) ? sm[t - ofs] : 0;
        __syncthreads();
        sm[t] += v;
        __syncthreads();
    }
    if (n < N) rowptr[n] = sm[t] - val;
    if (t == 255) bsums[blockIdx.x] = sm[255];
}

__global__ void k_scan2(int nb, int N, int* bsums, int* rowptr) {
    __shared__ int sm[256];
    int t = threadIdx.x;
    int v = (t < nb) ? bsums[t] : 0;
    sm[t] = v; __syncthreads();
    for (int ofs = 1; ofs < 256; ofs <<= 1) {
        int u = (t >= ofs) ? sm[t - ofs] : 0;
        __syncthreads();
        sm[t] += u;
        __syncthreads();
    }
    if (t < nb) bsums[t] = sm[t] - v;
    if (t == 255) rowptr[N] = sm[255];
}

__global__ void k_scan3(int N, int* rowptr, const int* __restrict__ bsums) {
    int n = blockIdx.x * blockDim.x + threadIdx.x;
    if (n < N) rowptr[n] += bsums[n >> 8];
}

// one packed 8B scattered store per edge: rec = {src, attr_bits}
__global__ void k_scatter(int E, int CH, const int* __restrict__ ei, const float* __restrict__ ea,
                          const int* __restrict__ rowptr, const int* __restrict__ H,
                          const int* __restrict__ rank, int2* __restrict__ rec) {
    int e = blockIdx.x * blockDim.x + threadIdx.x;
    if (e >= E) return;
    int s = ei[e], d = ei[E + e];
    int r = d >> 14, dr = d & (NRR - 1);
    int b = e / CH;
    int pos = rowptr[d] + H[((size_t)(r * RB + b)) * NRR + dr] + rank[e];
    unsigned long long pk = ((unsigned long long)(unsigned)__float_as_int(ea[e]) << 32)
                          | (unsigned long long)(unsigned)s;
    __builtin_nontemporal_store(pk, (unsigned long long*)&rec[pos]);
}

// ---------------- fused misc: selfloop fill + x->fp16 + W1 pack + wed dots ----------------

__global__ __launch_bounds__(256) void k_misc(
    int N, int nbN, int Mpad, const int* __restrict__ rowptr, int2* __restrict__ rec,
    const float* __restrict__ x, _Float16* __restrict__ xh,
    const float* __restrict__ W1, _Float16* __restrict__ Wpk,
    const float* __restrict__ We1, const float* __restrict__ ae1,
    const float* __restrict__ We2, const float* __restrict__ ae2,
    float* __restrict__ wed) {
    int bid = blockIdx.x;
    if (bid < nbN) {
        // self-loop: reserved last slot of each segment, mean incoming edge attr
        int d = bid * 256 + threadIdx.x;
        if (d < N) {
            int start = rowptr[d], slot = rowptr[d + 1] - 1;
            float ssum = 0.0f;
            for (int i = start; i < slot; ++i) ssum += __int_as_float(rec[i].y);
            float mean = ssum / fmaxf((float)(slot - start), 1.0f);
            rec[slot] = make_int2(d, __float_as_int(mean));
        }
    } else if (bid < nbN + Mpad / 32) {
        // x -> fp16, zero-padded
        int t = (bid - nbN) * 256 + threadIdx.x;
        int row = t >> 3;
        half8 h;
        if (row < N) {
            const float4* pp = (const float4*)(x + (size_t)t * 8);
            float4 f0 = pp[0], f1 = pp[1];
            h[0] = (_Float16)f0.x; h[1] = (_Float16)f0.y; h[2] = (_Float16)f0.z; h[3] = (_Float16)f0.w;
            h[4] = (_Float16)f1.x; h[5] = (_Float16)f1.y; h[6] = (_Float16)f1.z; h[7] = (_Float16)f1.w;
        } else {
#pragma unroll
            for (int i = 0; i < 8; ++i) h[i] = (_Float16)0.0f;
        }
        *(half8*)(xh + (size_t)t * 8) = h;
    } else {
        // W1 -> MFMA B-fragment order + wed dots (wed pre-scaled by log2e)
        int t = threadIdx.x;
        for (int i = 0; i < 32; ++i) {
            int idx = i * 256 + t;           // 8192 total
            int j  = idx & 7;
            int lq = (idx >> 3) & 63;
            int ks = (idx >> 9) & 1;
            int ct = idx >> 10;
            int k   = ks * 32 + (lq >> 4) * 8 + j;
            int col = ct * 16 + (lq & 15);
            Wpk[idx] = (_Float16)W1[k * 128 + col];
        }
        if (t < 8) {
            float ssum = 0.0f;
            for (int cc = 0; cc < 16; ++cc) ssum += We1[t * 16 + cc] * ae1[t * 16 + cc];
            wed[t] = ssum * LOG2E;
        }
        if (t == 8) {
            float ssum = 0.0f;
            for (int cc = 0; cc < 8; ++cc) ssum += We2[cc] * ae2[cc];
            wed[8] = ssum * LOG2E;
        }
    }
}

// ---------------- layer 1 dense via MFMA (attention dots pre-scaled by log2e) ----------------

#define LDSP 132

__global__ __launch_bounds__(256) void k_gemm1m(
    int N, const _Float16* __restrict__ xh, const _Float16* __restrict__ Wpk,
    const float* __restrict__ att_s, const float* __restrict__ att_d,
    __half* __restrict__ h1, float* __restrict__ asrc, float* __restrict__ adst) {
    __shared__ float hs[4 * 16 * LDSP];
    int tid = threadIdx.x;
    int w = tid >> 6, l = tid & 63;
    int row0 = blockIdx.x * 64 + w * 16;
    int arow = row0 + (l & 15);
    half8 a0 = *(const half8*)(xh + (size_t)arow * 64 + (l >> 4) * 8);
    half8 a1 = *(const half8*)(xh + (size_t)arow * 64 + 32 + (l >> 4) * 8);
    float* base = &hs[w * 16 * LDSP];
    int r0 = (l >> 4) * 4;
#pragma unroll
    for (int ct = 0; ct < 8; ++ct) {
        half8 b0 = *(const half8*)(Wpk + ((ct * 2 + 0) * 64 + l) * 8);
        half8 b1 = *(const half8*)(Wpk + ((ct * 2 + 1) * 64 + l) * 8);
        floatx4 acc = {0.f, 0.f, 0.f, 0.f};
        acc = __builtin_amdgcn_mfma_f32_16x16x32_f16(a0, b0, acc, 0, 0, 0);
        acc = __builtin_amdgcn_mfma_f32_16x16x32_f16(a1, b1, acc, 0, 0, 0);
        int col = ct * 16 + (l & 15);
#pragma unroll
        for (int i = 0; i < 4; ++i)
            base[(r0 + i) * LDSP + col] = acc[i];
    }
    __syncthreads();
    int r = tid >> 2, g = tid & 3;
    int rg = blockIdx.x * 64 + r;
    if (rg >= N) return;
    float v[32];
    const float* rp = &hs[r * LDSP + g * 32];
#pragma unroll
    for (int j = 0; j < 8; ++j) {
        floatx4 t4 = *(const floatx4*)(rp + j * 4);
        v[j * 4 + 0] = t4[0]; v[j * 4 + 1] = t4[1];
        v[j * 4 + 2] = t4[2]; v[j * 4 + 3] = t4[3];
    }
    float vs0 = 0.f, vs1 = 0.f, vd0 = 0.f, vd1 = 0.f;
    const float4* as4 = (const float4*)(att_s + g * 32);
    const float4* ad4 = (const float4*)(att_d + g * 32);
#pragma unroll
    for (int j = 0; j < 4; ++j) {
        float4 a4 = as4[j], d4 = ad4[j];
        vs0 += v[j*4+0]*a4.x + v[j*4+1]*a4.y + v[j*4+2]*a4.z + v[j*4+3]*a4.w;
        vd0 += v[j*4+0]*d4.x + v[j*4+1]*d4.y + v[j*4+2]*d4.z + v[j*4+3]*d4.w;
    }
#pragma unroll
    for (int j = 4; j < 8; ++j) {
        float4 a4 = as4[j], d4 = ad4[j];
        vs1 += v[j*4+0]*a4.x + v[j*4+1]*a4.y + v[j*4+2]*a4.z + v[j*4+3]*a4.w;
        vd1 += v[j*4+0]*d4.x + v[j*4+1]*d4.y + v[j*4+2]*d4.z + v[j*4+3]*d4.w;
    }
    union { __half h[32]; float4 f4[4]; } u;
#pragma unroll
    for (int i = 0; i < 32; ++i) u.h[i] = __float2half(v[i]);
    float4* hp = (float4*)(h1 + (size_t)rg * 128 + g * 32);
#pragma unroll
    for (int j = 0; j < 4; ++j) hp[j] = u.f4[j];
    asrc[rg * 8 + g * 2]     = vs0 * LOG2E;
    asrc[rg * 8 + g * 2 + 1] = vs1 * LOG2E;
    adst[rg * 8 + g * 2]     = vd0 * LOG2E;
    adst[rg * 8 + g * 2 + 1] = vd1 * LOG2E;
}

// ---------------- layer 1 aggregation v3 + fused layer-2 dense ----------------
// one wave per node; lane l = (eo = l>>3 edge slot, hd = l&7 head).
// Each lane owns all 16 channels of head hd for its edge: 2x float4 (32B) loads,
// p computed once per lane. Single stream, 8 edges/iter; rec prefetched 2 deep,
// asrc 1 deep -> all loop loads issue with register-ready addresses.
// Epilogue: per-head denom reduce (3 shfl), acc/denom -> conflict-free stride-65
// LDS transpose sums edges+heads in one pass; fused relu/b1 + W2 matmul + dots.

__global__ __launch_bounds__(256) void k_agg1(
    int N, const int* __restrict__ rowptr, const int2* __restrict__ rec,
    const float* __restrict__ asrc1, const float* __restrict__ adst1,
    const float* __restrict__ wed,
    const __half* __restrict__ h1v, const float* __restrict__ b1,
    const float* __restrict__ W2, const float* __restrict__ as2w, const float* __restrict__ ad2w,
    float* __restrict__ hh2, float* __restrict__ asrc2, float* __restrict__ adst2) {
    __shared__ float hs[4 * 1040];   // 4 waves x 16 rows x 65 floats
    int tid = threadIdx.x;
    int wid = (blockIdx.x * blockDim.x + tid) >> 6;
    if (wid >= N) return;
    int l = tid & 63, w = tid >> 6;
    int eo = l >> 3, hd = l & 7;
    int start = rowptr[wid], end = rowptr[wid + 1];
    int last = end - 1;
    int len = end - start;
    float adn = adst1[wid * 8 + hd];   // pre-scaled by log2e
    float wdh = wed[hd];               // pre-scaled by log2e
    const _Float16* h1p = (const _Float16*)h1v;

    float acc[16];
#pragma unroll
    for (int k = 0; k < 16; ++k) acc[k] = 0.f;
    float denom = 0.f;
    int e = start + eo;
    int2 rv  = rec[min(e, last)];
    int2 rn1 = rec[min(e + 8, last)];
    float av = asrc1[rv.x * 8 + hd];
    int nIt = (len + 7) >> 3;
    for (int it = 0; it < nIt; ++it) {
        const _Float16* hr = h1p + (((size_t)rv.x) << 7) + hd * 16;
        float4 hv0 = *(const float4*)hr;          // addr register-ready (rv 2 iters old)
        float4 hv1 = *(const float4*)(hr + 8);
        int2 rn2 = rec[min(e + 16, last)];        // 2-ahead rec
        float an = asrc1[rn1.x * 8 + hd];         // 1-ahead asrc (rn1 ready)
        float a = av + adn + __int_as_float(rv.y) * wdh;
        a = fmaxf(a, 0.2f * a);                   // leaky-relu (scale-commutes)
        float p = (e < end) ? exp2f(a) : 0.f;
        denom += p;
        const _Float16* x0 = (const _Float16*)&hv0;
        const _Float16* x1 = (const _Float16*)&hv1;
#pragma unroll
        for (int k = 0; k < 8; ++k) acc[k]     = fmaf(p, (float)x0[k], acc[k]);
#pragma unroll
        for (int k = 0; k < 8; ++k) acc[8 + k] = fmaf(p, (float)x1[k], acc[8 + k]);
        rv = rn1; rn1 = rn2; av = an; e += 8;
    }
    // denom over the 8 edge slots of this head (lanes differ in bits 3..5)
    denom += __shfl_xor(denom, 8);
    denom += __shfl_xor(denom, 16);
    denom += __shfl_xor(denom, 32);
    float invd = 1.0f / (denom + EPS);
    // normalized partials -> LDS [channel][lane], stride 65 (conflict-free both ways)
    float* hw = &hs[w * 1040];
#pragma unroll
    for (int k = 0; k < 16; ++k) hw[k * 65 + l] = acc[k] * invd;
    // sum 64 lanes per channel = sum over edges AND heads (head-mean numerator)
    int c = l & 15, qt = l >> 4;
    const float* rp = &hw[c * 65 + qt * 16];
    float v = 0.f;
#pragma unroll
    for (int i = 0; i < 16; ++i) v += rp[i];
    v += __shfl_xor(v, 16);
    v += __shfl_xor(v, 32);
    // t = relu(mean + b1); fused hh = t @ W2 (lane (c,qt) covers cols 2qt,2qt+1)
    float t = fmaxf(v * 0.125f + b1[c], 0.f);
    float p0 = t * W2[c * 8 + 2 * qt];
    float p1 = t * W2[c * 8 + 2 * qt + 1];
#pragma unroll
    for (int m = 1; m <= 8; m <<= 1) {
        p0 += __shfl_xor(p0, m);
        p1 += __shfl_xor(p1, m);
    }
    if (c == 0) *(float2*)&hh2[(size_t)wid * 8 + 2 * qt] = make_float2(p0, p1);
    float sd = p0 * as2w[2 * qt] + p1 * as2w[2 * qt + 1];
    float dd = p0 * ad2w[2 * qt] + p1 * ad2w[2 * qt + 1];
    sd += __shfl_xor(sd, 16); sd += __shfl_xor(sd, 32);
    dd += __shfl_xor(dd, 16); dd += __shfl_xor(dd, 32);
    if (l == 0) { asrc2[wid] = sd * LOG2E; adst2[wid] = dd * LOG2E; }
}

// ---------------- layer 2 aggregation (two streams, 2-deep rec prefetch) ----------------

__global__ __launch_bounds__(256) void k_agg2(
    int N, const int* __restrict__ rowptr, const int2* __restrict__ rec,
    const float* __restrict__ asrc2, const float* __restrict__ adst2,
    const float* __restrict__ wed,
    const float* __restrict__ hh, const float* __restrict__ b2, float* __restrict__ out) {
    int wid = (blockIdx.x * blockDim.x + threadIdx.x) >> 6;
    if (wid >= N) return;
    int l = threadIdx.x & 63;
    int eo = l >> 3, c = l & 7;
    int start = rowptr[wid], end = rowptr[wid + 1];
    int len = end - start;
    int G = (len + 7) >> 3;
    int nIt = (G + 1) >> 1;
    int startB = start + (nIt << 3);
    int endA = min(startB, end);
    float adn = adst2[wid];   // pre-scaled
    float w2 = wed[8];        // pre-scaled

    float acc = 0.0f, denom = 0.0f;
    int eA = start + eo, eB = startB + eo;
    int last = end - 1;
    int2 rvA  = rec[min(eA, last)];
    int2 rnA1 = rec[min(eA + 8, last)];
    int2 rvB  = rec[min(eB, last)];
    int2 rnB1 = rec[min(eB + 8, last)];
    float avA = asrc2[rvA.x];
    float avB = asrc2[rvB.x];
    for (int it = 0; it < nIt; ++it) {
        float hvA = hh[(size_t)rvA.x * 8 + c];
        float hvB = hh[(size_t)rvB.x * 8 + c];
        int2 rnA2 = rec[min(eA + 16, last)];
        int2 rnB2 = rec[min(eB + 16, last)];
        float anA = asrc2[rnA1.x];
        float anB = asrc2[rnB1.x];
        float aA = avA + adn + __int_as_float(rvA.y) * w2;
        aA = fmaxf(aA, 0.2f * aA);
        float pA = (eA < endA) ? exp2f(aA) : 0.0f;
        float aB = avB + adn + __int_as_float(rvB.y) * w2;
        aB = fmaxf(aB, 0.2f * aB);
        float pB = (eB < end) ? exp2f(aB) : 0.0f;
        denom += pA + pB;
        acc = fmaf(pA, hvA, fmaf(pB, hvB, acc));
        rvA = rnA1; rnA1 = rnA2; avA = anA; eA += 8;
        rvB = rnB1; rnB1 = rnB2; avB = anB; eB += 8;
    }
    acc += __shfl_xor(acc, 8);  acc += __shfl_xor(acc, 16);  acc += __shfl_xor(acc, 32);
    denom += __shfl_xor(denom, 8); denom += __shfl_xor(denom, 16); denom += __shfl_xor(denom, 32);
    if (l < 8) out[(size_t)wid * 8 + l] = acc / (denom + EPS) + b2[l];
}

// ---------------- launch ----------------

extern "C" void kernel_launch(void* const* d_in, const int* in_sizes, int n_in,
                              void* d_out, int out_size, void* d_ws, size_t ws_size,
                              hipStream_t stream) {
    const float* x        = (const float*)d_in[0];
    const int*   ei       = (const int*)d_in[1];
    const float* ea       = (const float*)d_in[2];
    const float* W1       = (const float*)d_in[3];
    const float* We1      = (const float*)d_in[4];
    const float* att_src1 = (const float*)d_in[5];
    const float* att_dst1 = (const float*)d_in[6];
    const float* att_edge1= (const float*)d_in[7];
    const float* b1       = (const float*)d_in[8];
    const float* W2       = (const float*)d_in[9];
    const float* We2      = (const float*)d_in[10];
    const float* att_src2 = (const float*)d_in[11];
    const float* att_dst2 = (const float*)d_in[12];
    const float* att_edge2= (const float*)d_in[13];
    const float* b2       = (const float*)d_in[14];
    float* out = (float*)d_out;

    const int N = in_sizes[0] / 64;
    const int E = in_sizes[2];
    const int E2 = E + N;
    const int CH = (E + RB - 1) / RB;
    const int NB64 = (N + 63) / 64;
    const int Mpad = NB64 * 64;

    char* p = (char*)d_ws;
    auto alloc = [&](size_t bytes) { void* r = (void*)p; p += (bytes + 255) & ~(size_t)255; return r; };
    // ---- persistent ----
    int*   rowptr = (int*)  alloc((size_t)(N + 1) * 4);
    int*   bsums  = (int*)  alloc((size_t)4096 * 4);
    int2*  rec    = (int2*) alloc((size_t)E2 * 8);
    _Float16* Wpk = (_Float16*)alloc((size_t)8192 * 2);
    __half* h1    = (__half*)alloc((size_t)Mpad * 128 * 2);
    float* asrc1  = (float*)alloc((size_t)N * 8 * 4);
    float* adst1  = (float*)alloc((size_t)N * 8 * 4);
    float* hh2    = (float*)alloc((size_t)N * 8 * 4);
    float* asrc2  = (float*)alloc((size_t)N * 4);
    float* adst2  = (float*)alloc((size_t)N * 4);
    float* wed    = (float*)alloc(16 * 4);
    // ---- phase-aliased scratch (sequential lifetimes) ----
    char* pS = p;
    int*   rank  = (int*)pS;                                            // CSR phase
    int*   H     = (int*)(pS + (((size_t)E * 4 + 255) & ~(size_t)255)); // CSR phase
    _Float16* xh = (_Float16*)pS;                                       // gemm phase

    const int nbN = (N + 255) / 256;

    hipLaunchKernelGGL(k_hist,    dim3(RNG * RB), dim3(256), 0, stream, E, CH, ei, H, rank);
    hipLaunchKernelGGL(k_cntscan, dim3(nbN), dim3(256), 0, stream, N, H, rowptr, bsums);
    hipLaunchKernelGGL(k_scan2,   dim3(1), dim3(256), 0, stream, nbN, N, bsums, rowptr);
    hipLaunchKernelGGL(k_scan3,   dim3(nbN), dim3(256), 0, stream, N, rowptr, bsums);
    hipLaunchKernelGGL(k_scatter, dim3((E + 255) / 256), dim3(256), 0, stream, E, CH, ei, ea, rowptr, H, rank, rec);
    hipLaunchKernelGGL(k_misc,    dim3(nbN + Mpad / 32 + 1), dim3(256), 0, stream, N, nbN, Mpad, rowptr,
                       rec, x, xh, W1, Wpk, We1, att_edge1, We2, att_edge2, wed);
    hipLaunchKernelGGL(k_gemm1m,  dim3(NB64), dim3(256), 0, stream, N, xh, Wpk, att_src1, att_dst1, h1, asrc1, adst1);
    hipLaunchKernelGGL(k_agg1,    dim3((N + 3) / 4), dim3(256), 0, stream, N, rowptr, rec, asrc1, adst1, wed,
                       h1, b1, W2, att_src2, att_dst2, hh2, asrc2, adst2);
    hipLaunchKernelGGL(k_agg2,    dim3((N + 3) / 4), dim3(256), 0, stream, N, rowptr, rec, asrc2, adst2, wed,
                       hh2, b2, out);
}

// Round 10
// 138.539 us; speedup vs baseline: 2.5627x; 1.0374x over previous
//
#include <hip/hip_runtime.h>
#include <hip/hip_fp16.h>
#include <math.h>

#define EPS 1e-16f
#define LOG2E 1.44269504088896340736f

typedef _Float16 half8 __attribute__((ext_vector_type(8)));
typedef float floatx4 __attribute__((ext_vector_type(4)));

// CSR-build geometry: 4 dst-ranges x 16384 nodes (64KB LDS histogram),
// 64 edge-chunk blocks per range -> 256 blocks (all CUs).
#define RNG 4
#define NRR 16384
#define RB  64

// ---------------- CSR build (atomic-free at global scope) ----------------

__global__ __launch_bounds__(256) void k_hist(int E, int CH, const int* __restrict__ ei,
                                              int* __restrict__ H, int* __restrict__ rank) {
    int r = blockIdx.x / RB, b = blockIdx.x % RB;
    __shared__ int hist[NRR];
    for (int i = threadIdx.x; i < NRR; i += 256) hist[i] = 0;
    __syncthreads();
    int lo = b * CH, hi = min(E, (b + 1) * CH);
    int rlo = r << 14;
#pragma unroll 4
    for (int e = lo + threadIdx.x; e < hi; e += 256) {
        int d = ei[E + e];
        int dr = d - rlo;
        if ((unsigned)dr < NRR) rank[e] = atomicAdd(&hist[dr], 1);
    }
    __syncthreads();
    int* Hb = H + (size_t)blockIdx.x * NRR;
    for (int i = threadIdx.x; i < NRR; i += 256) Hb[i] = hist[i];
}

// fused: per-node scan of the RB block-histograms (in place) + block-level
// exclusive scan of cnt into rowptr-local + bsums.  (no self-loop slot)
__global__ __launch_bounds__(256) void k_cntscan(int N, int* __restrict__ H,
                                                 int* rowptr, int* bsums) {
    __shared__ int sm[256];
    int t = threadIdx.x;
    int n = blockIdx.x * 256 + t;
    int sum = 0;
    if (n < N) {
        int r = n >> 14, dr = n & (NRR - 1);
        size_t base = ((size_t)(r * RB)) * NRR + dr;
#pragma unroll 8
        for (int b = 0; b < RB; ++b) {
            size_t idx = base + (size_t)b * NRR;
            int v = H[idx];
            H[idx] = sum;
            sum += v;
        }
    }
    int val = (n < N) ? sum : 0;
    sm[t] = val; __syncthreads();
    for (int ofs = 1; ofs < 256; ofs <<= 1) {
        int v = (t >= ofs) ? sm[t - ofs] : 0;
        __syncthreads();
        sm[t] += v;
        __syncthreads();
    }
    if (n < N) rowptr[n] = sm[t] - val;
    if (t == 255) bsums[blockIdx.x] = sm[255];
}

__global__ void k_scan2(int nb, int N, int* bsums, int* rowptr) {
    __shared__ int sm[256];
    int t = threadIdx.x;
    int v = (t < nb) ? bsums[t] : 0;
    sm[t] = v; __syncthreads();
    for (int ofs = 1; ofs < 256; ofs <<= 1) {
        int u = (t >= ofs) ? sm[t - ofs] : 0;
        __syncthreads();
        sm[t] += u;
        __syncthreads();
    }
    if (t < nb) bsums[t] = sm[t] - v;
    if (t == 255) rowptr[N] = sm[255];
}

__global__ void k_scan3(int N, int* rowptr, const int* __restrict__ bsums) {
    int n = blockIdx.x * blockDim.x + threadIdx.x;
    if (n < N) rowptr[n] += bsums[n >> 8];
}

// ---------------- fused misc: x->fp16 + W1 pack + wed dots (runs first) ----------------

__global__ __launch_bounds__(256) void k_misc(
    int N, int nbX, const float* __restrict__ x, _Float16* __restrict__ xh,
    const float* __restrict__ W1, _Float16* __restrict__ Wpk,
    const float* __restrict__ We1, const float* __restrict__ ae1,
    const float* __restrict__ We2, const float* __restrict__ ae2,
    float* __restrict__ wed) {
    int bid = blockIdx.x;
    if (bid < nbX) {
        // x -> fp16, zero-padded
        int t = bid * 256 + threadIdx.x;
        int row = t >> 3;
        half8 h;
        if (row < N) {
            const float4* pp = (const float4*)(x + (size_t)t * 8);
            float4 f0 = pp[0], f1 = pp[1];
            h[0] = (_Float16)f0.x; h[1] = (_Float16)f0.y; h[2] = (_Float16)f0.z; h[3] = (_Float16)f0.w;
            h[4] = (_Float16)f1.x; h[5] = (_Float16)f1.y; h[6] = (_Float16)f1.z; h[7] = (_Float16)f1.w;
        } else {
#pragma unroll
            for (int i = 0; i < 8; ++i) h[i] = (_Float16)0.0f;
        }
        *(half8*)(xh + (size_t)t * 8) = h;
    } else {
        // W1 -> MFMA B-fragment order + wed dots (pre-scaled by log2e)
        int t = threadIdx.x;
        for (int i = 0; i < 32; ++i) {
            int idx = i * 256 + t;           // 8192 total
            int j  = idx & 7;
            int lq = (idx >> 3) & 63;
            int ks = (idx >> 9) & 1;
            int ct = idx >> 10;
            int k   = ks * 32 + (lq >> 4) * 8 + j;
            int col = ct * 16 + (lq & 15);
            Wpk[idx] = (_Float16)W1[k * 128 + col];
        }
        if (t < 8) {
            float ssum = 0.0f;
            for (int cc = 0; cc < 16; ++cc) ssum += We1[t * 16 + cc] * ae1[t * 16 + cc];
            wed[t] = ssum * LOG2E;
        }
        if (t == 8) {
            float ssum = 0.0f;
            for (int cc = 0; cc < 8; ++cc) ssum += We2[cc] * ae2[cc];
            wed[8] = ssum * LOG2E;
        }
    }
}

// ---------------- fused: edge scatter (blocks < SB) + layer-1 MFMA gemm (rest) ----------

#define LDSP 132

__global__ __launch_bounds__(256) void k_scatgemm(
    int E, int CH, int SB, const int* __restrict__ ei, const float* __restrict__ ea,
    const int* __restrict__ rowptr, const int* __restrict__ H, const int* __restrict__ rank,
    int2* __restrict__ rec,
    int N, const _Float16* __restrict__ xh, const _Float16* __restrict__ Wpk,
    const float* __restrict__ att_s, const float* __restrict__ att_d,
    __half* __restrict__ h1, float* __restrict__ asrc, float* __restrict__ adst) {
    __shared__ float hs[4 * 16 * LDSP];
    if ((int)blockIdx.x < SB) {
        // ---- scatter: one packed 8B store per edge ----
        int e = blockIdx.x * 256 + threadIdx.x;
        if (e >= E) return;
        int s = ei[e], d = ei[E + e];
        int r = d >> 14, dr = d & (NRR - 1);
        int b = e / CH;
        int pos = rowptr[d] + H[((size_t)(r * RB + b)) * NRR + dr] + rank[e];
        unsigned long long pk = ((unsigned long long)(unsigned)__float_as_int(ea[e]) << 32)
                              | (unsigned long long)(unsigned)s;
        __builtin_nontemporal_store(pk, (unsigned long long*)&rec[pos]);
        return;
    }
    // ---- gemm: wave w computes rows [blk*64+w*16,+16) x 128; dots pre-scaled log2e ----
    int blk = blockIdx.x - SB;
    int tid = threadIdx.x;
    int w = tid >> 6, l = tid & 63;
    int row0 = blk * 64 + w * 16;
    int arow = row0 + (l & 15);
    half8 a0 = *(const half8*)(xh + (size_t)arow * 64 + (l >> 4) * 8);
    half8 a1 = *(const half8*)(xh + (size_t)arow * 64 + 32 + (l >> 4) * 8);
    float* base = &hs[w * 16 * LDSP];
    int r0 = (l >> 4) * 4;
#pragma unroll
    for (int ct = 0; ct < 8; ++ct) {
        half8 b0 = *(const half8*)(Wpk + ((ct * 2 + 0) * 64 + l) * 8);
        half8 b1 = *(const half8*)(Wpk + ((ct * 2 + 1) * 64 + l) * 8);
        floatx4 acc = {0.f, 0.f, 0.f, 0.f};
        acc = __builtin_amdgcn_mfma_f32_16x16x32_f16(a0, b0, acc, 0, 0, 0);
        acc = __builtin_amdgcn_mfma_f32_16x16x32_f16(a1, b1, acc, 0, 0, 0);
        int col = ct * 16 + (l & 15);
#pragma unroll
        for (int i = 0; i < 4; ++i)
            base[(r0 + i) * LDSP + col] = acc[i];
    }
    __syncthreads();
    int r = tid >> 2, g = tid & 3;
    int rg = blk * 64 + r;
    if (rg >= N) return;
    float v[32];
    const float* rp = &hs[r * LDSP + g * 32];
#pragma unroll
    for (int j = 0; j < 8; ++j) {
        floatx4 t4 = *(const floatx4*)(rp + j * 4);
        v[j * 4 + 0] = t4[0]; v[j * 4 + 1] = t4[1];
        v[j * 4 + 2] = t4[2]; v[j * 4 + 3] = t4[3];
    }
    float vs0 = 0.f, vs1 = 0.f, vd0 = 0.f, vd1 = 0.f;
    const float4* as4 = (const float4*)(att_s + g * 32);
    const float4* ad4 = (const float4*)(att_d + g * 32);
#pragma unroll
    for (int j = 0; j < 4; ++j) {
        float4 a4 = as4[j], d4 = ad4[j];
        vs0 += v[j*4+0]*a4.x + v[j*4+1]*a4.y + v[j*4+2]*a4.z + v[j*4+3]*a4.w;
        vd0 += v[j*4+0]*d4.x + v[j*4+1]*d4.y + v[j*4+2]*d4.z + v[j*4+3]*d4.w;
    }
#pragma unroll
    for (int j = 4; j < 8; ++j) {
        float4 a4 = as4[j], d4 = ad4[j];
        vs1 += v[j*4+0]*a4.x + v[j*4+1]*a4.y + v[j*4+2]*a4.z + v[j*4+3]*a4.w;
        vd1 += v[j*4+0]*d4.x + v[j*4+1]*d4.y + v[j*4+2]*d4.z + v[j*4+3]*d4.w;
    }
    union { __half h[32]; float4 f4[4]; } u;
#pragma unroll
    for (int i = 0; i < 32; ++i) u.h[i] = __float2half(v[i]);
    float4* hp = (float4*)(h1 + (size_t)rg * 128 + g * 32);
#pragma unroll
    for (int j = 0; j < 4; ++j) hp[j] = u.f4[j];
    asrc[rg * 8 + g * 2]     = vs0 * LOG2E;
    asrc[rg * 8 + g * 2 + 1] = vs1 * LOG2E;
    adst[rg * 8 + g * 2]     = vd0 * LOG2E;
    adst[rg * 8 + g * 2 + 1] = vd1 * LOG2E;
}

// ---------------- layer 1 aggregation (virtual self-loop) + fused layer-2 dense ---------
// one wave per node; lane l = (eo = l>>3 edge slot, hd = l&7 head). Segments hold only
// real edges; the self-loop (mean edge attr) is accumulated inline in the epilogue.

__global__ __launch_bounds__(256) void k_agg1(
    int N, const int* __restrict__ rowptr, const int2* __restrict__ rec,
    const float* __restrict__ asrc1, const float* __restrict__ adst1,
    const float* __restrict__ wed,
    const __half* __restrict__ h1v, const float* __restrict__ b1,
    const float* __restrict__ W2, const float* __restrict__ as2w, const float* __restrict__ ad2w,
    float* __restrict__ hh2, float* __restrict__ asrc2, float* __restrict__ adst2) {
    __shared__ float hs[4 * 1040];   // 4 waves x 16 rows x 65 floats
    int tid = threadIdx.x;
    int wid = (blockIdx.x * blockDim.x + tid) >> 6;
    if (wid >= N) return;
    int l = tid & 63, w = tid >> 6;
    int eo = l >> 3, hd = l & 7;
    int start = rowptr[wid], end = rowptr[wid + 1];
    int len = end - start;               // real edges
    int last = end - 1;
    bool has = (len > 0);
    float adn = adst1[wid * 8 + hd];     // pre-scaled by log2e
    float wdh = wed[hd];                 // pre-scaled by log2e
    const _Float16* h1p = (const _Float16*)h1v;

    float acc[16];
#pragma unroll
    for (int k = 0; k < 16; ++k) acc[k] = 0.f;
    float denom = 0.f, esum = 0.f;
    int e = start + eo;
    int2 rv  = rec[has ? min(e, last) : 0];
    int2 rn1 = rec[has ? min(e + 8, last) : 0];
    float av = asrc1[rv.x * 8 + hd];
    int nIt = (len + 7) >> 3;
    for (int it = 0; it < nIt; ++it) {
        const _Float16* hr = h1p + (((size_t)rv.x) << 7) + hd * 16;
        float4 hv0 = *(const float4*)hr;          // addr register-ready (rv 2 iters old)
        float4 hv1 = *(const float4*)(hr + 8);
        int2 rn2 = rec[min(e + 16, last)];        // 2-ahead rec
        float an = asrc1[rn1.x * 8 + hd];         // 1-ahead asrc
        float wgt = __int_as_float(rv.y);
        float a = av + adn + wgt * wdh;
        a = fmaxf(a, 0.2f * a);                   // leaky-relu (scale-commutes)
        bool valid = (e < end);
        float p = valid ? exp2f(a) : 0.f;
        esum += valid ? wgt : 0.f;
        denom += p;
        const _Float16* x0 = (const _Float16*)&hv0;
        const _Float16* x1 = (const _Float16*)&hv1;
#pragma unroll
        for (int k = 0; k < 8; ++k) acc[k]     = fmaf(p, (float)x0[k], acc[k]);
#pragma unroll
        for (int k = 0; k < 8; ++k) acc[8 + k] = fmaf(p, (float)x1[k], acc[8 + k]);
        rv = rn1; rn1 = rn2; av = an; e += 8;
    }
    // mean edge attr (reduce esum over the 8 edge-slot groups)
    esum += __shfl_xor(esum, 8);
    esum += __shfl_xor(esum, 16);
    esum += __shfl_xor(esum, 32);
    float mean = esum / (float)max(len, 1);
    // virtual self-loop (counted once: edge-slot group 0 only)
    float aself = asrc1[wid * 8 + hd] + adn + mean * wdh;
    aself = fmaxf(aself, 0.2f * aself);
    float pself = exp2f(aself);
    if (eo == 0) {
        denom += pself;
        const _Float16* hr = h1p + (((size_t)wid) << 7) + hd * 16;
        float4 hv0 = *(const float4*)hr;
        float4 hv1 = *(const float4*)(hr + 8);
        const _Float16* x0 = (const _Float16*)&hv0;
        const _Float16* x1 = (const _Float16*)&hv1;
#pragma unroll
        for (int k = 0; k < 8; ++k) acc[k]     = fmaf(pself, (float)x0[k], acc[k]);
#pragma unroll
        for (int k = 0; k < 8; ++k) acc[8 + k] = fmaf(pself, (float)x1[k], acc[8 + k]);
    }
    // denom over the 8 edge slots of this head
    denom += __shfl_xor(denom, 8);
    denom += __shfl_xor(denom, 16);
    denom += __shfl_xor(denom, 32);
    float invd = 1.0f / (denom + EPS);
    // normalized partials -> LDS [channel][lane], stride 65 (conflict-free both ways)
    float* hw = &hs[w * 1040];
#pragma unroll
    for (int k = 0; k < 16; ++k) hw[k * 65 + l] = acc[k] * invd;
    // sum 64 lanes per channel = sum over edges AND heads (head-mean numerator)
    int c = l & 15, qt = l >> 4;
    const float* rp = &hw[c * 65 + qt * 16];
    float v = 0.f;
#pragma unroll
    for (int i = 0; i < 16; ++i) v += rp[i];
    v += __shfl_xor(v, 16);
    v += __shfl_xor(v, 32);
    // t = relu(mean + b1); fused hh = t @ W2 (lane (c,qt) covers cols 2qt,2qt+1)
    float t = fmaxf(v * 0.125f + b1[c], 0.f);
    float p0 = t * W2[c * 8 + 2 * qt];
    float p1 = t * W2[c * 8 + 2 * qt + 1];
#pragma unroll
    for (int m = 1; m <= 8; m <<= 1) {
        p0 += __shfl_xor(p0, m);
        p1 += __shfl_xor(p1, m);
    }
    if (c == 0) *(float2*)&hh2[(size_t)wid * 8 + 2 * qt] = make_float2(p0, p1);
    float sd = p0 * as2w[2 * qt] + p1 * as2w[2 * qt + 1];
    float dd = p0 * ad2w[2 * qt] + p1 * ad2w[2 * qt + 1];
    sd += __shfl_xor(sd, 16); sd += __shfl_xor(sd, 32);
    dd += __shfl_xor(dd, 16); dd += __shfl_xor(dd, 32);
    if (l == 0) { asrc2[wid] = sd * LOG2E; adst2[wid] = dd * LOG2E; }
}

// ---------------- layer 2 aggregation (two streams, virtual self-loop) ----------------

__global__ __launch_bounds__(256) void k_agg2(
    int N, const int* __restrict__ rowptr, const int2* __restrict__ rec,
    const float* __restrict__ asrc2, const float* __restrict__ adst2,
    const float* __restrict__ wed,
    const float* __restrict__ hh, const float* __restrict__ b2, float* __restrict__ out) {
    int wid = (blockIdx.x * blockDim.x + threadIdx.x) >> 6;
    if (wid >= N) return;
    int l = threadIdx.x & 63;
    int eo = l >> 3, c = l & 7;
    int start = rowptr[wid], end = rowptr[wid + 1];
    int len = end - start;
    int last = end - 1;
    bool has = (len > 0);
    int G = (len + 7) >> 3;
    int nIt = (G + 1) >> 1;
    int startB = start + (nIt << 3);
    int endA = min(startB, end);
    float adn = adst2[wid];   // pre-scaled
    float w2 = wed[8];        // pre-scaled

    float acc = 0.0f, denom = 0.0f, esum = 0.0f;
    int eA = start + eo, eB = startB + eo;
    int2 rvA  = rec[has ? min(eA, last) : 0];
    int2 rnA1 = rec[has ? min(eA + 8, last) : 0];
    int2 rvB  = rec[has ? min(eB, last) : 0];
    int2 rnB1 = rec[has ? min(eB + 8, last) : 0];
    float avA = asrc2[rvA.x];
    float avB = asrc2[rvB.x];
    for (int it = 0; it < nIt; ++it) {
        float hvA = hh[(size_t)rvA.x * 8 + c];
        float hvB = hh[(size_t)rvB.x * 8 + c];
        int2 rnA2 = rec[min(eA + 16, last)];
        int2 rnB2 = rec[min(eB + 16, last)];
        float anA = asrc2[rnA1.x];
        float anB = asrc2[rnB1.x];
        float wA = __int_as_float(rvA.y);
        float wB = __int_as_float(rvB.y);
        float aA = avA + adn + wA * w2;
        aA = fmaxf(aA, 0.2f * aA);
        bool vA = (eA < endA);
        float pA = vA ? exp2f(aA) : 0.0f;
        float aB = avB + adn + wB * w2;
        aB = fmaxf(aB, 0.2f * aB);
        bool vB = (eB < end);
        float pB = vB ? exp2f(aB) : 0.0f;
        esum += (vA ? wA : 0.f) + (vB ? wB : 0.f);
        denom += pA + pB;
        acc = fmaf(pA, hvA, fmaf(pB, hvB, acc));
        rvA = rnA1; rnA1 = rnA2; avA = anA; eA += 8;
        rvB = rnB1; rnB1 = rnB2; avB = anB; eB += 8;
    }
    // mean attr + virtual self-loop (counted once via eo==0)
    esum += __shfl_xor(esum, 8); esum += __shfl_xor(esum, 16); esum += __shfl_xor(esum, 32);
    float mean = esum / (float)max(len, 1);
    float aself = asrc2[wid] + adn + mean * w2;
    aself = fmaxf(aself, 0.2f * aself);
    float pself = exp2f(aself);
    if (eo == 0) {
        denom += pself;
        acc = fmaf(pself, hh[(size_t)wid * 8 + c], acc);
    }
    acc += __shfl_xor(acc, 8);  acc += __shfl_xor(acc, 16);  acc += __shfl_xor(acc, 32);
    denom += __shfl_xor(denom, 8); denom += __shfl_xor(denom, 16); denom += __shfl_xor(denom, 32);
    if (l < 8) out[(size_t)wid * 8 + l] = acc / (denom + EPS) + b2[l];
}

// ---------------- launch ----------------

extern "C" void kernel_launch(void* const* d_in, const int* in_sizes, int n_in,
                              void* d_out, int out_size, void* d_ws, size_t ws_size,
                              hipStream_t stream) {
    const float* x        = (const float*)d_in[0];
    const int*   ei       = (const int*)d_in[1];
    const float* ea       = (const float*)d_in[2];
    const float* W1       = (const float*)d_in[3];
    const float* We1      = (const float*)d_in[4];
    const float* att_src1 = (const float*)d_in[5];
    const float* att_dst1 = (const float*)d_in[6];
    const float* att_edge1= (const float*)d_in[7];
    const float* b1       = (const float*)d_in[8];
    const float* W2       = (const float*)d_in[9];
    const float* We2      = (const float*)d_in[10];
    const float* att_src2 = (const float*)d_in[11];
    const float* att_dst2 = (const float*)d_in[12];
    const float* att_edge2= (const float*)d_in[13];
    const float* b2       = (const float*)d_in[14];
    float* out = (float*)d_out;

    const int N = in_sizes[0] / 64;
    const int E = in_sizes[2];
    const int CH = (E + RB - 1) / RB;
    const int NB64 = (N + 63) / 64;
    const int Mpad = NB64 * 64;
    const int SB = (E + 255) / 256;

    char* p = (char*)d_ws;
    auto alloc = [&](size_t bytes) { void* r = (void*)p; p += (bytes + 255) & ~(size_t)255; return r; };
    int*   rowptr = (int*)  alloc((size_t)(N + 1) * 4);
    int*   bsums  = (int*)  alloc((size_t)4096 * 4);
    int2*  rec    = (int2*) alloc((size_t)E * 8);
    _Float16* Wpk = (_Float16*)alloc((size_t)8192 * 2);
    _Float16* xh  = (_Float16*)alloc((size_t)Mpad * 64 * 2);
    __half* h1    = (__half*)alloc((size_t)Mpad * 128 * 2);
    float* asrc1  = (float*)alloc((size_t)N * 8 * 4);
    float* adst1  = (float*)alloc((size_t)N * 8 * 4);
    float* hh2    = (float*)alloc((size_t)N * 8 * 4);
    float* asrc2  = (float*)alloc((size_t)N * 4);
    float* adst2  = (float*)alloc((size_t)N * 4);
    float* wed    = (float*)alloc(16 * 4);
    int*   rank   = (int*)  alloc((size_t)E * 4);
    int*   H      = (int*)  alloc((size_t)RNG * RB * NRR * 4);

    const int nbN = (N + 255) / 256;
    const int nbX = Mpad / 32;

    hipLaunchKernelGGL(k_misc,     dim3(nbX + 1), dim3(256), 0, stream, N, nbX,
                       x, xh, W1, Wpk, We1, att_edge1, We2, att_edge2, wed);
    hipLaunchKernelGGL(k_hist,     dim3(RNG * RB), dim3(256), 0, stream, E, CH, ei, H, rank);
    hipLaunchKernelGGL(k_cntscan,  dim3(nbN), dim3(256), 0, stream, N, H, rowptr, bsums);
    hipLaunchKernelGGL(k_scan2,    dim3(1), dim3(256), 0, stream, nbN, N, bsums, rowptr);
    hipLaunchKernelGGL(k_scan3,    dim3(nbN), dim3(256), 0, stream, N, rowptr, bsums);
    hipLaunchKernelGGL(k_scatgemm, dim3(SB + NB64), dim3(256), 0, stream, E, CH, SB, ei, ea,
                       rowptr, H, rank, rec, N, xh, Wpk, att_src1, att_dst1, h1, asrc1, adst1);
    hipLaunchKernelGGL(k_agg1,     dim3((N + 3) / 4), dim3(256), 0, stream, N, rowptr, rec,
                       asrc1, adst1, wed, h1, b1, W2, att_src2, att_dst2, hh2, asrc2, adst2);
    hipLaunchKernelGGL(k_agg2,     dim3((N + 3) / 4), dim3(256), 0, stream, N, rowptr, rec,
                       asrc2, adst2, wed, hh2, b2, out);
}